// Round 1
// baseline (325.659 us; speedup 1.0000x reference)
//
#include <hip/hip_runtime.h>

typedef unsigned short u16;
typedef __attribute__((ext_vector_type(8))) unsigned short u16x8;
typedef __attribute__((ext_vector_type(8))) __bf16 bf16x8;
typedef __attribute__((ext_vector_type(4))) float f32x4;

__device__ __forceinline__ float bf2f(u16 u) {
    return __uint_as_float(((unsigned)u) << 16);
}
__device__ __forceinline__ u16 f2bf(float f) {
    unsigned u = __float_as_uint(f);
    return (u16)((u + 0x7FFFu + ((u >> 16) & 1u)) >> 16);
}

// ---------------------------------------------------------------------------
// K0: weight transform.  w1t[tap][o][ci] = w_conv1[o][ci][dy][dx]*scale2[o]
//     w2t[tap][o][ci] = w_conv2[o][ci][dy][dx]
//     wrt[o][ci]      = w_res[o][ci][0][0]
//     bias2f[o]       = b2 - m2*scale2
// total work = 294912 + 589824 + 32768 + 256 = 917760 = 3585*256
// ---------------------------------------------------------------------------
__global__ void prep_weights(const float* __restrict__ w1, const float* __restrict__ w2,
                             const float* __restrict__ wr,
                             const float* __restrict__ g2, const float* __restrict__ b2,
                             const float* __restrict__ m2, const float* __restrict__ v2,
                             u16* __restrict__ w1t, u16* __restrict__ w2t,
                             u16* __restrict__ wrt, float* __restrict__ bias2f) {
    int i = blockIdx.x * 256 + threadIdx.x;
    if (i < 294912) {
        int ci = i & 127; int t = i >> 7; int o = t & 255; int tap = t >> 8;
        int dy = tap / 3, dx = tap - dy * 3;
        float sc = g2[o] * rsqrtf(v2[o] + 1e-5f);
        w1t[i] = f2bf(w1[((o * 128 + ci) * 3 + dy) * 3 + dx] * sc);
    } else if (i < 294912 + 589824) {
        int j = i - 294912;
        int ci = j & 255; int t = j >> 8; int o = t & 255; int tap = t >> 8;
        int dy = tap / 3, dx = tap - dy * 3;
        w2t[j] = f2bf(w2[((o * 256 + ci) * 3 + dy) * 3 + dx]);
    } else if (i < 294912 + 589824 + 32768) {
        int j = i - (294912 + 589824);
        int ci = j & 127; int o = j >> 7;
        wrt[j] = f2bf(wr[o * 128 + ci]);
    } else {
        int o = i - (294912 + 589824 + 32768);
        if (o < 256) {
            float sc = g2[o] * rsqrtf(v2[o] + 1e-5f);
            bias2f[o] = b2[o] - m2[o] * sc;
        }
    }
}

// ---------------------------------------------------------------------------
// zero pad borders of pre [16][129][129][128] : row y=128 and col x=128
// total = 16*129*128 + 16*128*128 = 526336 = 2056*256
// ---------------------------------------------------------------------------
__global__ void zero_pre_pad(u16* __restrict__ pre) {
    int i = blockIdx.x * 256 + threadIdx.x;
    if (i < 16 * 129 * 128) {
        int c = i & 127; int t = i >> 7; int n = t / 129; int xx = t - n * 129;
        pre[((n * 129 + 128) * 129 + xx) * 128 + c] = 0;
    } else {
        int j = i - 16 * 129 * 128;
        int c = j & 127; int t = j >> 7; int n = t >> 7; int y = t & 127;
        pre[((n * 129 + y) * 129 + 128) * 128 + c] = 0;
    }
}

// ---------------------------------------------------------------------------
// zero pad borders of h1 [16][66][66][256]
// cells per image: 2*66 + 2*64 = 260 ; total = 16*260*256 = 1064960 = 4160*256
// ---------------------------------------------------------------------------
__global__ void zero_h1_pad(u16* __restrict__ h1) {
    int i = blockIdx.x * 256 + threadIdx.x;
    int c = i & 255;
    int t = i >> 8;
    int n = t / 260;
    int cl = t - n * 260;
    int y, x;
    if (cl < 66)       { y = 0;        x = cl; }
    else if (cl < 132) { y = 65;       x = cl - 66; }
    else if (cl < 196) { x = 0;        y = cl - 131; }
    else               { x = 65;       y = cl - 195; }
    h1[((n * 66 + y) * 66 + x) * 256 + c] = 0;
}

// ---------------------------------------------------------------------------
// K1: pre = relu(BN1(x)), NCHW f32 -> padded NHWC bf16 (interior only)
// one block per (n,y): transpose 128c x 128x tile through LDS
// ---------------------------------------------------------------------------
__global__ void pre_kernel(const float* __restrict__ x, const float* __restrict__ g,
                           const float* __restrict__ b, const float* __restrict__ m,
                           const float* __restrict__ v, u16* __restrict__ pre) {
    __shared__ u16 tile[128 * 136];
    int n = blockIdx.x >> 7, y = blockIdx.x & 127;
    int tid = threadIdx.x;
    int c = tid >> 1, xh = (tid & 1) << 6;
    float sc = g[c] * rsqrtf(v[c] + 1e-5f);
    float bi = b[c] - m[c] * sc;
    const float4* src = (const float4*)(x + (((n * 128 + c) * 128 + y) << 7) + xh);
#pragma unroll
    for (int j = 0; j < 16; ++j) {
        float4 val = src[j];
        int xb = xh + j * 4;
        tile[(xb + 0) * 136 + c] = f2bf(fmaxf(val.x * sc + bi, 0.f));
        tile[(xb + 1) * 136 + c] = f2bf(fmaxf(val.y * sc + bi, 0.f));
        tile[(xb + 2) * 136 + c] = f2bf(fmaxf(val.z * sc + bi, 0.f));
        tile[(xb + 3) * 136 + c] = f2bf(fmaxf(val.w * sc + bi, 0.f));
    }
    __syncthreads();
    int c0 = (tid & 15) << 3;
#pragma unroll
    for (int xi = 0; xi < 8; ++xi) {
        int xx = xi * 16 + (tid >> 4);
        u16x8 val = *(const u16x8*)&tile[xx * 136 + c0];
        *(u16x8*)(pre + ((n * 129 + y) * 129 + xx) * 128 + c0) = val;
    }
}

// ---------------------------------------------------------------------------
// templated implicit-GEMM conv (m97 structure):
//   tile 128(M=pixels) x 128(N=out ch), BK=64, 4 waves (2x2), 16x16x32 bf16 MFMA
//   A staged via per-lane-gather global_load_lds (linear LDS [pix][k])
//   B (weights [tap][256][CIN]) staged as [o][k]
// grid = 1024 blocks: bn = bid&1 (out-ch half), Mbase = (bid>>1)*128
// ---------------------------------------------------------------------------
template <int CIN, int NTAPS, int STRIDE, bool BIASRELU>
__global__ __launch_bounds__(256, 2)
void conv_mfma(const u16* __restrict__ in, const u16* __restrict__ wt,
               const float* __restrict__ bias, u16* __restrict__ out,
               int in_row, int in_img, int out_base, int out_row, int out_img) {
    constexpr int CSTEPS = CIN / 64;
    constexpr int KSTEPS = CSTEPS * NTAPS;
    __shared__ u16 lA[128 * 64];
    __shared__ u16 lB[128 * 64];

    const int tid = threadIdx.x;
    const int w = tid >> 6, l = tid & 63;
    const int bn = blockIdx.x & 1;
    const int Mbase = (blockIdx.x >> 1) << 7;
    const int wm = w >> 1, wn = w & 1;
    const int srow = l >> 3;
    const int chunk = l & 7;

    int abase[4], wbase[4];
#pragma unroll
    for (int i = 0; i < 4; ++i) {
        int pix = w * 32 + i * 8 + srow;
        int mm = Mbase + pix;
        int nn = mm >> 12, p = (mm >> 6) & 63, q = mm & 63;
        abase[i] = nn * in_img + (STRIDE * p) * in_row + (STRIDE * q) * CIN + chunk * 8;
        wbase[i] = (bn * 128 + pix) * CIN + chunk * 8;
    }

    f32x4 acc[4][4] = {};

    int abyte[4], bbyte[4];
#pragma unroll
    for (int f = 0; f < 4; ++f) {
        abyte[f] = ((wm * 64 + f * 16 + (l & 15)) * 64 + ((l >> 4) * 8)) * 2;
        bbyte[f] = ((wn * 64 + f * 16 + (l & 15)) * 64 + ((l >> 4) * 8)) * 2;
    }

    for (int ks = 0; ks < KSTEPS; ++ks) {
        const int tap = ks / CSTEPS;
        const int c0 = (ks % CSTEPS) * 64;
        const int dy = (NTAPS == 9) ? (tap / 3) : 0;
        const int dx = (NTAPS == 9) ? (tap - dy * 3) : 0;
        const int aoff = dy * in_row + dx * CIN + c0;
        const int boff = tap * 256 * CIN + c0;
        __syncthreads();
#pragma unroll
        for (int i = 0; i < 4; ++i) {
            const u16* gsrc = in + abase[i] + aoff;
            u16* ldst = &lA[(w * 32 + i * 8) * 64];
            __builtin_amdgcn_global_load_lds((__attribute__((address_space(1))) void*)gsrc,
                                             (__attribute__((address_space(3))) void*)ldst,
                                             16, 0, 0);
        }
#pragma unroll
        for (int i = 0; i < 4; ++i) {
            const u16* gsrc = wt + wbase[i] + boff;
            u16* ldst = &lB[(w * 32 + i * 8) * 64];
            __builtin_amdgcn_global_load_lds((__attribute__((address_space(1))) void*)gsrc,
                                             (__attribute__((address_space(3))) void*)ldst,
                                             16, 0, 0);
        }
        __syncthreads();
#pragma unroll
        for (int kk = 0; kk < 2; ++kk) {
            bf16x8 af[4], bv[4];
#pragma unroll
            for (int f = 0; f < 4; ++f)
                af[f] = *(const bf16x8*)((const char*)lA + abyte[f] + kk * 64);
#pragma unroll
            for (int f = 0; f < 4; ++f)
                bv[f] = *(const bf16x8*)((const char*)lB + bbyte[f] + kk * 64);
#pragma unroll
            for (int fm = 0; fm < 4; ++fm)
#pragma unroll
                for (int fn = 0; fn < 4; ++fn)
                    acc[fm][fn] = __builtin_amdgcn_mfma_f32_16x16x32_bf16(
                        af[fm], bv[fn], acc[fm][fn], 0, 0, 0);
        }
    }

    // epilogue: C frag = (col=lane&15 -> o, row=(lane>>4)*4+j -> pixel)
#pragma unroll
    for (int fm = 0; fm < 4; ++fm) {
        const int mloc = wm * 64 + fm * 16 + ((l >> 4) << 2);
#pragma unroll
        for (int fn = 0; fn < 4; ++fn) {
            const int o = bn * 128 + wn * 64 + fn * 16 + (l & 15);
            float bb = 0.f;
            if (BIASRELU) bb = bias[o];
#pragma unroll
            for (int j = 0; j < 4; ++j) {
                int mm = Mbase + mloc + j;
                int nn = mm >> 12, p = (mm >> 6) & 63, q = mm & 63;
                float val = acc[fm][fn][j] + bb;
                if (BIASRELU) val = fmaxf(val, 0.f);
                out[out_base + nn * out_img + p * out_row + q * 256 + o] = f2bf(val);
            }
        }
    }
}

// ---------------------------------------------------------------------------
// SE pooling stage 1: partial[n][pc][o] = sum over 128 pixels (deterministic)
// grid = 16*32 = 512 blocks
// ---------------------------------------------------------------------------
__global__ void pool_kernel(const u16* __restrict__ h2, float* __restrict__ partial) {
    int n = blockIdx.x >> 5, pc = blockIdx.x & 31;
    int t = threadIdx.x;
    const u16* base = h2 + (n * 4096 + pc * 128) * 256 + t;
    float s = 0.f;
#pragma unroll 8
    for (int r = 0; r < 128; ++r) s += bf2f(base[r * 256]);
    partial[(n * 32 + pc) * 256 + t] = s;
}

// ---------------------------------------------------------------------------
// SE MLP: a = sigmoid(relu(mean @ w1^T + b1) @ w2^T + b2)   (1 block, exact f32)
// ---------------------------------------------------------------------------
__global__ void se_kernel(const float* __restrict__ partial,
                          const float* __restrict__ w1, const float* __restrict__ b1,
                          const float* __restrict__ w2, const float* __restrict__ b2,
                          float* __restrict__ a) {
    __shared__ float sm[16 * 256];
    __shared__ float hl[16 * 16];
    int t = threadIdx.x;
    for (int n = 0; n < 16; ++n) {
        float s = 0.f;
        for (int pc = 0; pc < 32; ++pc) s += partial[(n * 32 + pc) * 256 + t];
        sm[n * 256 + t] = s * (1.0f / 4096.0f);
    }
    __syncthreads();
    {
        int bb = t >> 4, j = t & 15;
        float d = b1[j];
        for (int c = 0; c < 256; ++c) d += sm[bb * 256 + c] * w1[j * 256 + c];
        hl[bb * 16 + j] = fmaxf(d, 0.f);
    }
    __syncthreads();
    {
        int o = t;
        for (int bb = 0; bb < 16; ++bb) {
            float z = b2[o];
            for (int j = 0; j < 16; ++j) z += hl[bb * 16 + j] * w2[o * 16 + j];
            a[bb * 256 + o] = 1.0f / (1.0f + expf(-z));
        }
    }
}

// ---------------------------------------------------------------------------
// K5: out[n][o][p][q] = h2[n][p][q][o]*a[n][o] + res[n][p][q][o]  (NHWC->NCHW)
// one block per (n,p)
// ---------------------------------------------------------------------------
__global__ void finalize_kernel(const u16* __restrict__ h2, const u16* __restrict__ res,
                                const float* __restrict__ a, float* __restrict__ out) {
    __shared__ u16 th[256 * 68];
    __shared__ float al[256];
    int n = blockIdx.x >> 6, p = blockIdx.x & 63;
    int t = threadIdx.x;
    al[t] = a[n * 256 + t];
    __syncthreads();
    int o8 = (t & 31) << 3, qr = t >> 5;
    int pixbase = n * 4096 + p * 64;
#pragma unroll
    for (int qi = 0; qi < 8; ++qi) {
        int q = qi * 8 + qr;
        int gi = (pixbase + q) * 256 + o8;
        u16x8 hv = *(const u16x8*)(h2 + gi);
        u16x8 rv = *(const u16x8*)(res + gi);
#pragma unroll
        for (int k = 0; k < 8; ++k) {
            float vv = bf2f(hv[k]) * al[o8 + k] + bf2f(rv[k]);
            th[(o8 + k) * 68 + q] = f2bf(vv);
        }
    }
    __syncthreads();
    int q4 = (t & 15) << 2, ob = t >> 4;
#pragma unroll
    for (int oi = 0; oi < 16; ++oi) {
        int o = oi * 16 + ob;
        float4 vv;
        vv.x = bf2f(th[o * 68 + q4 + 0]);
        vv.y = bf2f(th[o * 68 + q4 + 1]);
        vv.z = bf2f(th[o * 68 + q4 + 2]);
        vv.w = bf2f(th[o * 68 + q4 + 3]);
        *(float4*)(out + ((n * 256 + o) * 64 + p) * 64 + q4) = vv;
    }
}

// ---------------------------------------------------------------------------
// workspace layout (bytes)
// ---------------------------------------------------------------------------
static const size_t OFF_PRE  = 0;                       // 68,161,536  (16*129*129*128 bf16); reused for h2
static const size_t OFF_H1   = 68161536;                // 35,684,352  (16*66*66*256 bf16)
static const size_t OFF_RES  = 103845888;               // 33,554,432  (16*64*64*256 bf16)
static const size_t OFF_W1T  = 137400320;               // 589,824
static const size_t OFF_W2T  = 137990144;               // 1,179,648
static const size_t OFF_WRT  = 139169792;               // 65,536
static const size_t OFF_B2F  = 139235328;               // 1,024
static const size_t OFF_PART = 139236352;               // 524,288
static const size_t OFF_A    = 139760640;               // 16,384

extern "C" void kernel_launch(void* const* d_in, const int* in_sizes, int n_in,
                              void* d_out, int out_size, void* d_ws, size_t ws_size,
                              hipStream_t stream) {
    (void)in_sizes; (void)n_in; (void)out_size; (void)ws_size;
    const float* x      = (const float*)d_in[0];
    const float* bn1_g  = (const float*)d_in[1];
    const float* bn1_b  = (const float*)d_in[2];
    const float* bn1_m  = (const float*)d_in[3];
    const float* bn1_v  = (const float*)d_in[4];
    const float* bn2_g  = (const float*)d_in[5];
    const float* bn2_b  = (const float*)d_in[6];
    const float* bn2_m  = (const float*)d_in[7];
    const float* bn2_v  = (const float*)d_in[8];
    const float* wc1    = (const float*)d_in[9];
    const float* wc2    = (const float*)d_in[10];
    const float* wres   = (const float*)d_in[11];
    const float* se_w1  = (const float*)d_in[12];
    const float* se_b1  = (const float*)d_in[13];
    const float* se_w2  = (const float*)d_in[14];
    const float* se_b2  = (const float*)d_in[15];

    char* ws = (char*)d_ws;
    u16*   pre    = (u16*)(ws + OFF_PRE);
    u16*   h2     = (u16*)(ws + OFF_PRE);   // aliases pre (dead by conv2)
    u16*   h1     = (u16*)(ws + OFF_H1);
    u16*   res    = (u16*)(ws + OFF_RES);
    u16*   w1t    = (u16*)(ws + OFF_W1T);
    u16*   w2t    = (u16*)(ws + OFF_W2T);
    u16*   wrt    = (u16*)(ws + OFF_WRT);
    float* bias2f = (float*)(ws + OFF_B2F);
    float* part   = (float*)(ws + OFF_PART);
    float* avec   = (float*)(ws + OFF_A);
    float* out    = (float*)d_out;

    prep_weights<<<3585, 256, 0, stream>>>(wc1, wc2, wres, bn2_g, bn2_b, bn2_m, bn2_v,
                                           w1t, w2t, wrt, bias2f);
    zero_pre_pad<<<2056, 256, 0, stream>>>(pre);
    zero_h1_pad<<<4160, 256, 0, stream>>>(h1);
    pre_kernel<<<2048, 256, 0, stream>>>(x, bn1_g, bn1_b, bn1_m, bn1_v, pre);

    // conv1: 3x3 s2, 128->256, +BN2(bias)+ReLU, out = padded h1 (base (1,1))
    conv_mfma<128, 9, 2, true><<<1024, 256, 0, stream>>>(
        pre, w1t, bias2f, h1,
        129 * 128, 129 * 129 * 128,
        67 * 256, 66 * 256, 66 * 66 * 256);

    // residual: 1x1 s2, 128->256
    conv_mfma<128, 1, 2, false><<<1024, 256, 0, stream>>>(
        pre, wrt, nullptr, res,
        129 * 128, 129 * 129 * 128,
        0, 64 * 256, 4096 * 256);

    // conv2: 3x3 s1, 256->256 (h2 overwrites pre region)
    conv_mfma<256, 9, 1, false><<<1024, 256, 0, stream>>>(
        h1, w2t, nullptr, h2,
        66 * 256, 66 * 66 * 256,
        0, 64 * 256, 4096 * 256);

    pool_kernel<<<512, 256, 0, stream>>>(h2, part);
    se_kernel<<<1, 256, 0, stream>>>(part, se_w1, se_b1, se_w2, se_b2, avec);
    finalize_kernel<<<1024, 256, 0, stream>>>(h2, res, avec, out);
}

// Round 2
// 289.590 us; speedup vs baseline: 1.1246x; 1.1246x over previous
//
#include <hip/hip_runtime.h>

typedef unsigned short u16;
typedef __attribute__((ext_vector_type(8))) unsigned short u16x8;
typedef __attribute__((ext_vector_type(8))) __bf16 bf16x8;
typedef __attribute__((ext_vector_type(4))) float f32x4;

__device__ __forceinline__ float bf2f(u16 u) {
    return __uint_as_float(((unsigned)u) << 16);
}
__device__ __forceinline__ u16 f2bf(float f) {
    unsigned u = __float_as_uint(f);
    return (u16)((u + 0x7FFFu + ((u >> 16) & 1u)) >> 16);
}

// ---------------------------------------------------------------------------
// K0: weight transform.  w1t[tap][o][ci] = w_conv1[o][ci][dy][dx]*scale2[o]
//     w2t[tap][o][ci] = w_conv2[o][ci][dy][dx];  wrt[o][ci] = w_res[o][ci]
//     bias2f[o] = b2 - m2*scale2
// ---------------------------------------------------------------------------
__global__ void prep_weights(const float* __restrict__ w1, const float* __restrict__ w2,
                             const float* __restrict__ wr,
                             const float* __restrict__ g2, const float* __restrict__ b2,
                             const float* __restrict__ m2, const float* __restrict__ v2,
                             u16* __restrict__ w1t, u16* __restrict__ w2t,
                             u16* __restrict__ wrt, float* __restrict__ bias2f) {
    int i = blockIdx.x * 256 + threadIdx.x;
    if (i < 294912) {
        int ci = i & 127; int t = i >> 7; int o = t & 255; int tap = t >> 8;
        int dy = tap / 3, dx = tap - dy * 3;
        float sc = g2[o] * rsqrtf(v2[o] + 1e-5f);
        w1t[i] = f2bf(w1[((o * 128 + ci) * 3 + dy) * 3 + dx] * sc);
    } else if (i < 294912 + 589824) {
        int j = i - 294912;
        int ci = j & 255; int t = j >> 8; int o = t & 255; int tap = t >> 8;
        int dy = tap / 3, dx = tap - dy * 3;
        w2t[j] = f2bf(w2[((o * 256 + ci) * 3 + dy) * 3 + dx]);
    } else if (i < 294912 + 589824 + 32768) {
        int j = i - (294912 + 589824);
        int ci = j & 127; int o = j >> 7;
        wrt[j] = f2bf(wr[o * 128 + ci]);
    } else {
        int o = i - (294912 + 589824 + 32768);
        if (o < 256) {
            float sc = g2[o] * rsqrtf(v2[o] + 1e-5f);
            bias2f[o] = b2[o] - m2[o] * sc;
        }
    }
}

// ---------------------------------------------------------------------------
// zero pad borders of pre [16][129][129][128] : row y=128 and col x=128
// ---------------------------------------------------------------------------
__global__ void zero_pre_pad(u16* __restrict__ pre) {
    int i = blockIdx.x * 256 + threadIdx.x;
    if (i < 16 * 129 * 128) {
        int c = i & 127; int t = i >> 7; int n = t / 129; int xx = t - n * 129;
        pre[((n * 129 + 128) * 129 + xx) * 128 + c] = 0;
    } else {
        int j = i - 16 * 129 * 128;
        int c = j & 127; int t = j >> 7; int n = t >> 7; int y = t & 127;
        pre[((n * 129 + y) * 129 + 128) * 128 + c] = 0;
    }
}

// ---------------------------------------------------------------------------
// zero pad borders of h1 [16][66][66][256]
// ---------------------------------------------------------------------------
__global__ void zero_h1_pad(u16* __restrict__ h1) {
    int i = blockIdx.x * 256 + threadIdx.x;
    int c = i & 255;
    int t = i >> 8;
    int n = t / 260;
    int cl = t - n * 260;
    int y, x;
    if (cl < 66)       { y = 0;        x = cl; }
    else if (cl < 132) { y = 65;       x = cl - 66; }
    else if (cl < 196) { x = 0;        y = cl - 131; }
    else               { x = 65;       y = cl - 195; }
    h1[((n * 66 + y) * 66 + x) * 256 + c] = 0;
}

// ---------------------------------------------------------------------------
// K1: pre = relu(BN1(x)), NCHW f32 -> padded NHWC bf16 (interior only)
// ---------------------------------------------------------------------------
__global__ void pre_kernel(const float* __restrict__ x, const float* __restrict__ g,
                           const float* __restrict__ b, const float* __restrict__ m,
                           const float* __restrict__ v, u16* __restrict__ pre) {
    __shared__ u16 tile[128 * 136];
    int n = blockIdx.x >> 7, y = blockIdx.x & 127;
    int tid = threadIdx.x;
    int c = tid >> 1, xh = (tid & 1) << 6;
    float sc = g[c] * rsqrtf(v[c] + 1e-5f);
    float bi = b[c] - m[c] * sc;
    const float4* src = (const float4*)(x + (((n * 128 + c) * 128 + y) << 7) + xh);
#pragma unroll
    for (int j = 0; j < 16; ++j) {
        float4 val = src[j];
        int xb = xh + j * 4;
        tile[(xb + 0) * 136 + c] = f2bf(fmaxf(val.x * sc + bi, 0.f));
        tile[(xb + 1) * 136 + c] = f2bf(fmaxf(val.y * sc + bi, 0.f));
        tile[(xb + 2) * 136 + c] = f2bf(fmaxf(val.z * sc + bi, 0.f));
        tile[(xb + 3) * 136 + c] = f2bf(fmaxf(val.w * sc + bi, 0.f));
    }
    __syncthreads();
    int c0 = (tid & 15) << 3;
#pragma unroll
    for (int xi = 0; xi < 8; ++xi) {
        int xx = xi * 16 + (tid >> 4);
        u16x8 val = *(const u16x8*)&tile[xx * 136 + c0];
        *(u16x8*)(pre + ((n * 129 + y) * 129 + xx) * 128 + c0) = val;
    }
}

// ===========================================================================
// 8-phase 256x256 implicit-GEMM conv (T2+T3+T4+T5)
//   BM=256 pixels, BN=256 out-ch, BK=64, 8 waves (2x4), 512 threads
//   LDS: A,B double-buffered K-tiles, 128 KiB total
//   Wave->tile interleave: m-frag f -> row (f>>2)*128 + wm*64 + (f&3)*16
//                          n-frag g -> col (g>>1)*128 + (g&1)*64 + wn*16
//   => phase quadrant (MH,NH) reads exactly A-half MH, B-half NH (uniform).
//   Staging: per phase one half (2 x global_load_lds per thread):
//     q0: A1(t+1)  q1: B1(t+1)  q2: A0(t+2)  q3: B0(t+2)
//   vmcnt(4) before tile-boundary barrier (drain vmcnt(0) at tile KT-2).
//   T2 swizzle: lds byte col ^= ((row&7)<<4); applied as inverse-swizzled
//   per-lane GLOBAL source (linear LDS dest) + swizzled ds_read address.
// ===========================================================================
struct Frags { bf16x8 a[4][2]; bf16x8 b[2][2]; };

template <int MH, int NH>
__device__ __forceinline__ Frags ldsread(const u16* lds, int Ab, int Bb,
                                         int wm, int wn, int l15, const int colw[2]) {
    Frags f;
#pragma unroll
    for (int fm = 0; fm < 4; ++fm)
#pragma unroll
        for (int kk = 0; kk < 2; ++kk)
            f.a[fm][kk] = *(const bf16x8*)&lds[Ab + (MH * 128 + wm * 64 + fm * 16 + l15) * 64 + colw[kk]];
#pragma unroll
    for (int gn = 0; gn < 2; ++gn)
#pragma unroll
        for (int kk = 0; kk < 2; ++kk)
            f.b[gn][kk] = *(const bf16x8*)&lds[Bb + (NH * 128 + gn * 64 + wn * 16 + l15) * 64 + colw[kk]];
    return f;
}

template <int MH, int NH>
__device__ __forceinline__ void mfma16(const Frags& f, f32x4 (&acc)[8][4]) {
#pragma unroll
    for (int fm = 0; fm < 4; ++fm)
#pragma unroll
        for (int gn = 0; gn < 2; ++gn)
#pragma unroll
            for (int kk = 0; kk < 2; ++kk)
                acc[MH * 4 + fm][NH * 2 + gn] = __builtin_amdgcn_mfma_f32_16x16x32_bf16(
                    f.a[fm][kk], f.b[gn][kk], acc[MH * 4 + fm][NH * 2 + gn], 0, 0, 0);
}

template <int CIN, int NTAPS, int STRIDE, bool BIASRELU>
__global__ __launch_bounds__(512, 2)
void conv_8ph(const u16* __restrict__ in, const u16* __restrict__ wt,
              const float* __restrict__ bias, u16* __restrict__ out,
              int in_row, int in_img, int out_base, int out_row, int out_img) {
    constexpr int CSTEPS = CIN / 64;
    constexpr int KT = CSTEPS * NTAPS;
    __shared__ __attribute__((aligned(16))) u16 lds[65536];  // A: [0,32768), B: [32768,65536)

    const int tid = threadIdx.x;
    const int w = tid >> 6, l = tid & 63;
    const int wm = w >> 2, wn = w & 3;
    const int l15 = l & 15;
    const int Mbase = blockIdx.x << 8;

    // ---- staging per-thread constants (inverse-swizzled source chunk) ----
    const int srow = tid >> 3;                               // row within 64-row round
    const int swze = (((tid & 7) ^ (srow & 7)) << 3);        // u16 offset of 16B chunk
    int agb[2][2], bgb[2][2];
#pragma unroll
    for (int h = 0; h < 2; ++h)
#pragma unroll
        for (int r = 0; r < 2; ++r) {
            int locrow = h * 128 + r * 64 + srow;
            int pix = Mbase + locrow;
            int nn = pix >> 12, p = (pix >> 6) & 63, q = pix & 63;
            agb[h][r] = nn * in_img + (STRIDE * p) * in_row + (STRIDE * q) * CIN + swze;
            bgb[h][r] = locrow * CIN + swze;
        }

    // ---- swizzled ds_read column offsets (u16 units) ----
    int colw[2];
#pragma unroll
    for (int kk = 0; kk < 2; ++kk)
        colw[kk] = (kk * 32 + (l >> 4) * 8) ^ ((l & 7) << 3);

    f32x4 acc[8][4] = {};

#define AOFF(ks) (((NTAPS == 9) ? ((((ks) / CSTEPS) / 3) * in_row + (((ks) / CSTEPS) % 3) * CIN) : 0) + ((ks) % CSTEPS) * 64)
#define BOFF(ks) (((ks) / CSTEPS) * 256 * CIN + ((ks) % CSTEPS) * 64)
#define STAGE_A(h, ks) {                                                            \
    int _ao = AOFF(ks); int _tb = (ks) & 1;                                         \
    __builtin_amdgcn_global_load_lds(                                               \
        (__attribute__((address_space(1))) void*)(in + agb[h][0] + _ao),            \
        (__attribute__((address_space(3))) void*)&lds[_tb * 16384 + (h) * 8192 + 0 * 4096 + w * 512], 16, 0, 0); \
    __builtin_amdgcn_global_load_lds(                                               \
        (__attribute__((address_space(1))) void*)(in + agb[h][1] + _ao),            \
        (__attribute__((address_space(3))) void*)&lds[_tb * 16384 + (h) * 8192 + 1 * 4096 + w * 512], 16, 0, 0); }
#define STAGE_B(h, ks) {                                                            \
    int _bo = BOFF(ks); int _tb = (ks) & 1;                                         \
    __builtin_amdgcn_global_load_lds(                                               \
        (__attribute__((address_space(1))) void*)(wt + bgb[h][0] + _bo),            \
        (__attribute__((address_space(3))) void*)&lds[32768 + _tb * 16384 + (h) * 8192 + 0 * 4096 + w * 512], 16, 0, 0); \
    __builtin_amdgcn_global_load_lds(                                               \
        (__attribute__((address_space(1))) void*)(wt + bgb[h][1] + _bo),            \
        (__attribute__((address_space(3))) void*)&lds[32768 + _tb * 16384 + (h) * 8192 + 1 * 4096 + w * 512], 16, 0, 0); }
#define BARRIER() { __builtin_amdgcn_s_barrier(); asm volatile("" ::: "memory"); }

    // ---- prologue: A0(0),B0(0),A1(0),B1(0),A0(1),B0(1); wait oldest 8 ----
    STAGE_A(0, 0); STAGE_B(0, 0); STAGE_A(1, 0); STAGE_B(1, 0);
    STAGE_A(0, 1); STAGE_B(0, 1);
    asm volatile("s_waitcnt vmcnt(4)" ::: "memory");
    BARRIER();

    // ---- main loop ----
#pragma unroll 2
    for (int t = 0; t < KT; ++t) {
        const int Ab = (t & 1) * 16384;
        const int Bb = 32768 + (t & 1) * 16384;
        {   // phase q0: quadrant (0,0); stage A1(t+1)
            Frags fr = ldsread<0, 0>(lds, Ab, Bb, wm, wn, l15, colw);
            if (t + 1 < KT) STAGE_A(1, t + 1);
            __builtin_amdgcn_s_barrier();
            asm volatile("s_waitcnt lgkmcnt(0)" ::: "memory");
            __builtin_amdgcn_s_setprio(1);
            mfma16<0, 0>(fr, acc);
            __builtin_amdgcn_s_setprio(0);
            BARRIER();
        }
        {   // phase q1: quadrant (0,1); stage B1(t+1)
            Frags fr = ldsread<0, 1>(lds, Ab, Bb, wm, wn, l15, colw);
            if (t + 1 < KT) STAGE_B(1, t + 1);
            __builtin_amdgcn_s_barrier();
            asm volatile("s_waitcnt lgkmcnt(0)" ::: "memory");
            __builtin_amdgcn_s_setprio(1);
            mfma16<0, 1>(fr, acc);
            __builtin_amdgcn_s_setprio(0);
            BARRIER();
        }
        {   // phase q2: quadrant (1,0); stage A0(t+2)
            Frags fr = ldsread<1, 0>(lds, Ab, Bb, wm, wn, l15, colw);
            if (t + 2 < KT) STAGE_A(0, t + 2);
            __builtin_amdgcn_s_barrier();
            asm volatile("s_waitcnt lgkmcnt(0)" ::: "memory");
            __builtin_amdgcn_s_setprio(1);
            mfma16<1, 0>(fr, acc);
            __builtin_amdgcn_s_setprio(0);
            BARRIER();
        }
        {   // phase q3: quadrant (1,1); stage B0(t+2); boundary vmcnt
            Frags fr = ldsread<1, 1>(lds, Ab, Bb, wm, wn, l15, colw);
            if (t + 2 < KT) STAGE_B(0, t + 2);
            __builtin_amdgcn_s_barrier();
            asm volatile("s_waitcnt lgkmcnt(0)" ::: "memory");
            __builtin_amdgcn_s_setprio(1);
            mfma16<1, 1>(fr, acc);
            __builtin_amdgcn_s_setprio(0);
            if (t + 2 < KT) {
                asm volatile("s_waitcnt vmcnt(4)" ::: "memory");
            } else if (t + 1 < KT) {
                asm volatile("s_waitcnt vmcnt(0)" ::: "memory");
            }
            BARRIER();
        }
    }
#undef AOFF
#undef BOFF
#undef STAGE_A
#undef STAGE_B
#undef BARRIER

    // ---- epilogue: C frag (col=lane&15 -> o, row=(lane>>4)*4+j -> pixel) ----
#pragma unroll
    for (int f = 0; f < 8; ++f) {
        const int prow = (f >> 2) * 128 + wm * 64 + (f & 3) * 16 + ((l >> 4) << 2);
#pragma unroll
        for (int g = 0; g < 4; ++g) {
            const int o = (g >> 1) * 128 + (g & 1) * 64 + wn * 16 + l15;
            float bb = 0.f;
            if (BIASRELU) bb = bias[o];
#pragma unroll
            for (int j = 0; j < 4; ++j) {
                int pix = Mbase + prow + j;
                int nn = pix >> 12, p = (pix >> 6) & 63, q = pix & 63;
                float val = acc[f][g][j] + bb;
                if (BIASRELU) val = fmaxf(val, 0.f);
                out[out_base + nn * out_img + p * out_row + q * 256 + o] = f2bf(val);
            }
        }
    }
}

// ---------------------------------------------------------------------------
// old 128x128 2-phase conv (kept for the tiny 1x1 residual conv, K=128)
// ---------------------------------------------------------------------------
template <int CIN, int NTAPS, int STRIDE, bool BIASRELU>
__global__ __launch_bounds__(256, 2)
void conv_mfma(const u16* __restrict__ in, const u16* __restrict__ wt,
               const float* __restrict__ bias, u16* __restrict__ out,
               int in_row, int in_img, int out_base, int out_row, int out_img) {
    constexpr int CSTEPS = CIN / 64;
    constexpr int KSTEPS = CSTEPS * NTAPS;
    __shared__ u16 lA[128 * 64];
    __shared__ u16 lB[128 * 64];

    const int tid = threadIdx.x;
    const int w = tid >> 6, l = tid & 63;
    const int bn = blockIdx.x & 1;
    const int Mbase = (blockIdx.x >> 1) << 7;
    const int wm = w >> 1, wn = w & 1;
    const int srow = l >> 3;
    const int chunk = l & 7;

    int abase[4], wbase[4];
#pragma unroll
    for (int i = 0; i < 4; ++i) {
        int pix = w * 32 + i * 8 + srow;
        int mm = Mbase + pix;
        int nn = mm >> 12, p = (mm >> 6) & 63, q = mm & 63;
        abase[i] = nn * in_img + (STRIDE * p) * in_row + (STRIDE * q) * CIN + chunk * 8;
        wbase[i] = (bn * 128 + pix) * CIN + chunk * 8;
    }

    f32x4 acc[4][4] = {};

    int abyte[4], bbyte[4];
#pragma unroll
    for (int f = 0; f < 4; ++f) {
        abyte[f] = ((wm * 64 + f * 16 + (l & 15)) * 64 + ((l >> 4) * 8)) * 2;
        bbyte[f] = ((wn * 64 + f * 16 + (l & 15)) * 64 + ((l >> 4) * 8)) * 2;
    }

    for (int ks = 0; ks < KSTEPS; ++ks) {
        const int tap = ks / CSTEPS;
        const int c0 = (ks % CSTEPS) * 64;
        const int dy = (NTAPS == 9) ? (tap / 3) : 0;
        const int dx = (NTAPS == 9) ? (tap - dy * 3) : 0;
        const int aoff = dy * in_row + dx * CIN + c0;
        const int boff = tap * 256 * CIN + c0;
        __syncthreads();
#pragma unroll
        for (int i = 0; i < 4; ++i) {
            const u16* gsrc = in + abase[i] + aoff;
            u16* ldst = &lA[(w * 32 + i * 8) * 64];
            __builtin_amdgcn_global_load_lds((__attribute__((address_space(1))) void*)gsrc,
                                             (__attribute__((address_space(3))) void*)ldst,
                                             16, 0, 0);
        }
#pragma unroll
        for (int i = 0; i < 4; ++i) {
            const u16* gsrc = wt + wbase[i] + boff;
            u16* ldst = &lB[(w * 32 + i * 8) * 64];
            __builtin_amdgcn_global_load_lds((__attribute__((address_space(1))) void*)gsrc,
                                             (__attribute__((address_space(3))) void*)ldst,
                                             16, 0, 0);
        }
        __syncthreads();
#pragma unroll
        for (int kk = 0; kk < 2; ++kk) {
            bf16x8 af[4], bv[4];
#pragma unroll
            for (int f = 0; f < 4; ++f)
                af[f] = *(const bf16x8*)((const char*)lA + abyte[f] + kk * 64);
#pragma unroll
            for (int f = 0; f < 4; ++f)
                bv[f] = *(const bf16x8*)((const char*)lB + bbyte[f] + kk * 64);
#pragma unroll
            for (int fm = 0; fm < 4; ++fm)
#pragma unroll
                for (int fn = 0; fn < 4; ++fn)
                    acc[fm][fn] = __builtin_amdgcn_mfma_f32_16x16x32_bf16(
                        af[fm], bv[fn], acc[fm][fn], 0, 0, 0);
        }
    }

#pragma unroll
    for (int fm = 0; fm < 4; ++fm) {
        const int mloc = wm * 64 + fm * 16 + ((l >> 4) << 2);
#pragma unroll
        for (int fn = 0; fn < 4; ++fn) {
            const int o = bn * 128 + wn * 64 + fn * 16 + (l & 15);
            float bb = 0.f;
            if (BIASRELU) bb = bias[o];
#pragma unroll
            for (int j = 0; j < 4; ++j) {
                int mm = Mbase + mloc + j;
                int nn = mm >> 12, p = (mm >> 6) & 63, q = mm & 63;
                float val = acc[fm][fn][j] + bb;
                if (BIASRELU) val = fmaxf(val, 0.f);
                out[out_base + nn * out_img + p * out_row + q * 256 + o] = f2bf(val);
            }
        }
    }
}

// ---------------------------------------------------------------------------
// SE pooling stage 1: partial[n][pc][o] = sum over 128 pixels (deterministic)
// ---------------------------------------------------------------------------
__global__ void pool_kernel(const u16* __restrict__ h2, float* __restrict__ partial) {
    int n = blockIdx.x >> 5, pc = blockIdx.x & 31;
    int t = threadIdx.x;
    const u16* base = h2 + (n * 4096 + pc * 128) * 256 + t;
    float s = 0.f;
#pragma unroll 8
    for (int r = 0; r < 128; ++r) s += bf2f(base[r * 256]);
    partial[(n * 32 + pc) * 256 + t] = s;
}

// ---------------------------------------------------------------------------
// SE MLP: a = sigmoid(relu(mean @ w1^T + b1) @ w2^T + b2)
// ---------------------------------------------------------------------------
__global__ void se_kernel(const float* __restrict__ partial,
                          const float* __restrict__ w1, const float* __restrict__ b1,
                          const float* __restrict__ w2, const float* __restrict__ b2,
                          float* __restrict__ a) {
    __shared__ float sm[16 * 256];
    __shared__ float hl[16 * 16];
    int t = threadIdx.x;
    for (int n = 0; n < 16; ++n) {
        float s = 0.f;
        for (int pc = 0; pc < 32; ++pc) s += partial[(n * 32 + pc) * 256 + t];
        sm[n * 256 + t] = s * (1.0f / 4096.0f);
    }
    __syncthreads();
    {
        int bb = t >> 4, j = t & 15;
        float d = b1[j];
        for (int c = 0; c < 256; ++c) d += sm[bb * 256 + c] * w1[j * 256 + c];
        hl[bb * 16 + j] = fmaxf(d, 0.f);
    }
    __syncthreads();
    {
        int o = t;
        for (int bb = 0; bb < 16; ++bb) {
            float z = b2[o];
            for (int j = 0; j < 16; ++j) z += hl[bb * 16 + j] * w2[o * 16 + j];
            a[bb * 256 + o] = 1.0f / (1.0f + expf(-z));
        }
    }
}

// ---------------------------------------------------------------------------
// K5: out[n][o][p][q] = h2[n][p][q][o]*a[n][o] + res[n][p][q][o]
// ---------------------------------------------------------------------------
__global__ void finalize_kernel(const u16* __restrict__ h2, const u16* __restrict__ res,
                                const float* __restrict__ a, float* __restrict__ out) {
    __shared__ u16 th[256 * 68];
    __shared__ float al[256];
    int n = blockIdx.x >> 6, p = blockIdx.x & 63;
    int t = threadIdx.x;
    al[t] = a[n * 256 + t];
    __syncthreads();
    int o8 = (t & 31) << 3, qr = t >> 5;
    int pixbase = n * 4096 + p * 64;
#pragma unroll
    for (int qi = 0; qi < 8; ++qi) {
        int q = qi * 8 + qr;
        int gi = (pixbase + q) * 256 + o8;
        u16x8 hv = *(const u16x8*)(h2 + gi);
        u16x8 rv = *(const u16x8*)(res + gi);
#pragma unroll
        for (int k = 0; k < 8; ++k) {
            float vv = bf2f(hv[k]) * al[o8 + k] + bf2f(rv[k]);
            th[(o8 + k) * 68 + q] = f2bf(vv);
        }
    }
    __syncthreads();
    int q4 = (t & 15) << 2, ob = t >> 4;
#pragma unroll
    for (int oi = 0; oi < 16; ++oi) {
        int o = oi * 16 + ob;
        float4 vv;
        vv.x = bf2f(th[o * 68 + q4 + 0]);
        vv.y = bf2f(th[o * 68 + q4 + 1]);
        vv.z = bf2f(th[o * 68 + q4 + 2]);
        vv.w = bf2f(th[o * 68 + q4 + 3]);
        *(float4*)(out + ((n * 256 + o) * 64 + p) * 64 + q4) = vv;
    }
}

// ---------------------------------------------------------------------------
// workspace layout (bytes)
// ---------------------------------------------------------------------------
static const size_t OFF_PRE  = 0;                       // 68,161,536 ; reused for h2
static const size_t OFF_H1   = 68161536;                // 35,684,352
static const size_t OFF_RES  = 103845888;               // 33,554,432
static const size_t OFF_W1T  = 137400320;               // 589,824
static const size_t OFF_W2T  = 137990144;               // 1,179,648
static const size_t OFF_WRT  = 139169792;               // 65,536
static const size_t OFF_B2F  = 139235328;               // 1,024
static const size_t OFF_PART = 139236352;               // 524,288
static const size_t OFF_A    = 139760640;               // 16,384

extern "C" void kernel_launch(void* const* d_in, const int* in_sizes, int n_in,
                              void* d_out, int out_size, void* d_ws, size_t ws_size,
                              hipStream_t stream) {
    (void)in_sizes; (void)n_in; (void)out_size; (void)ws_size;
    const float* x      = (const float*)d_in[0];
    const float* bn1_g  = (const float*)d_in[1];
    const float* bn1_b  = (const float*)d_in[2];
    const float* bn1_m  = (const float*)d_in[3];
    const float* bn1_v  = (const float*)d_in[4];
    const float* bn2_g  = (const float*)d_in[5];
    const float* bn2_b  = (const float*)d_in[6];
    const float* bn2_m  = (const float*)d_in[7];
    const float* bn2_v  = (const float*)d_in[8];
    const float* wc1    = (const float*)d_in[9];
    const float* wc2    = (const float*)d_in[10];
    const float* wres   = (const float*)d_in[11];
    const float* se_w1  = (const float*)d_in[12];
    const float* se_b1  = (const float*)d_in[13];
    const float* se_w2  = (const float*)d_in[14];
    const float* se_b2  = (const float*)d_in[15];

    char* ws = (char*)d_ws;
    u16*   pre    = (u16*)(ws + OFF_PRE);
    u16*   h2     = (u16*)(ws + OFF_PRE);   // aliases pre (dead by conv2)
    u16*   h1     = (u16*)(ws + OFF_H1);
    u16*   res    = (u16*)(ws + OFF_RES);
    u16*   w1t    = (u16*)(ws + OFF_W1T);
    u16*   w2t    = (u16*)(ws + OFF_W2T);
    u16*   wrt    = (u16*)(ws + OFF_WRT);
    float* bias2f = (float*)(ws + OFF_B2F);
    float* part   = (float*)(ws + OFF_PART);
    float* avec   = (float*)(ws + OFF_A);
    float* out    = (float*)d_out;

    prep_weights<<<3585, 256, 0, stream>>>(wc1, wc2, wres, bn2_g, bn2_b, bn2_m, bn2_v,
                                           w1t, w2t, wrt, bias2f);
    zero_pre_pad<<<2056, 256, 0, stream>>>(pre);
    zero_h1_pad<<<4160, 256, 0, stream>>>(h1);
    pre_kernel<<<2048, 256, 0, stream>>>(x, bn1_g, bn1_b, bn1_m, bn1_v, pre);

    // conv1: 3x3 s2, 128->256, +BN2(bias)+ReLU, out = padded h1 (base (1,1))
    conv_8ph<128, 9, 2, true><<<256, 512, 0, stream>>>(
        pre, w1t, bias2f, h1,
        129 * 128, 129 * 129 * 128,
        67 * 256, 66 * 256, 66 * 66 * 256);

    // residual: 1x1 s2, 128->256 (old small-tile kernel)
    conv_mfma<128, 1, 2, false><<<1024, 256, 0, stream>>>(
        pre, wrt, nullptr, res,
        129 * 128, 129 * 129 * 128,
        0, 64 * 256, 4096 * 256);

    // conv2: 3x3 s1, 256->256 (h2 overwrites pre region)
    conv_8ph<256, 9, 1, false><<<256, 512, 0, stream>>>(
        h1, w2t, nullptr, h2,
        66 * 256, 66 * 66 * 256,
        0, 64 * 256, 4096 * 256);

    pool_kernel<<<512, 256, 0, stream>>>(h2, part);
    se_kernel<<<1, 256, 0, stream>>>(part, se_w1, se_b1, se_w2, se_b2, avec);
    finalize_kernel<<<1024, 256, 0, stream>>>(h2, res, avec, out);
}

// Round 3
// 272.525 us; speedup vs baseline: 1.1950x; 1.0626x over previous
//
#include <hip/hip_runtime.h>

typedef unsigned short u16;
typedef __attribute__((ext_vector_type(8))) unsigned short u16x8;
typedef __attribute__((ext_vector_type(8))) __bf16 bf16x8;
typedef __attribute__((ext_vector_type(4))) float f32x4;

__device__ __forceinline__ float bf2f(u16 u) {
    return __uint_as_float(((unsigned)u) << 16);
}
__device__ __forceinline__ u16 f2bf(float f) {
    unsigned u = __float_as_uint(f);
    return (u16)((u + 0x7FFFu + ((u >> 16) & 1u)) >> 16);
}

// ---------------------------------------------------------------------------
// K0: weight transform.  w1t[tap][o][ci] = w_conv1[o][ci][dy][dx]*scale2[o]
//     w2t[tap][o][ci] = w_conv2[o][ci][dy][dx];  wrt[o][ci] = w_res[o][ci]
//     bias2f[o] = b2 - m2*scale2
// ---------------------------------------------------------------------------
__global__ void prep_weights(const float* __restrict__ w1, const float* __restrict__ w2,
                             const float* __restrict__ wr,
                             const float* __restrict__ g2, const float* __restrict__ b2,
                             const float* __restrict__ m2, const float* __restrict__ v2,
                             u16* __restrict__ w1t, u16* __restrict__ w2t,
                             u16* __restrict__ wrt, float* __restrict__ bias2f) {
    int i = blockIdx.x * 256 + threadIdx.x;
    if (i < 294912) {
        int ci = i & 127; int t = i >> 7; int o = t & 255; int tap = t >> 8;
        int dy = tap / 3, dx = tap - dy * 3;
        float sc = g2[o] * rsqrtf(v2[o] + 1e-5f);
        w1t[i] = f2bf(w1[((o * 128 + ci) * 3 + dy) * 3 + dx] * sc);
    } else if (i < 294912 + 589824) {
        int j = i - 294912;
        int ci = j & 255; int t = j >> 8; int o = t & 255; int tap = t >> 8;
        int dy = tap / 3, dx = tap - dy * 3;
        w2t[j] = f2bf(w2[((o * 256 + ci) * 3 + dy) * 3 + dx]);
    } else if (i < 294912 + 589824 + 32768) {
        int j = i - (294912 + 589824);
        int ci = j & 127; int o = j >> 7;
        wrt[j] = f2bf(wr[o * 128 + ci]);
    } else {
        int o = i - (294912 + 589824 + 32768);
        if (o < 256) {
            float sc = g2[o] * rsqrtf(v2[o] + 1e-5f);
            bias2f[o] = b2[o] - m2[o] * sc;
        }
    }
}

// ---------------------------------------------------------------------------
// zero pad borders of pre [16][129][129][128] : row y=128 and col x=128
// ---------------------------------------------------------------------------
__global__ void zero_pre_pad(u16* __restrict__ pre) {
    int i = blockIdx.x * 256 + threadIdx.x;
    if (i < 16 * 129 * 128) {
        int c = i & 127; int t = i >> 7; int n = t / 129; int xx = t - n * 129;
        pre[((n * 129 + 128) * 129 + xx) * 128 + c] = 0;
    } else {
        int j = i - 16 * 129 * 128;
        int c = j & 127; int t = j >> 7; int n = t >> 7; int y = t & 127;
        pre[((n * 129 + y) * 129 + 128) * 128 + c] = 0;
    }
}

// ---------------------------------------------------------------------------
// zero pad borders of h1 [16][66][66][256]
// ---------------------------------------------------------------------------
__global__ void zero_h1_pad(u16* __restrict__ h1) {
    int i = blockIdx.x * 256 + threadIdx.x;
    int c = i & 255;
    int t = i >> 8;
    int n = t / 260;
    int cl = t - n * 260;
    int y, x;
    if (cl < 66)       { y = 0;        x = cl; }
    else if (cl < 132) { y = 65;       x = cl - 66; }
    else if (cl < 196) { x = 0;        y = cl - 131; }
    else               { x = 65;       y = cl - 195; }
    h1[((n * 66 + y) * 66 + x) * 256 + c] = 0;
}

// ---------------------------------------------------------------------------
// K1: pre = relu(BN1(x)), NCHW f32 -> padded NHWC bf16 (interior only)
// ---------------------------------------------------------------------------
__global__ void pre_kernel(const float* __restrict__ x, const float* __restrict__ g,
                           const float* __restrict__ b, const float* __restrict__ m,
                           const float* __restrict__ v, u16* __restrict__ pre) {
    __shared__ u16 tile[128 * 136];
    int n = blockIdx.x >> 7, y = blockIdx.x & 127;
    int tid = threadIdx.x;
    int c = tid >> 1, xh = (tid & 1) << 6;
    float sc = g[c] * rsqrtf(v[c] + 1e-5f);
    float bi = b[c] - m[c] * sc;
    const float4* src = (const float4*)(x + (((n * 128 + c) * 128 + y) << 7) + xh);
#pragma unroll
    for (int j = 0; j < 16; ++j) {
        float4 val = src[j];
        int xb = xh + j * 4;
        tile[(xb + 0) * 136 + c] = f2bf(fmaxf(val.x * sc + bi, 0.f));
        tile[(xb + 1) * 136 + c] = f2bf(fmaxf(val.y * sc + bi, 0.f));
        tile[(xb + 2) * 136 + c] = f2bf(fmaxf(val.z * sc + bi, 0.f));
        tile[(xb + 3) * 136 + c] = f2bf(fmaxf(val.w * sc + bi, 0.f));
    }
    __syncthreads();
    int c0 = (tid & 15) << 3;
#pragma unroll
    for (int xi = 0; xi < 8; ++xi) {
        int xx = xi * 16 + (tid >> 4);
        u16x8 val = *(const u16x8*)&tile[xx * 136 + c0];
        *(u16x8*)(pre + ((n * 129 + y) * 129 + xx) * 128 + c0) = val;
    }
}

// ===========================================================================
// 8-phase 256x256 implicit-GEMM conv (T2+T3+T4+T5) with Gray-code operand
// reuse: per K-tile quadrant order (0,0)->(0,1)->(1,1)->(1,0); ds_reads per
// wave per K-tile = 24 b128 (minimum) instead of 48.
//   BM=256 pixels, BN=256 out-ch, BK=64, 8 waves (2x4), 512 threads
//   Staging: q0:A1(t+1)  q1:B1(t+1)  q2:A0(t+2)  q3:B0(t+2); vmcnt(4)/tile.
//   T2 swizzle: lds byte col ^= ((row&7)<<4) via inverse-swizzled global src.
// ===========================================================================
template <int CIN, int NTAPS, int STRIDE, bool BIASRELU>
__global__ __launch_bounds__(512, 2)
void conv_8ph(const u16* __restrict__ in, const u16* __restrict__ wt,
              const float* __restrict__ bias, u16* __restrict__ out,
              int in_row, int in_img, int out_base, int out_row, int out_img) {
    constexpr int CSTEPS = CIN / 64;
    constexpr int KT = CSTEPS * NTAPS;
    __shared__ __attribute__((aligned(16))) u16 lds[65536];  // A: [0,32768), B: [32768,65536)

    const int tid = threadIdx.x;
    const int w = tid >> 6, l = tid & 63;
    const int wm = w >> 2, wn = w & 3;
    const int l15 = l & 15;
    const int Mbase = blockIdx.x << 8;

    // ---- staging per-thread constants (inverse-swizzled source chunk) ----
    const int srow = tid >> 3;                               // row within 64-row round
    const int swze = (((tid & 7) ^ (srow & 7)) << 3);        // u16 offset of 16B chunk
    int pix0 = Mbase + srow;
    int nn0 = pix0 >> 12, p0 = (pix0 >> 6) & 63, q0 = pix0 & 63;
    const int abase0 = nn0 * in_img + (STRIDE * p0) * in_row + (STRIDE * q0) * CIN + swze;
    const int astep = STRIDE * in_row;    // +64 pixels = +1 p-row (block is p-aligned)
    const int bbase0 = srow * CIN + swze;
    const int bstep = 64 * CIN;

    // ---- swizzled ds_read column offsets (u16 units) ----
    int colw[2];
#pragma unroll
    for (int kk = 0; kk < 2; ++kk)
        colw[kk] = (kk * 32 + (l >> 4) * 8) ^ ((l & 7) << 3);

    f32x4 acc[8][4] = {};
    bf16x8 afr[4][2], b0f[2][2], b1f[2][2];

#define AOFF(ks) (((NTAPS == 9) ? ((((ks) / CSTEPS) / 3) * in_row + (((ks) / CSTEPS) % 3) * CIN) : 0) + ((ks) % CSTEPS) * 64)
#define BOFF(ks) (((ks) / CSTEPS) * 256 * CIN + ((ks) % CSTEPS) * 64)
#define GLDS(gsrc, ldst) __builtin_amdgcn_global_load_lds(                          \
        (__attribute__((address_space(1))) void*)(gsrc),                            \
        (__attribute__((address_space(3))) void*)(ldst), 16, 0, 0)
#define STAGE_A(h, ks) {                                                            \
    int _ao = AOFF(ks); int _tb = (ks) & 1;                                         \
    GLDS(in + abase0 + (2 * (h) + 0) * astep + _ao,                                 \
         &lds[_tb * 16384 + (h) * 8192 + 0 * 4096 + w * 512]);                      \
    GLDS(in + abase0 + (2 * (h) + 1) * astep + _ao,                                 \
         &lds[_tb * 16384 + (h) * 8192 + 1 * 4096 + w * 512]); }
#define STAGE_B(h, ks) {                                                            \
    int _bo = BOFF(ks); int _tb = (ks) & 1;                                         \
    GLDS(wt + bbase0 + (2 * (h) + 0) * bstep + _bo,                                 \
         &lds[32768 + _tb * 16384 + (h) * 8192 + 0 * 4096 + w * 512]);              \
    GLDS(wt + bbase0 + (2 * (h) + 1) * bstep + _bo,                                 \
         &lds[32768 + _tb * 16384 + (h) * 8192 + 1 * 4096 + w * 512]); }
#define BARRIER() { __builtin_amdgcn_s_barrier(); asm volatile("" ::: "memory"); }
#define LDA(MH) {                                                                   \
    _Pragma("unroll") for (int fm = 0; fm < 4; ++fm)                                \
    _Pragma("unroll") for (int kk = 0; kk < 2; ++kk)                                \
        afr[fm][kk] = *(const bf16x8*)&lds[Ab + ((MH) * 128 + wm * 64 + fm * 16 + l15) * 64 + colw[kk]]; }
#define LDB(NH, dst) {                                                              \
    _Pragma("unroll") for (int gn = 0; gn < 2; ++gn)                                \
    _Pragma("unroll") for (int kk = 0; kk < 2; ++kk)                                \
        dst[gn][kk] = *(const bf16x8*)&lds[Bb + ((NH) * 128 + gn * 64 + wn * 16 + l15) * 64 + colw[kk]]; }
#define MFMA_Q(MH, NH, bset) {                                                      \
    _Pragma("unroll") for (int fm = 0; fm < 4; ++fm)                                \
    _Pragma("unroll") for (int gn = 0; gn < 2; ++gn)                                \
    _Pragma("unroll") for (int kk = 0; kk < 2; ++kk)                                \
        acc[(MH) * 4 + fm][(NH) * 2 + gn] = __builtin_amdgcn_mfma_f32_16x16x32_bf16( \
            afr[fm][kk], bset[gn][kk], acc[(MH) * 4 + fm][(NH) * 2 + gn], 0, 0, 0); }
#define LGK0() asm volatile("s_waitcnt lgkmcnt(0)" ::: "memory")

    // ---- prologue: stage tile0 fully + tile1 first halves; wait tile0 ----
    STAGE_A(0, 0); STAGE_B(0, 0); STAGE_A(1, 0); STAGE_B(1, 0);
    STAGE_A(0, 1); STAGE_B(0, 1);
    asm volatile("s_waitcnt vmcnt(4)" ::: "memory");
    BARRIER();

    // ---- steady loop: t in [0, KT-2) ----
#pragma unroll 2
    for (int t = 0; t < KT - 2; ++t) {
        const int Ab = (t & 1) * 16384;
        const int Bb = 32768 + (t & 1) * 16384;
        // ph0: quadrant (0,0) -- read A0 + B0
        LDA(0); LDB(0, b0f);
        STAGE_A(1, t + 1);
        __builtin_amdgcn_s_barrier();
        LGK0();
        __builtin_amdgcn_s_setprio(1);
        MFMA_Q(0, 0, b0f);
        __builtin_amdgcn_s_setprio(0);
        BARRIER();
        // ph1: quadrant (0,1) -- read B1, reuse A0
        LDB(1, b1f);
        STAGE_B(1, t + 1);
        __builtin_amdgcn_s_barrier();
        LGK0();
        __builtin_amdgcn_s_setprio(1);
        MFMA_Q(0, 1, b1f);
        __builtin_amdgcn_s_setprio(0);
        BARRIER();
        // ph2: quadrant (1,1) -- read A1, reuse B1
        LDA(1);
        STAGE_A(0, t + 2);
        __builtin_amdgcn_s_barrier();
        LGK0();
        __builtin_amdgcn_s_setprio(1);
        MFMA_Q(1, 1, b1f);
        __builtin_amdgcn_s_setprio(0);
        BARRIER();
        // ph3: quadrant (1,0) -- reuse A1 + B0; boundary vmcnt
        STAGE_B(0, t + 2);
        __builtin_amdgcn_s_barrier();
        __builtin_amdgcn_s_setprio(1);
        MFMA_Q(1, 0, b0f);
        __builtin_amdgcn_s_setprio(0);
        asm volatile("s_waitcnt vmcnt(4)" ::: "memory");
        BARRIER();
    }

    // ---- tail tile KT-2: stage only A1/B1(KT-1); drain vmcnt ----
    {
        const int Ab = ((KT - 2) & 1) * 16384;
        const int Bb = 32768 + ((KT - 2) & 1) * 16384;
        LDA(0); LDB(0, b0f);
        STAGE_A(1, KT - 1);
        __builtin_amdgcn_s_barrier();
        LGK0();
        __builtin_amdgcn_s_setprio(1);
        MFMA_Q(0, 0, b0f);
        __builtin_amdgcn_s_setprio(0);
        BARRIER();
        LDB(1, b1f);
        STAGE_B(1, KT - 1);
        __builtin_amdgcn_s_barrier();
        LGK0();
        __builtin_amdgcn_s_setprio(1);
        MFMA_Q(0, 1, b1f);
        __builtin_amdgcn_s_setprio(0);
        BARRIER();
        LDA(1);
        __builtin_amdgcn_s_barrier();
        LGK0();
        __builtin_amdgcn_s_setprio(1);
        MFMA_Q(1, 1, b1f);
        __builtin_amdgcn_s_setprio(0);
        BARRIER();
        __builtin_amdgcn_s_barrier();
        __builtin_amdgcn_s_setprio(1);
        MFMA_Q(1, 0, b0f);
        __builtin_amdgcn_s_setprio(0);
        asm volatile("s_waitcnt vmcnt(0)" ::: "memory");
        BARRIER();
    }
    // ---- tail tile KT-1: fully resident; no barriers/staging needed ----
    {
        const int Ab = ((KT - 1) & 1) * 16384;
        const int Bb = 32768 + ((KT - 1) & 1) * 16384;
        LDA(0); LDB(0, b0f); LDB(1, b1f);
        MFMA_Q(0, 0, b0f);
        MFMA_Q(0, 1, b1f);
        LDA(1);
        MFMA_Q(1, 1, b1f);
        MFMA_Q(1, 0, b0f);
    }
#undef AOFF
#undef BOFF
#undef GLDS
#undef STAGE_A
#undef STAGE_B
#undef BARRIER
#undef LDA
#undef LDB
#undef MFMA_Q
#undef LGK0

    // ---- epilogue: C frag (col=lane&15 -> o, row=(lane>>4)*4+j -> pixel) ----
#pragma unroll
    for (int f = 0; f < 8; ++f) {
        const int prow = (f >> 2) * 128 + wm * 64 + (f & 3) * 16 + ((l >> 4) << 2);
#pragma unroll
        for (int g = 0; g < 4; ++g) {
            const int o = (g >> 1) * 128 + (g & 1) * 64 + wn * 16 + l15;
            float bb = 0.f;
            if (BIASRELU) bb = bias[o];
#pragma unroll
            for (int j = 0; j < 4; ++j) {
                int pix = Mbase + prow + j;
                int nn = pix >> 12, p = (pix >> 6) & 63, q = pix & 63;
                float val = acc[f][g][j] + bb;
                if (BIASRELU) val = fmaxf(val, 0.f);
                out[out_base + nn * out_img + p * out_row + q * 256 + o] = f2bf(val);
            }
        }
    }
}

// ---------------------------------------------------------------------------
// old 128x128 2-phase conv (kept for the tiny 1x1 residual conv, K=128)
// ---------------------------------------------------------------------------
template <int CIN, int NTAPS, int STRIDE, bool BIASRELU>
__global__ __launch_bounds__(256, 2)
void conv_mfma(const u16* __restrict__ in, const u16* __restrict__ wt,
               const float* __restrict__ bias, u16* __restrict__ out,
               int in_row, int in_img, int out_base, int out_row, int out_img) {
    constexpr int CSTEPS = CIN / 64;
    constexpr int KSTEPS = CSTEPS * NTAPS;
    __shared__ u16 lA[128 * 64];
    __shared__ u16 lB[128 * 64];

    const int tid = threadIdx.x;
    const int w = tid >> 6, l = tid & 63;
    const int bn = blockIdx.x & 1;
    const int Mbase = (blockIdx.x >> 1) << 7;
    const int wm = w >> 1, wn = w & 1;
    const int srow = l >> 3;
    const int chunk = l & 7;

    int abase[4], wbase[4];
#pragma unroll
    for (int i = 0; i < 4; ++i) {
        int pix = w * 32 + i * 8 + srow;
        int mm = Mbase + pix;
        int nn = mm >> 12, p = (mm >> 6) & 63, q = mm & 63;
        abase[i] = nn * in_img + (STRIDE * p) * in_row + (STRIDE * q) * CIN + chunk * 8;
        wbase[i] = (bn * 128 + pix) * CIN + chunk * 8;
    }

    f32x4 acc[4][4] = {};

    int abyte[4], bbyte[4];
#pragma unroll
    for (int f = 0; f < 4; ++f) {
        abyte[f] = ((wm * 64 + f * 16 + (l & 15)) * 64 + ((l >> 4) * 8)) * 2;
        bbyte[f] = ((wn * 64 + f * 16 + (l & 15)) * 64 + ((l >> 4) * 8)) * 2;
    }

    for (int ks = 0; ks < KSTEPS; ++ks) {
        const int tap = ks / CSTEPS;
        const int c0 = (ks % CSTEPS) * 64;
        const int dy = (NTAPS == 9) ? (tap / 3) : 0;
        const int dx = (NTAPS == 9) ? (tap - dy * 3) : 0;
        const int aoff = dy * in_row + dx * CIN + c0;
        const int boff = tap * 256 * CIN + c0;
        __syncthreads();
#pragma unroll
        for (int i = 0; i < 4; ++i) {
            const u16* gsrc = in + abase[i] + aoff;
            u16* ldst = &lA[(w * 32 + i * 8) * 64];
            __builtin_amdgcn_global_load_lds((__attribute__((address_space(1))) void*)gsrc,
                                             (__attribute__((address_space(3))) void*)ldst,
                                             16, 0, 0);
        }
#pragma unroll
        for (int i = 0; i < 4; ++i) {
            const u16* gsrc = wt + wbase[i] + boff;
            u16* ldst = &lB[(w * 32 + i * 8) * 64];
            __builtin_amdgcn_global_load_lds((__attribute__((address_space(1))) void*)gsrc,
                                             (__attribute__((address_space(3))) void*)ldst,
                                             16, 0, 0);
        }
        __syncthreads();
#pragma unroll
        for (int kk = 0; kk < 2; ++kk) {
            bf16x8 af[4], bv[4];
#pragma unroll
            for (int f = 0; f < 4; ++f)
                af[f] = *(const bf16x8*)((const char*)lA + abyte[f] + kk * 64);
#pragma unroll
            for (int f = 0; f < 4; ++f)
                bv[f] = *(const bf16x8*)((const char*)lB + bbyte[f] + kk * 64);
#pragma unroll
            for (int fm = 0; fm < 4; ++fm)
#pragma unroll
                for (int fn = 0; fn < 4; ++fn)
                    acc[fm][fn] = __builtin_amdgcn_mfma_f32_16x16x32_bf16(
                        af[fm], bv[fn], acc[fm][fn], 0, 0, 0);
        }
    }

#pragma unroll
    for (int fm = 0; fm < 4; ++fm) {
        const int mloc = wm * 64 + fm * 16 + ((l >> 4) << 2);
#pragma unroll
        for (int fn = 0; fn < 4; ++fn) {
            const int o = bn * 128 + wn * 64 + fn * 16 + (l & 15);
            float bb = 0.f;
            if (BIASRELU) bb = bias[o];
#pragma unroll
            for (int j = 0; j < 4; ++j) {
                int mm = Mbase + mloc + j;
                int nn = mm >> 12, p = (mm >> 6) & 63, q = mm & 63;
                float val = acc[fm][fn][j] + bb;
                if (BIASRELU) val = fmaxf(val, 0.f);
                out[out_base + nn * out_img + p * out_row + q * 256 + o] = f2bf(val);
            }
        }
    }
}

// ---------------------------------------------------------------------------
// SE pooling stage 1 (vectorized): partial[n][pc][o] = sum over 128 pixels
// thread t: channel octet (t&31)*8, pixel lane t>>5 (strided over 128 pixels)
// ---------------------------------------------------------------------------
__global__ void pool_kernel(const u16* __restrict__ h2, float* __restrict__ partial) {
    __shared__ float sm[256 * 9];
    int n = blockIdx.x >> 5, pc = blockIdx.x & 31;
    int t = threadIdx.x;
    int o8 = (t & 31) << 3, pl = t >> 5;
    const u16* base = h2 + (n * 4096 + pc * 128 + pl) * 256 + o8;
    float s[8] = {};
#pragma unroll
    for (int k = 0; k < 16; ++k) {
        u16x8 v = *(const u16x8*)(base + k * 8 * 256);
#pragma unroll
        for (int j = 0; j < 8; ++j) s[j] += bf2f(v[j]);
    }
#pragma unroll
    for (int j = 0; j < 8; ++j) sm[(o8 + j) * 9 + pl] = s[j];
    __syncthreads();
    float r = 0.f;
#pragma unroll
    for (int p = 0; p < 8; ++p) r += sm[t * 9 + p];
    partial[(n * 32 + pc) * 256 + t] = r;
}

// ---------------------------------------------------------------------------
// SE MLP: a = sigmoid(relu(mean @ w1^T + b1) @ w2^T + b2)
// ---------------------------------------------------------------------------
__global__ void se_kernel(const float* __restrict__ partial,
                          const float* __restrict__ w1, const float* __restrict__ b1,
                          const float* __restrict__ w2, const float* __restrict__ b2,
                          float* __restrict__ a) {
    __shared__ float sm[16 * 256];
    __shared__ float hl[16 * 16];
    int t = threadIdx.x;
    for (int n = 0; n < 16; ++n) {
        float s = 0.f;
        for (int pc = 0; pc < 32; ++pc) s += partial[(n * 32 + pc) * 256 + t];
        sm[n * 256 + t] = s * (1.0f / 4096.0f);
    }
    __syncthreads();
    {
        int bb = t >> 4, j = t & 15;
        float d = b1[j];
        for (int c = 0; c < 256; ++c) d += sm[bb * 256 + c] * w1[j * 256 + c];
        hl[bb * 16 + j] = fmaxf(d, 0.f);
    }
    __syncthreads();
    {
        int o = t;
        for (int bb = 0; bb < 16; ++bb) {
            float z = b2[o];
            for (int j = 0; j < 16; ++j) z += hl[bb * 16 + j] * w2[o * 16 + j];
            a[bb * 256 + o] = 1.0f / (1.0f + expf(-z));
        }
    }
}

// ---------------------------------------------------------------------------
// K5: out[n][o][p][q] = h2[n][p][q][o]*a[n][o] + res[n][p][q][o]
// ---------------------------------------------------------------------------
__global__ void finalize_kernel(const u16* __restrict__ h2, const u16* __restrict__ res,
                                const float* __restrict__ a, float* __restrict__ out) {
    __shared__ u16 th[256 * 68];
    __shared__ float al[256];
    int n = blockIdx.x >> 6, p = blockIdx.x & 63;
    int t = threadIdx.x;
    al[t] = a[n * 256 + t];
    __syncthreads();
    int o8 = (t & 31) << 3, qr = t >> 5;
    int pixbase = n * 4096 + p * 64;
#pragma unroll
    for (int qi = 0; qi < 8; ++qi) {
        int q = qi * 8 + qr;
        int gi = (pixbase + q) * 256 + o8;
        u16x8 hv = *(const u16x8*)(h2 + gi);
        u16x8 rv = *(const u16x8*)(res + gi);
#pragma unroll
        for (int k = 0; k < 8; ++k) {
            float vv = bf2f(hv[k]) * al[o8 + k] + bf2f(rv[k]);
            th[(o8 + k) * 68 + q] = f2bf(vv);
        }
    }
    __syncthreads();
    int q4 = (t & 15) << 2, ob = t >> 4;
#pragma unroll
    for (int oi = 0; oi < 16; ++oi) {
        int o = oi * 16 + ob;
        float4 vv;
        vv.x = bf2f(th[o * 68 + q4 + 0]);
        vv.y = bf2f(th[o * 68 + q4 + 1]);
        vv.z = bf2f(th[o * 68 + q4 + 2]);
        vv.w = bf2f(th[o * 68 + q4 + 3]);
        *(float4*)(out + ((n * 256 + o) * 64 + p) * 64 + q4) = vv;
    }
}

// ---------------------------------------------------------------------------
// workspace layout (bytes)
// ---------------------------------------------------------------------------
static const size_t OFF_PRE  = 0;                       // 68,161,536 ; reused for h2
static const size_t OFF_H1   = 68161536;                // 35,684,352
static const size_t OFF_RES  = 103845888;               // 33,554,432
static const size_t OFF_W1T  = 137400320;               // 589,824
static const size_t OFF_W2T  = 137990144;               // 1,179,648
static const size_t OFF_WRT  = 139169792;               // 65,536
static const size_t OFF_B2F  = 139235328;               // 1,024
static const size_t OFF_PART = 139236352;               // 524,288
static const size_t OFF_A    = 139760640;               // 16,384

extern "C" void kernel_launch(void* const* d_in, const int* in_sizes, int n_in,
                              void* d_out, int out_size, void* d_ws, size_t ws_size,
                              hipStream_t stream) {
    (void)in_sizes; (void)n_in; (void)out_size; (void)ws_size;
    const float* x      = (const float*)d_in[0];
    const float* bn1_g  = (const float*)d_in[1];
    const float* bn1_b  = (const float*)d_in[2];
    const float* bn1_m  = (const float*)d_in[3];
    const float* bn1_v  = (const float*)d_in[4];
    const float* bn2_g  = (const float*)d_in[5];
    const float* bn2_b  = (const float*)d_in[6];
    const float* bn2_m  = (const float*)d_in[7];
    const float* bn2_v  = (const float*)d_in[8];
    const float* wc1    = (const float*)d_in[9];
    const float* wc2    = (const float*)d_in[10];
    const float* wres   = (const float*)d_in[11];
    const float* se_w1  = (const float*)d_in[12];
    const float* se_b1  = (const float*)d_in[13];
    const float* se_w2  = (const float*)d_in[14];
    const float* se_b2  = (const float*)d_in[15];

    char* ws = (char*)d_ws;
    u16*   pre    = (u16*)(ws + OFF_PRE);
    u16*   h2     = (u16*)(ws + OFF_PRE);   // aliases pre (dead by conv2)
    u16*   h1     = (u16*)(ws + OFF_H1);
    u16*   res    = (u16*)(ws + OFF_RES);
    u16*   w1t    = (u16*)(ws + OFF_W1T);
    u16*   w2t    = (u16*)(ws + OFF_W2T);
    u16*   wrt    = (u16*)(ws + OFF_WRT);
    float* bias2f = (float*)(ws + OFF_B2F);
    float* part   = (float*)(ws + OFF_PART);
    float* avec   = (float*)(ws + OFF_A);
    float* out    = (float*)d_out;

    prep_weights<<<3585, 256, 0, stream>>>(wc1, wc2, wres, bn2_g, bn2_b, bn2_m, bn2_v,
                                           w1t, w2t, wrt, bias2f);
    zero_pre_pad<<<2056, 256, 0, stream>>>(pre);
    zero_h1_pad<<<4160, 256, 0, stream>>>(h1);
    pre_kernel<<<2048, 256, 0, stream>>>(x, bn1_g, bn1_b, bn1_m, bn1_v, pre);

    // conv1: 3x3 s2, 128->256, +BN2(bias)+ReLU, out = padded h1 (base (1,1))
    conv_8ph<128, 9, 2, true><<<256, 512, 0, stream>>>(
        pre, w1t, bias2f, h1,
        129 * 128, 129 * 129 * 128,
        67 * 256, 66 * 256, 66 * 66 * 256);

    // residual: 1x1 s2, 128->256 (old small-tile kernel)
    conv_mfma<128, 1, 2, false><<<1024, 256, 0, stream>>>(
        pre, wrt, nullptr, res,
        129 * 128, 129 * 129 * 128,
        0, 64 * 256, 4096 * 256);

    // conv2: 3x3 s1, 256->256 (h2 overwrites pre region)
    conv_8ph<256, 9, 1, false><<<256, 512, 0, stream>>>(
        h1, w2t, nullptr, h2,
        66 * 256, 66 * 66 * 256,
        0, 64 * 256, 4096 * 256);

    pool_kernel<<<512, 256, 0, stream>>>(h2, part);
    se_kernel<<<1, 256, 0, stream>>>(part, se_w1, se_b1, se_w2, se_b2, avec);
    finalize_kernel<<<1024, 256, 0, stream>>>(h2, res, avec, out);
}

// Round 4
// 216.747 us; speedup vs baseline: 1.5025x; 1.2573x over previous
//
#include <hip/hip_runtime.h>

typedef unsigned short u16;
typedef __attribute__((ext_vector_type(8))) unsigned short u16x8;
typedef __attribute__((ext_vector_type(8))) __bf16 bf16x8;
typedef __attribute__((ext_vector_type(4))) float f32x4;

__device__ __forceinline__ float bf2f(u16 u) {
    return __uint_as_float(((unsigned)u) << 16);
}
__device__ __forceinline__ u16 f2bf(float f) {
    unsigned u = __float_as_uint(f);
    return (u16)((u + 0x7FFFu + ((u >> 16) & 1u)) >> 16);
}

// ---------------------------------------------------------------------------
// setup kernel: weight transform + pad zeroing, one launch.
//   blocks [0,3585): prep weights; [3585,5641): zero pre pad; [5641,9801): h1 pad
// ---------------------------------------------------------------------------
__global__ void setup_kernel(const float* __restrict__ w1, const float* __restrict__ w2,
                             const float* __restrict__ wr,
                             const float* __restrict__ g2, const float* __restrict__ b2,
                             const float* __restrict__ m2, const float* __restrict__ v2,
                             u16* __restrict__ w1t, u16* __restrict__ w2t,
                             u16* __restrict__ wrt, float* __restrict__ bias2f,
                             u16* __restrict__ pre, u16* __restrict__ h1) {
    int b = blockIdx.x;
    if (b < 3585) {
        int i = b * 256 + threadIdx.x;
        if (i < 294912) {
            int ci = i & 127; int t = i >> 7; int o = t & 255; int tap = t >> 8;
            int dy = tap / 3, dx = tap - dy * 3;
            float sc = g2[o] * rsqrtf(v2[o] + 1e-5f);
            w1t[i] = f2bf(w1[((o * 128 + ci) * 3 + dy) * 3 + dx] * sc);
        } else if (i < 294912 + 589824) {
            int j = i - 294912;
            int ci = j & 255; int t = j >> 8; int o = t & 255; int tap = t >> 8;
            int dy = tap / 3, dx = tap - dy * 3;
            w2t[j] = f2bf(w2[((o * 256 + ci) * 3 + dy) * 3 + dx]);
        } else if (i < 294912 + 589824 + 32768) {
            int j = i - (294912 + 589824);
            int ci = j & 127; int o = j >> 7;
            wrt[j] = f2bf(wr[o * 128 + ci]);
        } else {
            int o = i - (294912 + 589824 + 32768);
            if (o < 256) {
                float sc = g2[o] * rsqrtf(v2[o] + 1e-5f);
                bias2f[o] = b2[o] - m2[o] * sc;
            }
        }
    } else if (b < 3585 + 2056) {
        int i = (b - 3585) * 256 + threadIdx.x;
        if (i < 16 * 129 * 128) {
            int c = i & 127; int t = i >> 7; int n = t / 129; int xx = t - n * 129;
            pre[((n * 129 + 128) * 129 + xx) * 128 + c] = 0;
        } else {
            int j = i - 16 * 129 * 128;
            int c = j & 127; int t = j >> 7; int n = t >> 7; int y = t & 127;
            pre[((n * 129 + y) * 129 + 128) * 128 + c] = 0;
        }
    } else {
        int i = (b - (3585 + 2056)) * 256 + threadIdx.x;
        int c = i & 255;
        int t = i >> 8;
        int n = t / 260;
        int cl = t - n * 260;
        int y, x;
        if (cl < 66)       { y = 0;  x = cl; }
        else if (cl < 132) { y = 65; x = cl - 66; }
        else if (cl < 196) { x = 0;  y = cl - 131; }
        else               { x = 65; y = cl - 195; }
        h1[((n * 66 + y) * 66 + x) * 256 + c] = 0;
    }
}

// ---------------------------------------------------------------------------
// K1: pre = relu(BN1(x)), NCHW f32 -> padded NHWC bf16 (interior only)
// ---------------------------------------------------------------------------
__global__ void pre_kernel(const float* __restrict__ x, const float* __restrict__ g,
                           const float* __restrict__ b, const float* __restrict__ m,
                           const float* __restrict__ v, u16* __restrict__ pre) {
    __shared__ u16 tile[128 * 136];
    int n = blockIdx.x >> 7, y = blockIdx.x & 127;
    int tid = threadIdx.x;
    int c = tid >> 1, xh = (tid & 1) << 6;
    float sc = g[c] * rsqrtf(v[c] + 1e-5f);
    float bi = b[c] - m[c] * sc;
    const float4* src = (const float4*)(x + (((n * 128 + c) * 128 + y) << 7) + xh);
#pragma unroll
    for (int j = 0; j < 16; ++j) {
        float4 val = src[j];
        int xb = xh + j * 4;
        tile[(xb + 0) * 136 + c] = f2bf(fmaxf(val.x * sc + bi, 0.f));
        tile[(xb + 1) * 136 + c] = f2bf(fmaxf(val.y * sc + bi, 0.f));
        tile[(xb + 2) * 136 + c] = f2bf(fmaxf(val.z * sc + bi, 0.f));
        tile[(xb + 3) * 136 + c] = f2bf(fmaxf(val.w * sc + bi, 0.f));
    }
    __syncthreads();
    int c0 = (tid & 15) << 3;
#pragma unroll
    for (int xi = 0; xi < 8; ++xi) {
        int xx = xi * 16 + (tid >> 4);
        u16x8 val = *(const u16x8*)&tile[xx * 136 + c0];
        *(u16x8*)(pre + ((n * 129 + y) * 129 + xx) * 128 + c0) = val;
    }
}

// ===========================================================================
// 8-phase 256x256 implicit-GEMM conv, Gray-code operand reuse, A TRIPLE-
// buffered (HBM-latency stream) + B double-buffered (L2-hot weights).
// LDS = 3*32K (A) + 2*32K (B) = 160 KiB.
//   per tile t: ph0 stage B0(t+1), ph1 B1(t+1), ph2 A0(t+2), ph3 A1(t+2)
//   vmcnt(4) at ph3 drains exactly tile t+1's operands, keeps A(t+2) flying.
//   T2 swizzle: lds chunk ^= row&7 via inverse-swizzled global source.
//   POOL: conv2 fuses the SE global-avg partial sums into the epilogue.
// ===========================================================================
template <int CIN, int NTAPS, int STRIDE, bool BIASRELU, bool POOL>
__global__ __launch_bounds__(512, 2)
void conv_8ph(const u16* __restrict__ in, const u16* __restrict__ wt,
              const float* __restrict__ bias, u16* __restrict__ out,
              float* __restrict__ pool_out,
              int in_row, int in_img, int out_base, int out_row, int out_img) {
    constexpr int CSTEPS = CIN / 64;
    constexpr int KT = CSTEPS * NTAPS;
    // A buffers: 0, 16384, 32768 ; B buffers: 49152, 65536   (u16 units)
    __shared__ __attribute__((aligned(16))) u16 lds[81920];

    const int tid = threadIdx.x;
    const int w = tid >> 6, l = tid & 63;
    const int wm = w >> 2, wn = w & 3;
    const int l15 = l & 15;
    const int Mbase = blockIdx.x << 8;

    const int srow = tid >> 3;
    const int swze = (((tid & 7) ^ (srow & 7)) << 3);
    int pix0 = Mbase + srow;
    int nn0 = pix0 >> 12, p0 = (pix0 >> 6) & 63, q0 = pix0 & 63;
    const int abase0 = nn0 * in_img + (STRIDE * p0) * in_row + (STRIDE * q0) * CIN + swze;
    const int astep = STRIDE * in_row;
    const int bbase0 = srow * CIN + swze;
    const int bstep = 64 * CIN;

    int colw[2];
#pragma unroll
    for (int kk = 0; kk < 2; ++kk)
        colw[kk] = (kk * 32 + (l >> 4) * 8) ^ ((l & 7) << 3);

    f32x4 acc[8][4] = {};
    bf16x8 afr[4][2], b0f[2][2], b1f[2][2];

#define AOFF(ks) (((NTAPS == 9) ? ((((ks) / CSTEPS) / 3) * in_row + (((ks) / CSTEPS) % 3) * CIN) : 0) + ((ks) % CSTEPS) * 64)
#define BOFF(ks) (((ks) / CSTEPS) * 256 * CIN + ((ks) % CSTEPS) * 64)
#define GLDS(gsrc, ldst) __builtin_amdgcn_global_load_lds(                          \
        (__attribute__((address_space(1))) void*)(gsrc),                            \
        (__attribute__((address_space(3))) void*)(ldst), 16, 0, 0)
#define STAGE_A(base, h, ks) {                                                      \
    int _ao = AOFF(ks);                                                             \
    GLDS(in + abase0 + (2 * (h) + 0) * astep + _ao,                                 \
         &lds[(base) + (h) * 8192 + 0 * 4096 + w * 512]);                           \
    GLDS(in + abase0 + (2 * (h) + 1) * astep + _ao,                                 \
         &lds[(base) + (h) * 8192 + 1 * 4096 + w * 512]); }
#define STAGE_B(base, h, ks) {                                                      \
    int _bo = BOFF(ks);                                                             \
    GLDS(wt + bbase0 + (2 * (h) + 0) * bstep + _bo,                                 \
         &lds[(base) + (h) * 8192 + 0 * 4096 + w * 512]);                           \
    GLDS(wt + bbase0 + (2 * (h) + 1) * bstep + _bo,                                 \
         &lds[(base) + (h) * 8192 + 1 * 4096 + w * 512]); }
#define BARRIER() { __builtin_amdgcn_s_barrier(); asm volatile("" ::: "memory"); }
#define LDA(base, MH) {                                                             \
    _Pragma("unroll") for (int fm = 0; fm < 4; ++fm)                                \
    _Pragma("unroll") for (int kk = 0; kk < 2; ++kk)                                \
        afr[fm][kk] = *(const bf16x8*)&lds[(base) + ((MH) * 128 + wm * 64 + fm * 16 + l15) * 64 + colw[kk]]; }
#define LDB(base, NH, dst) {                                                        \
    _Pragma("unroll") for (int gn = 0; gn < 2; ++gn)                                \
    _Pragma("unroll") for (int kk = 0; kk < 2; ++kk)                                \
        dst[gn][kk] = *(const bf16x8*)&lds[(base) + ((NH) * 128 + gn * 64 + wn * 16 + l15) * 64 + colw[kk]]; }
#define MFMA_Q(MH, NH, bset) {                                                      \
    _Pragma("unroll") for (int fm = 0; fm < 4; ++fm)                                \
    _Pragma("unroll") for (int gn = 0; gn < 2; ++gn)                                \
    _Pragma("unroll") for (int kk = 0; kk < 2; ++kk)                                \
        acc[(MH) * 4 + fm][(NH) * 2 + gn] = __builtin_amdgcn_mfma_f32_16x16x32_bf16( \
            afr[fm][kk], bset[gn][kk], acc[(MH) * 4 + fm][(NH) * 2 + gn], 0, 0, 0); }
#define LGK0() asm volatile("s_waitcnt lgkmcnt(0)" ::: "memory")

    // ---- prologue: A(0)->buf0, B(0)->buf0, A(1)->buf1; drain A(0),B(0) ----
    STAGE_A(0, 0, 0); STAGE_A(0, 1, 0);
    STAGE_B(49152, 0, 0); STAGE_B(49152, 1, 0);
    STAGE_A(16384, 0, 1); STAGE_A(16384, 1, 1);
    asm volatile("s_waitcnt vmcnt(4)" ::: "memory");
    BARRIER();

    int Ar = 0;          // A read buffer (tile t)
    int As = 32768;      // A stage buffer (tile t+2)
    int Brel = 0;        // B read rel offset (tile t); stage = ^16384

    // ---- steady loop ----
#pragma unroll 1
    for (int t = 0; t < KT - 2; ++t) {
        const int Br = 49152 + Brel, Bs = 49152 + (Brel ^ 16384);
        // ph0: quadrant (0,0); read A0+B0; stage B0(t+1)
        LDA(Ar, 0); LDB(Br, 0, b0f);
        STAGE_B(Bs, 0, t + 1);
        __builtin_amdgcn_s_barrier();
        LGK0();
        __builtin_amdgcn_s_setprio(1);
        MFMA_Q(0, 0, b0f);
        __builtin_amdgcn_s_setprio(0);
        BARRIER();
        // ph1: quadrant (0,1); read B1; stage B1(t+1)
        LDB(Br, 1, b1f);
        STAGE_B(Bs, 1, t + 1);
        __builtin_amdgcn_s_barrier();
        LGK0();
        __builtin_amdgcn_s_setprio(1);
        MFMA_Q(0, 1, b1f);
        __builtin_amdgcn_s_setprio(0);
        BARRIER();
        // ph2: quadrant (1,1); read A1; stage A0(t+2)
        LDA(Ar, 1);
        STAGE_A(As, 0, t + 2);
        __builtin_amdgcn_s_barrier();
        LGK0();
        __builtin_amdgcn_s_setprio(1);
        MFMA_Q(1, 1, b1f);
        __builtin_amdgcn_s_setprio(0);
        BARRIER();
        // ph3: quadrant (1,0); stage A1(t+2); counted vmcnt
        STAGE_A(As, 1, t + 2);
        __builtin_amdgcn_s_barrier();
        __builtin_amdgcn_s_setprio(1);
        MFMA_Q(1, 0, b0f);
        __builtin_amdgcn_s_setprio(0);
        asm volatile("s_waitcnt vmcnt(4)" ::: "memory");
        BARRIER();
        Ar = (Ar == 32768) ? 0 : Ar + 16384;
        As = (As == 32768) ? 0 : As + 16384;
        Brel ^= 16384;
    }

    // ---- tile KT-2: stage only B(KT-1); drain everything ----
    {
        const int Br = 49152 + Brel, Bs = 49152 + (Brel ^ 16384);
        LDA(Ar, 0); LDB(Br, 0, b0f);
        STAGE_B(Bs, 0, KT - 1);
        __builtin_amdgcn_s_barrier();
        LGK0();
        __builtin_amdgcn_s_setprio(1);
        MFMA_Q(0, 0, b0f);
        __builtin_amdgcn_s_setprio(0);
        BARRIER();
        LDB(Br, 1, b1f);
        STAGE_B(Bs, 1, KT - 1);
        __builtin_amdgcn_s_barrier();
        LGK0();
        __builtin_amdgcn_s_setprio(1);
        MFMA_Q(0, 1, b1f);
        __builtin_amdgcn_s_setprio(0);
        BARRIER();
        LDA(Ar, 1);
        __builtin_amdgcn_s_barrier();
        LGK0();
        __builtin_amdgcn_s_setprio(1);
        MFMA_Q(1, 1, b1f);
        __builtin_amdgcn_s_setprio(0);
        BARRIER();
        __builtin_amdgcn_s_barrier();
        __builtin_amdgcn_s_setprio(1);
        MFMA_Q(1, 0, b0f);
        __builtin_amdgcn_s_setprio(0);
        asm volatile("s_waitcnt vmcnt(0)" ::: "memory");
        BARRIER();
        Ar = (Ar == 32768) ? 0 : Ar + 16384;
        Brel ^= 16384;
    }
    // ---- tile KT-1: fully resident ----
    {
        const int Br = 49152 + Brel;
        LDA(Ar, 0); LDB(Br, 0, b0f); LDB(Br, 1, b1f);
        MFMA_Q(0, 0, b0f);
        MFMA_Q(0, 1, b1f);
        LDA(Ar, 1);
        MFMA_Q(1, 1, b1f);
        MFMA_Q(1, 0, b0f);
    }
#undef AOFF
#undef BOFF
#undef GLDS
#undef STAGE_A
#undef STAGE_B
#undef LDA
#undef LDB
#undef LGK0

    // ---- epilogue: C frag (col=lane&15 -> o, row=(lane>>4)*4+j -> pixel) ----
#pragma unroll
    for (int f = 0; f < 8; ++f) {
        const int prow = (f >> 2) * 128 + wm * 64 + (f & 3) * 16 + ((l >> 4) << 2);
#pragma unroll
        for (int g = 0; g < 4; ++g) {
            const int o = (g >> 1) * 128 + (g & 1) * 64 + wn * 16 + l15;
            float bb = 0.f;
            if (BIASRELU) bb = bias[o];
#pragma unroll
            for (int j = 0; j < 4; ++j) {
                int pix = Mbase + prow + j;
                int nn = pix >> 12, p = (pix >> 6) & 63, q = pix & 63;
                float val = acc[f][g][j] + bb;
                if (BIASRELU) val = fmaxf(val, 0.f);
                out[out_base + nn * out_img + p * out_row + q * 256 + o] = f2bf(val);
            }
        }
    }

    // ---- fused SE pooling: per-block column sums (deterministic) ----
    if (POOL) {
        float ps[4];
#pragma unroll
        for (int g = 0; g < 4; ++g) {
            float s = 0.f;
#pragma unroll
            for (int f = 0; f < 8; ++f)
#pragma unroll
                for (int j = 0; j < 4; ++j) s += acc[f][g][j];
            s += __shfl_xor(s, 16);
            s += __shfl_xor(s, 32);
            ps[g] = s;
        }
        // drain own LDS reads before reusing lds as float scratch
        asm volatile("s_waitcnt lgkmcnt(0)" ::: "memory");
        BARRIER();
        float* fl = (float*)lds;
        if ((l >> 4) == 0) {
#pragma unroll
            for (int g = 0; g < 4; ++g) {
                int o = (g >> 1) * 128 + (g & 1) * 64 + wn * 16 + l15;
                fl[wm * 256 + o] = ps[g];
            }
        }
        BARRIER();
        if (tid < 256)
            pool_out[blockIdx.x * 256 + tid] = fl[tid] + fl[256 + tid];
    }
#undef MFMA_Q
#undef BARRIER
}

// ---------------------------------------------------------------------------
// old 128x128 2-phase conv (kept for the tiny 1x1 residual conv, K=128)
// ---------------------------------------------------------------------------
template <int CIN, int NTAPS, int STRIDE, bool BIASRELU>
__global__ __launch_bounds__(256, 2)
void conv_mfma(const u16* __restrict__ in, const u16* __restrict__ wt,
               const float* __restrict__ bias, u16* __restrict__ out,
               int in_row, int in_img, int out_base, int out_row, int out_img) {
    constexpr int CSTEPS = CIN / 64;
    constexpr int KSTEPS = CSTEPS * NTAPS;
    __shared__ u16 lA[128 * 64];
    __shared__ u16 lB[128 * 64];

    const int tid = threadIdx.x;
    const int w = tid >> 6, l = tid & 63;
    const int bn = blockIdx.x & 1;
    const int Mbase = (blockIdx.x >> 1) << 7;
    const int wm = w >> 1, wn = w & 1;
    const int srow = l >> 3;
    const int chunk = l & 7;

    int abase[4], wbase[4];
#pragma unroll
    for (int i = 0; i < 4; ++i) {
        int pix = w * 32 + i * 8 + srow;
        int mm = Mbase + pix;
        int nn = mm >> 12, p = (mm >> 6) & 63, q = mm & 63;
        abase[i] = nn * in_img + (STRIDE * p) * in_row + (STRIDE * q) * CIN + chunk * 8;
        wbase[i] = (bn * 128 + pix) * CIN + chunk * 8;
    }

    f32x4 acc[4][4] = {};

    int abyte[4], bbyte[4];
#pragma unroll
    for (int f = 0; f < 4; ++f) {
        abyte[f] = ((wm * 64 + f * 16 + (l & 15)) * 64 + ((l >> 4) * 8)) * 2;
        bbyte[f] = ((wn * 64 + f * 16 + (l & 15)) * 64 + ((l >> 4) * 8)) * 2;
    }

    for (int ks = 0; ks < KSTEPS; ++ks) {
        const int tap = ks / CSTEPS;
        const int c0 = (ks % CSTEPS) * 64;
        const int dy = (NTAPS == 9) ? (tap / 3) : 0;
        const int dx = (NTAPS == 9) ? (tap - dy * 3) : 0;
        const int aoff = dy * in_row + dx * CIN + c0;
        const int boff = tap * 256 * CIN + c0;
        __syncthreads();
#pragma unroll
        for (int i = 0; i < 4; ++i) {
            const u16* gsrc = in + abase[i] + aoff;
            u16* ldst = &lA[(w * 32 + i * 8) * 64];
            __builtin_amdgcn_global_load_lds((__attribute__((address_space(1))) void*)gsrc,
                                             (__attribute__((address_space(3))) void*)ldst,
                                             16, 0, 0);
        }
#pragma unroll
        for (int i = 0; i < 4; ++i) {
            const u16* gsrc = wt + wbase[i] + boff;
            u16* ldst = &lB[(w * 32 + i * 8) * 64];
            __builtin_amdgcn_global_load_lds((__attribute__((address_space(1))) void*)gsrc,
                                             (__attribute__((address_space(3))) void*)ldst,
                                             16, 0, 0);
        }
        __syncthreads();
#pragma unroll
        for (int kk = 0; kk < 2; ++kk) {
            bf16x8 af[4], bv[4];
#pragma unroll
            for (int f = 0; f < 4; ++f)
                af[f] = *(const bf16x8*)((const char*)lA + abyte[f] + kk * 64);
#pragma unroll
            for (int f = 0; f < 4; ++f)
                bv[f] = *(const bf16x8*)((const char*)lB + bbyte[f] + kk * 64);
#pragma unroll
            for (int fm = 0; fm < 4; ++fm)
#pragma unroll
                for (int fn = 0; fn < 4; ++fn)
                    acc[fm][fn] = __builtin_amdgcn_mfma_f32_16x16x32_bf16(
                        af[fm], bv[fn], acc[fm][fn], 0, 0, 0);
        }
    }

#pragma unroll
    for (int fm = 0; fm < 4; ++fm) {
        const int mloc = wm * 64 + fm * 16 + ((l >> 4) << 2);
#pragma unroll
        for (int fn = 0; fn < 4; ++fn) {
            const int o = bn * 128 + wn * 64 + fn * 16 + (l & 15);
            float bb = 0.f;
            if (BIASRELU) bb = bias[o];
#pragma unroll
            for (int j = 0; j < 4; ++j) {
                int mm = Mbase + mloc + j;
                int nn = mm >> 12, p = (mm >> 6) & 63, q = mm & 63;
                float val = acc[fm][fn][j] + bb;
                if (BIASRELU) val = fmaxf(val, 0.f);
                out[out_base + nn * out_img + p * out_row + q * 256 + o] = f2bf(val);
            }
        }
    }
}

// ---------------------------------------------------------------------------
// SE MLP: a = sigmoid(relu(mean @ w1^T + b1) @ w2^T + b2)
// partial layout: [256 blocks][256 o], block b covers image b>>4
// ---------------------------------------------------------------------------
__global__ void se_kernel(const float* __restrict__ partial,
                          const float* __restrict__ w1, const float* __restrict__ b1,
                          const float* __restrict__ w2, const float* __restrict__ b2,
                          float* __restrict__ a) {
    __shared__ float sm[16 * 256];
    __shared__ float hl[16 * 16];
    int t = threadIdx.x;
    for (int n = 0; n < 16; ++n) {
        float s = 0.f;
#pragma unroll
        for (int k = 0; k < 16; ++k) s += partial[(n * 16 + k) * 256 + t];
        sm[n * 256 + t] = s * (1.0f / 4096.0f);
    }
    __syncthreads();
    {
        int bb = t >> 4, j = t & 15;
        float d = b1[j];
        for (int c = 0; c < 256; ++c) d += sm[bb * 256 + c] * w1[j * 256 + c];
        hl[bb * 16 + j] = fmaxf(d, 0.f);
    }
    __syncthreads();
    {
        int o = t;
        for (int bb = 0; bb < 16; ++bb) {
            float z = b2[o];
            for (int j = 0; j < 16; ++j) z += hl[bb * 16 + j] * w2[o * 16 + j];
            a[bb * 256 + o] = 1.0f / (1.0f + expf(-z));
        }
    }
}

// ---------------------------------------------------------------------------
// K5: out[n][o][p][q] = h2[n][p][q][o]*a[n][o] + res[n][p][q][o]
// ---------------------------------------------------------------------------
__global__ void finalize_kernel(const u16* __restrict__ h2, const u16* __restrict__ res,
                                const float* __restrict__ a, float* __restrict__ out) {
    __shared__ u16 th[256 * 68];
    __shared__ float al[256];
    int n = blockIdx.x >> 6, p = blockIdx.x & 63;
    int t = threadIdx.x;
    al[t] = a[n * 256 + t];
    __syncthreads();
    int o8 = (t & 31) << 3, qr = t >> 5;
    int pixbase = n * 4096 + p * 64;
#pragma unroll
    for (int qi = 0; qi < 8; ++qi) {
        int q = qi * 8 + qr;
        int gi = (pixbase + q) * 256 + o8;
        u16x8 hv = *(const u16x8*)(h2 + gi);
        u16x8 rv = *(const u16x8*)(res + gi);
#pragma unroll
        for (int k = 0; k < 8; ++k) {
            float vv = bf2f(hv[k]) * al[o8 + k] + bf2f(rv[k]);
            th[(o8 + k) * 68 + q] = f2bf(vv);
        }
    }
    __syncthreads();
    int q4 = (t & 15) << 2, ob = t >> 4;
#pragma unroll
    for (int oi = 0; oi < 16; ++oi) {
        int o = oi * 16 + ob;
        float4 vv;
        vv.x = bf2f(th[o * 68 + q4 + 0]);
        vv.y = bf2f(th[o * 68 + q4 + 1]);
        vv.z = bf2f(th[o * 68 + q4 + 2]);
        vv.w = bf2f(th[o * 68 + q4 + 3]);
        *(float4*)(out + ((n * 256 + o) * 64 + p) * 64 + q4) = vv;
    }
}

// ---------------------------------------------------------------------------
// workspace layout (bytes)
// ---------------------------------------------------------------------------
static const size_t OFF_PRE  = 0;                       // 68,161,536 ; reused for h2
static const size_t OFF_H1   = 68161536;                // 35,684,352
static const size_t OFF_RES  = 103845888;               // 33,554,432
static const size_t OFF_W1T  = 137400320;               // 589,824
static const size_t OFF_W2T  = 137990144;               // 1,179,648
static const size_t OFF_WRT  = 139169792;               // 65,536
static const size_t OFF_B2F  = 139235328;               // 1,024
static const size_t OFF_PART = 139236352;               // 262,144 (256 blocks x 256 f32)
static const size_t OFF_A    = 139760640;               // 16,384

extern "C" void kernel_launch(void* const* d_in, const int* in_sizes, int n_in,
                              void* d_out, int out_size, void* d_ws, size_t ws_size,
                              hipStream_t stream) {
    (void)in_sizes; (void)n_in; (void)out_size; (void)ws_size;
    const float* x      = (const float*)d_in[0];
    const float* bn1_g  = (const float*)d_in[1];
    const float* bn1_b  = (const float*)d_in[2];
    const float* bn1_m  = (const float*)d_in[3];
    const float* bn1_v  = (const float*)d_in[4];
    const float* bn2_g  = (const float*)d_in[5];
    const float* bn2_b  = (const float*)d_in[6];
    const float* bn2_m  = (const float*)d_in[7];
    const float* bn2_v  = (const float*)d_in[8];
    const float* wc1    = (const float*)d_in[9];
    const float* wc2    = (const float*)d_in[10];
    const float* wres   = (const float*)d_in[11];
    const float* se_w1  = (const float*)d_in[12];
    const float* se_b1  = (const float*)d_in[13];
    const float* se_w2  = (const float*)d_in[14];
    const float* se_b2  = (const float*)d_in[15];

    char* ws = (char*)d_ws;
    u16*   pre    = (u16*)(ws + OFF_PRE);
    u16*   h2     = (u16*)(ws + OFF_PRE);   // aliases pre (dead by conv2)
    u16*   h1     = (u16*)(ws + OFF_H1);
    u16*   res    = (u16*)(ws + OFF_RES);
    u16*   w1t    = (u16*)(ws + OFF_W1T);
    u16*   w2t    = (u16*)(ws + OFF_W2T);
    u16*   wrt    = (u16*)(ws + OFF_WRT);
    float* bias2f = (float*)(ws + OFF_B2F);
    float* part   = (float*)(ws + OFF_PART);
    float* avec   = (float*)(ws + OFF_A);
    float* out    = (float*)d_out;

    setup_kernel<<<9801, 256, 0, stream>>>(wc1, wc2, wres, bn2_g, bn2_b, bn2_m, bn2_v,
                                           w1t, w2t, wrt, bias2f, pre, h1);
    pre_kernel<<<2048, 256, 0, stream>>>(x, bn1_g, bn1_b, bn1_m, bn1_v, pre);

    // conv1: 3x3 s2, 128->256, +BN2(bias)+ReLU, out = padded h1 (base (1,1))
    conv_8ph<128, 9, 2, true, false><<<256, 512, 0, stream>>>(
        pre, w1t, bias2f, h1, nullptr,
        129 * 128, 129 * 129 * 128,
        67 * 256, 66 * 256, 66 * 66 * 256);

    // residual: 1x1 s2, 128->256 (old small-tile kernel)
    conv_mfma<128, 1, 2, false><<<1024, 256, 0, stream>>>(
        pre, wrt, nullptr, res,
        129 * 128, 129 * 129 * 128,
        0, 64 * 256, 4096 * 256);

    // conv2: 3x3 s1, 256->256 (h2 overwrites pre region) + fused SE pooling
    conv_8ph<256, 9, 1, false, true><<<256, 512, 0, stream>>>(
        h1, w2t, nullptr, h2, part,
        66 * 256, 66 * 66 * 256,
        0, 64 * 256, 4096 * 256);

    se_kernel<<<1, 256, 0, stream>>>(part, se_w1, se_b1, se_w2, se_b2, avec);
    finalize_kernel<<<1024, 256, 0, stream>>>(h2, res, avec, out);
}

// Round 5
// 212.931 us; speedup vs baseline: 1.5294x; 1.0179x over previous
//
#include <hip/hip_runtime.h>

typedef unsigned short u16;
typedef __attribute__((ext_vector_type(8))) unsigned short u16x8;
typedef __attribute__((ext_vector_type(8))) __bf16 bf16x8;
typedef __attribute__((ext_vector_type(4))) float f32x4;

__device__ __forceinline__ float bf2f(u16 u) {
    return __uint_as_float(((unsigned)u) << 16);
}
__device__ __forceinline__ u16 f2bf(float f) {
    unsigned u = __float_as_uint(f);
    return (u16)((u + 0x7FFFu + ((u >> 16) & 1u)) >> 16);
}

// ---------------------------------------------------------------------------
// setup kernel: weight transform + pad zeroing, one launch.
// ---------------------------------------------------------------------------
__global__ void setup_kernel(const float* __restrict__ w1, const float* __restrict__ w2,
                             const float* __restrict__ wr,
                             const float* __restrict__ g2, const float* __restrict__ b2,
                             const float* __restrict__ m2, const float* __restrict__ v2,
                             u16* __restrict__ w1t, u16* __restrict__ w2t,
                             u16* __restrict__ wrt, float* __restrict__ bias2f,
                             u16* __restrict__ pre, u16* __restrict__ h1) {
    int b = blockIdx.x;
    if (b < 3585) {
        int i = b * 256 + threadIdx.x;
        if (i < 294912) {
            int ci = i & 127; int t = i >> 7; int o = t & 255; int tap = t >> 8;
            int dy = tap / 3, dx = tap - dy * 3;
            float sc = g2[o] * rsqrtf(v2[o] + 1e-5f);
            w1t[i] = f2bf(w1[((o * 128 + ci) * 3 + dy) * 3 + dx] * sc);
        } else if (i < 294912 + 589824) {
            int j = i - 294912;
            int ci = j & 255; int t = j >> 8; int o = t & 255; int tap = t >> 8;
            int dy = tap / 3, dx = tap - dy * 3;
            w2t[j] = f2bf(w2[((o * 256 + ci) * 3 + dy) * 3 + dx]);
        } else if (i < 294912 + 589824 + 32768) {
            int j = i - (294912 + 589824);
            int ci = j & 127; int o = j >> 7;
            wrt[j] = f2bf(wr[o * 128 + ci]);
        } else {
            int o = i - (294912 + 589824 + 32768);
            if (o < 256) {
                float sc = g2[o] * rsqrtf(v2[o] + 1e-5f);
                bias2f[o] = b2[o] - m2[o] * sc;
            }
        }
    } else if (b < 3585 + 2056) {
        int i = (b - 3585) * 256 + threadIdx.x;
        if (i < 16 * 129 * 128) {
            int c = i & 127; int t = i >> 7; int n = t / 129; int xx = t - n * 129;
            pre[((n * 129 + 128) * 129 + xx) * 128 + c] = 0;
        } else {
            int j = i - 16 * 129 * 128;
            int c = j & 127; int t = j >> 7; int n = t >> 7; int y = t & 127;
            pre[((n * 129 + y) * 129 + 128) * 128 + c] = 0;
        }
    } else {
        int i = (b - (3585 + 2056)) * 256 + threadIdx.x;
        int c = i & 255;
        int t = i >> 8;
        int n = t / 260;
        int cl = t - n * 260;
        int y, x;
        if (cl < 66)       { y = 0;  x = cl; }
        else if (cl < 132) { y = 65; x = cl - 66; }
        else if (cl < 196) { x = 0;  y = cl - 131; }
        else               { x = 65; y = cl - 195; }
        h1[((n * 66 + y) * 66 + x) * 256 + c] = 0;
    }
}

// ---------------------------------------------------------------------------
// K1: pre = relu(BN1(x)), NCHW f32 -> padded NHWC bf16 (interior only)
// ---------------------------------------------------------------------------
__global__ void pre_kernel(const float* __restrict__ x, const float* __restrict__ g,
                           const float* __restrict__ b, const float* __restrict__ m,
                           const float* __restrict__ v, u16* __restrict__ pre) {
    __shared__ u16 tile[128 * 136];
    int n = blockIdx.x >> 7, y = blockIdx.x & 127;
    int tid = threadIdx.x;
    int c = tid >> 1, xh = (tid & 1) << 6;
    float sc = g[c] * rsqrtf(v[c] + 1e-5f);
    float bi = b[c] - m[c] * sc;
    const float4* src = (const float4*)(x + (((n * 128 + c) * 128 + y) << 7) + xh);
#pragma unroll
    for (int j = 0; j < 16; ++j) {
        float4 val = src[j];
        int xb = xh + j * 4;
        tile[(xb + 0) * 136 + c] = f2bf(fmaxf(val.x * sc + bi, 0.f));
        tile[(xb + 1) * 136 + c] = f2bf(fmaxf(val.y * sc + bi, 0.f));
        tile[(xb + 2) * 136 + c] = f2bf(fmaxf(val.z * sc + bi, 0.f));
        tile[(xb + 3) * 136 + c] = f2bf(fmaxf(val.w * sc + bi, 0.f));
    }
    __syncthreads();
    int c0 = (tid & 15) << 3;
#pragma unroll
    for (int xi = 0; xi < 8; ++xi) {
        int xx = xi * 16 + (tid >> 4);
        u16x8 val = *(const u16x8*)&tile[xx * 136 + c0];
        *(u16x8*)(pre + ((n * 129 + y) * 129 + xx) * 128 + c0) = val;
    }
}

// ===========================================================================
// 256x256 implicit-GEMM conv: Gray-code operand reuse, A triple-buffered,
// B double-buffered, ONE barrier + ONE counted vmcnt per K-tile.
//   Slot discipline (audited): at tile t, reads hit A slot t%3 / B slot t&1;
//   staging hits A slot (t+2)%3 / B slot (t+1)&1 -- never a slot being read
//   this tile; drift across tiles is blocked by the boundary barrier; all
//   ds_reads are MFMA-consumed (lgkm-retired) before that barrier.
//   vmcnt(4) at boundary drains A(t+1)+B(t+1), keeps A(t+2) in flight.
//   T2 swizzle via inverse-swizzled global source + swizzled ds_read.
//   POOL: conv2 fuses the SE global-avg partial sums into the epilogue.
// ===========================================================================
template <int CIN, int NTAPS, int STRIDE, bool BIASRELU, bool POOL>
__global__ __launch_bounds__(512, 2)
void conv_8ph(const u16* __restrict__ in, const u16* __restrict__ wt,
              const float* __restrict__ bias, u16* __restrict__ out,
              float* __restrict__ pool_out,
              int in_row, int in_img, int out_base, int out_row, int out_img) {
    constexpr int CSTEPS = CIN / 64;
    constexpr int KT = CSTEPS * NTAPS;
    // A buffers: 0, 16384, 32768 ; B buffers: 49152, 65536   (u16 units)
    __shared__ __attribute__((aligned(16))) u16 lds[81920];

    const int tid = threadIdx.x;
    const int w = tid >> 6, l = tid & 63;
    const int wm = w >> 2, wn = w & 3;
    const int l15 = l & 15;
    const int Mbase = blockIdx.x << 8;

    const int srow = tid >> 3;
    const int swze = (((tid & 7) ^ (srow & 7)) << 3);
    int pix0 = Mbase + srow;
    int nn0 = pix0 >> 12, p0 = (pix0 >> 6) & 63, q0 = pix0 & 63;
    const int abase0 = nn0 * in_img + (STRIDE * p0) * in_row + (STRIDE * q0) * CIN + swze;
    const int astep = STRIDE * in_row;
    const int bbase0 = srow * CIN + swze;
    const int bstep = 64 * CIN;

    int colw[2];
#pragma unroll
    for (int kk = 0; kk < 2; ++kk)
        colw[kk] = (kk * 32 + (l >> 4) * 8) ^ ((l & 7) << 3);

    f32x4 acc[8][4] = {};
    bf16x8 afr[4][2], b0f[2][2], b1f[2][2];

#define AOFF(ks) (((NTAPS == 9) ? ((((ks) / CSTEPS) / 3) * in_row + (((ks) / CSTEPS) % 3) * CIN) : 0) + ((ks) % CSTEPS) * 64)
#define BOFF(ks) (((ks) / CSTEPS) * 256 * CIN + ((ks) % CSTEPS) * 64)
#define GLDS(gsrc, ldst) __builtin_amdgcn_global_load_lds(                          \
        (__attribute__((address_space(1))) void*)(gsrc),                            \
        (__attribute__((address_space(3))) void*)(ldst), 16, 0, 0)
#define STAGE_A(base, h, ks) {                                                      \
    int _ao = AOFF(ks);                                                             \
    GLDS(in + abase0 + (2 * (h) + 0) * astep + _ao,                                 \
         &lds[(base) + (h) * 8192 + 0 * 4096 + w * 512]);                           \
    GLDS(in + abase0 + (2 * (h) + 1) * astep + _ao,                                 \
         &lds[(base) + (h) * 8192 + 1 * 4096 + w * 512]); }
#define STAGE_B(base, h, ks) {                                                      \
    int _bo = BOFF(ks);                                                             \
    GLDS(wt + bbase0 + (2 * (h) + 0) * bstep + _bo,                                 \
         &lds[(base) + (h) * 8192 + 0 * 4096 + w * 512]);                           \
    GLDS(wt + bbase0 + (2 * (h) + 1) * bstep + _bo,                                 \
         &lds[(base) + (h) * 8192 + 1 * 4096 + w * 512]); }
#define BARRIER() { __builtin_amdgcn_s_barrier(); asm volatile("" ::: "memory"); }
#define LDA(base, MH) {                                                             \
    _Pragma("unroll") for (int fm = 0; fm < 4; ++fm)                                \
    _Pragma("unroll") for (int kk = 0; kk < 2; ++kk)                                \
        afr[fm][kk] = *(const bf16x8*)&lds[(base) + ((MH) * 128 + wm * 64 + fm * 16 + l15) * 64 + colw[kk]]; }
#define LDB(base, NH, dst) {                                                        \
    _Pragma("unroll") for (int gn = 0; gn < 2; ++gn)                                \
    _Pragma("unroll") for (int kk = 0; kk < 2; ++kk)                                \
        dst[gn][kk] = *(const bf16x8*)&lds[(base) + ((NH) * 128 + gn * 64 + wn * 16 + l15) * 64 + colw[kk]]; }
#define MFMA_Q(MH, NH, bset) {                                                      \
    _Pragma("unroll") for (int fm = 0; fm < 4; ++fm)                                \
    _Pragma("unroll") for (int gn = 0; gn < 2; ++gn)                                \
    _Pragma("unroll") for (int kk = 0; kk < 2; ++kk)                                \
        acc[(MH) * 4 + fm][(NH) * 2 + gn] = __builtin_amdgcn_mfma_f32_16x16x32_bf16( \
            afr[fm][kk], bset[gn][kk], acc[(MH) * 4 + fm][(NH) * 2 + gn], 0, 0, 0); }

    // ---- prologue: A(0),B(0),A(1); drain A(0)+B(0), keep A(1) flying ----
    STAGE_A(0, 0, 0); STAGE_A(0, 1, 0);
    STAGE_B(49152, 0, 0); STAGE_B(49152, 1, 0);
    STAGE_A(16384, 0, 1); STAGE_A(16384, 1, 1);
    asm volatile("s_waitcnt vmcnt(4)" ::: "memory");
    BARRIER();

    int Ar = 0;          // A read slot (tile t)
    int As = 32768;      // A stage slot (tile t+2)
    int Brel = 0;        // B read slot rel offset; stage = ^16384

    // ---- steady loop: ONE barrier + ONE counted vmcnt per K-tile ----
#pragma unroll 1
    for (int t = 0; t < KT - 2; ++t) {
        const int Br = 49152 + Brel, Bs = 49152 + (Brel ^ 16384);
        LDA(Ar, 0);
        LDB(Br, 0, b0f);
        LDB(Br, 1, b1f);
        STAGE_B(Bs, 0, t + 1); STAGE_B(Bs, 1, t + 1);
        __builtin_amdgcn_s_setprio(1);
        MFMA_Q(0, 0, b0f);
        MFMA_Q(0, 1, b1f);
        __builtin_amdgcn_s_setprio(0);
        LDA(Ar, 1);
        STAGE_A(As, 0, t + 2); STAGE_A(As, 1, t + 2);
        __builtin_amdgcn_s_setprio(1);
        MFMA_Q(1, 1, b1f);
        MFMA_Q(1, 0, b0f);
        __builtin_amdgcn_s_setprio(0);
        asm volatile("s_waitcnt vmcnt(4)" ::: "memory");
        BARRIER();
        Ar = (Ar == 32768) ? 0 : Ar + 16384;
        As = (As == 32768) ? 0 : As + 16384;
        Brel ^= 16384;
    }

    // ---- tile KT-2: stage only B(KT-1); drain everything ----
    {
        const int Br = 49152 + Brel, Bs = 49152 + (Brel ^ 16384);
        LDA(Ar, 0);
        LDB(Br, 0, b0f);
        LDB(Br, 1, b1f);
        STAGE_B(Bs, 0, KT - 1); STAGE_B(Bs, 1, KT - 1);
        __builtin_amdgcn_s_setprio(1);
        MFMA_Q(0, 0, b0f);
        MFMA_Q(0, 1, b1f);
        __builtin_amdgcn_s_setprio(0);
        LDA(Ar, 1);
        __builtin_amdgcn_s_setprio(1);
        MFMA_Q(1, 1, b1f);
        MFMA_Q(1, 0, b0f);
        __builtin_amdgcn_s_setprio(0);
        asm volatile("s_waitcnt vmcnt(0)" ::: "memory");
        BARRIER();
        Ar = (Ar == 32768) ? 0 : Ar + 16384;
        Brel ^= 16384;
    }
    // ---- tile KT-1: fully resident; no staging, no barrier ----
    {
        const int Br = 49152 + Brel;
        LDA(Ar, 0);
        LDB(Br, 0, b0f);
        LDB(Br, 1, b1f);
        MFMA_Q(0, 0, b0f);
        MFMA_Q(0, 1, b1f);
        LDA(Ar, 1);
        MFMA_Q(1, 1, b1f);
        MFMA_Q(1, 0, b0f);
    }
#undef AOFF
#undef BOFF
#undef GLDS
#undef STAGE_A
#undef STAGE_B
#undef LDA
#undef LDB

    // ---- epilogue: C frag (col=lane&15 -> o, row=(lane>>4)*4+j -> pixel) ----
#pragma unroll
    for (int f = 0; f < 8; ++f) {
        const int prow = (f >> 2) * 128 + wm * 64 + (f & 3) * 16 + ((l >> 4) << 2);
#pragma unroll
        for (int g = 0; g < 4; ++g) {
            const int o = (g >> 1) * 128 + (g & 1) * 64 + wn * 16 + l15;
            float bb = 0.f;
            if (BIASRELU) bb = bias[o];
#pragma unroll
            for (int j = 0; j < 4; ++j) {
                int pix = Mbase + prow + j;
                int nn = pix >> 12, p = (pix >> 6) & 63, q = pix & 63;
                float val = acc[f][g][j] + bb;
                if (BIASRELU) val = fmaxf(val, 0.f);
                out[out_base + nn * out_img + p * out_row + q * 256 + o] = f2bf(val);
            }
        }
    }

    // ---- fused SE pooling: per-block column sums (deterministic) ----
    if (POOL) {
        float ps[4];
#pragma unroll
        for (int g = 0; g < 4; ++g) {
            float s = 0.f;
#pragma unroll
            for (int f = 0; f < 8; ++f)
#pragma unroll
                for (int j = 0; j < 4; ++j) s += acc[f][g][j];
            s += __shfl_xor(s, 16);
            s += __shfl_xor(s, 32);
            ps[g] = s;
        }
        // drain own LDS reads before reusing lds as float scratch
        asm volatile("s_waitcnt lgkmcnt(0)" ::: "memory");
        BARRIER();
        float* fl = (float*)lds;
        if ((l >> 4) == 0) {
#pragma unroll
            for (int g = 0; g < 4; ++g) {
                int o = (g >> 1) * 128 + (g & 1) * 64 + wn * 16 + l15;
                fl[wm * 256 + o] = ps[g];
            }
        }
        BARRIER();
        if (tid < 256)
            pool_out[blockIdx.x * 256 + tid] = fl[tid] + fl[256 + tid];
    }
#undef MFMA_Q
#undef BARRIER
}

// ---------------------------------------------------------------------------
// old 128x128 2-phase conv (kept for the tiny 1x1 residual conv, K=128)
// ---------------------------------------------------------------------------
template <int CIN, int NTAPS, int STRIDE, bool BIASRELU>
__global__ __launch_bounds__(256, 2)
void conv_mfma(const u16* __restrict__ in, const u16* __restrict__ wt,
               const float* __restrict__ bias, u16* __restrict__ out,
               int in_row, int in_img, int out_base, int out_row, int out_img) {
    constexpr int CSTEPS = CIN / 64;
    constexpr int KSTEPS = CSTEPS * NTAPS;
    __shared__ u16 lA[128 * 64];
    __shared__ u16 lB[128 * 64];

    const int tid = threadIdx.x;
    const int w = tid >> 6, l = tid & 63;
    const int bn = blockIdx.x & 1;
    const int Mbase = (blockIdx.x >> 1) << 7;
    const int wm = w >> 1, wn = w & 1;
    const int srow = l >> 3;
    const int chunk = l & 7;

    int abase[4], wbase[4];
#pragma unroll
    for (int i = 0; i < 4; ++i) {
        int pix = w * 32 + i * 8 + srow;
        int mm = Mbase + pix;
        int nn = mm >> 12, p = (mm >> 6) & 63, q = mm & 63;
        abase[i] = nn * in_img + (STRIDE * p) * in_row + (STRIDE * q) * CIN + chunk * 8;
        wbase[i] = (bn * 128 + pix) * CIN + chunk * 8;
    }

    f32x4 acc[4][4] = {};

    int abyte[4], bbyte[4];
#pragma unroll
    for (int f = 0; f < 4; ++f) {
        abyte[f] = ((wm * 64 + f * 16 + (l & 15)) * 64 + ((l >> 4) * 8)) * 2;
        bbyte[f] = ((wn * 64 + f * 16 + (l & 15)) * 64 + ((l >> 4) * 8)) * 2;
    }

    for (int ks = 0; ks < KSTEPS; ++ks) {
        const int tap = ks / CSTEPS;
        const int c0 = (ks % CSTEPS) * 64;
        const int dy = (NTAPS == 9) ? (tap / 3) : 0;
        const int dx = (NTAPS == 9) ? (tap - dy * 3) : 0;
        const int aoff = dy * in_row + dx * CIN + c0;
        const int boff = tap * 256 * CIN + c0;
        __syncthreads();
#pragma unroll
        for (int i = 0; i < 4; ++i) {
            const u16* gsrc = in + abase[i] + aoff;
            u16* ldst = &lA[(w * 32 + i * 8) * 64];
            __builtin_amdgcn_global_load_lds((__attribute__((address_space(1))) void*)gsrc,
                                             (__attribute__((address_space(3))) void*)ldst,
                                             16, 0, 0);
        }
#pragma unroll
        for (int i = 0; i < 4; ++i) {
            const u16* gsrc = wt + wbase[i] + boff;
            u16* ldst = &lB[(w * 32 + i * 8) * 64];
            __builtin_amdgcn_global_load_lds((__attribute__((address_space(1))) void*)gsrc,
                                             (__attribute__((address_space(3))) void*)ldst,
                                             16, 0, 0);
        }
        __syncthreads();
#pragma unroll
        for (int kk = 0; kk < 2; ++kk) {
            bf16x8 af[4], bv[4];
#pragma unroll
            for (int f = 0; f < 4; ++f)
                af[f] = *(const bf16x8*)((const char*)lA + abyte[f] + kk * 64);
#pragma unroll
            for (int f = 0; f < 4; ++f)
                bv[f] = *(const bf16x8*)((const char*)lB + bbyte[f] + kk * 64);
#pragma unroll
            for (int fm = 0; fm < 4; ++fm)
#pragma unroll
                for (int fn = 0; fn < 4; ++fn)
                    acc[fm][fn] = __builtin_amdgcn_mfma_f32_16x16x32_bf16(
                        af[fm], bv[fn], acc[fm][fn], 0, 0, 0);
        }
    }

#pragma unroll
    for (int fm = 0; fm < 4; ++fm) {
        const int mloc = wm * 64 + fm * 16 + ((l >> 4) << 2);
#pragma unroll
        for (int fn = 0; fn < 4; ++fn) {
            const int o = bn * 128 + wn * 64 + fn * 16 + (l & 15);
            float bb = 0.f;
            if (BIASRELU) bb = bias[o];
#pragma unroll
            for (int j = 0; j < 4; ++j) {
                int mm = Mbase + mloc + j;
                int nn = mm >> 12, p = (mm >> 6) & 63, q = mm & 63;
                float val = acc[fm][fn][j] + bb;
                if (BIASRELU) val = fmaxf(val, 0.f);
                out[out_base + nn * out_img + p * out_row + q * 256 + o] = f2bf(val);
            }
        }
    }
}

// ---------------------------------------------------------------------------
// SE MLP: a = sigmoid(relu(mean @ w1^T + b1) @ w2^T + b2)
// partial layout: [256 blocks][256 o], block b covers image b>>4
// ---------------------------------------------------------------------------
__global__ void se_kernel(const float* __restrict__ partial,
                          const float* __restrict__ w1, const float* __restrict__ b1,
                          const float* __restrict__ w2, const float* __restrict__ b2,
                          float* __restrict__ a) {
    __shared__ float sm[16 * 256];
    __shared__ float hl[16 * 16];
    int t = threadIdx.x;
    for (int n = 0; n < 16; ++n) {
        float s = 0.f;
#pragma unroll
        for (int k = 0; k < 16; ++k) s += partial[(n * 16 + k) * 256 + t];
        sm[n * 256 + t] = s * (1.0f / 4096.0f);
    }
    __syncthreads();
    {
        int bb = t >> 4, j = t & 15;
        float d = b1[j];
        for (int c = 0; c < 256; ++c) d += sm[bb * 256 + c] * w1[j * 256 + c];
        hl[bb * 16 + j] = fmaxf(d, 0.f);
    }
    __syncthreads();
    {
        int o = t;
        for (int bb = 0; bb < 16; ++bb) {
            float z = b2[o];
            for (int j = 0; j < 16; ++j) z += hl[bb * 16 + j] * w2[o * 16 + j];
            a[bb * 256 + o] = 1.0f / (1.0f + expf(-z));
        }
    }
}

// ---------------------------------------------------------------------------
// K5: out[n][o][p][q] = h2[n][p][q][o]*a[n][o] + res[n][p][q][o]
// ---------------------------------------------------------------------------
__global__ void finalize_kernel(const u16* __restrict__ h2, const u16* __restrict__ res,
                                const float* __restrict__ a, float* __restrict__ out) {
    __shared__ u16 th[256 * 68];
    __shared__ float al[256];
    int n = blockIdx.x >> 6, p = blockIdx.x & 63;
    int t = threadIdx.x;
    al[t] = a[n * 256 + t];
    __syncthreads();
    int o8 = (t & 31) << 3, qr = t >> 5;
    int pixbase = n * 4096 + p * 64;
#pragma unroll
    for (int qi = 0; qi < 8; ++qi) {
        int q = qi * 8 + qr;
        int gi = (pixbase + q) * 256 + o8;
        u16x8 hv = *(const u16x8*)(h2 + gi);
        u16x8 rv = *(const u16x8*)(res + gi);
#pragma unroll
        for (int k = 0; k < 8; ++k) {
            float vv = bf2f(hv[k]) * al[o8 + k] + bf2f(rv[k]);
            th[(o8 + k) * 68 + q] = f2bf(vv);
        }
    }
    __syncthreads();
    int q4 = (t & 15) << 2, ob = t >> 4;
#pragma unroll
    for (int oi = 0; oi < 16; ++oi) {
        int o = oi * 16 + ob;
        float4 vv;
        vv.x = bf2f(th[o * 68 + q4 + 0]);
        vv.y = bf2f(th[o * 68 + q4 + 1]);
        vv.z = bf2f(th[o * 68 + q4 + 2]);
        vv.w = bf2f(th[o * 68 + q4 + 3]);
        *(float4*)(out + ((n * 256 + o) * 64 + p) * 64 + q4) = vv;
    }
}

// ---------------------------------------------------------------------------
// workspace layout (bytes)
// ---------------------------------------------------------------------------
static const size_t OFF_PRE  = 0;                       // 68,161,536 ; reused for h2
static const size_t OFF_H1   = 68161536;                // 35,684,352
static const size_t OFF_RES  = 103845888;               // 33,554,432
static const size_t OFF_W1T  = 137400320;               // 589,824
static const size_t OFF_W2T  = 137990144;               // 1,179,648
static const size_t OFF_WRT  = 139169792;               // 65,536
static const size_t OFF_B2F  = 139235328;               // 1,024
static const size_t OFF_PART = 139236352;               // 262,144 (256 blocks x 256 f32)
static const size_t OFF_A    = 139760640;               // 16,384

extern "C" void kernel_launch(void* const* d_in, const int* in_sizes, int n_in,
                              void* d_out, int out_size, void* d_ws, size_t ws_size,
                              hipStream_t stream) {
    (void)in_sizes; (void)n_in; (void)out_size; (void)ws_size;
    const float* x      = (const float*)d_in[0];
    const float* bn1_g  = (const float*)d_in[1];
    const float* bn1_b  = (const float*)d_in[2];
    const float* bn1_m  = (const float*)d_in[3];
    const float* bn1_v  = (const float*)d_in[4];
    const float* bn2_g  = (const float*)d_in[5];
    const float* bn2_b  = (const float*)d_in[6];
    const float* bn2_m  = (const float*)d_in[7];
    const float* bn2_v  = (const float*)d_in[8];
    const float* wc1    = (const float*)d_in[9];
    const float* wc2    = (const float*)d_in[10];
    const float* wres   = (const float*)d_in[11];
    const float* se_w1  = (const float*)d_in[12];
    const float* se_b1  = (const float*)d_in[13];
    const float* se_w2  = (const float*)d_in[14];
    const float* se_b2  = (const float*)d_in[15];

    char* ws = (char*)d_ws;
    u16*   pre    = (u16*)(ws + OFF_PRE);
    u16*   h2     = (u16*)(ws + OFF_PRE);   // aliases pre (dead by conv2)
    u16*   h1     = (u16*)(ws + OFF_H1);
    u16*   res    = (u16*)(ws + OFF_RES);
    u16*   w1t    = (u16*)(ws + OFF_W1T);
    u16*   w2t    = (u16*)(ws + OFF_W2T);
    u16*   wrt    = (u16*)(ws + OFF_WRT);
    float* bias2f = (float*)(ws + OFF_B2F);
    float* part   = (float*)(ws + OFF_PART);
    float* avec   = (float*)(ws + OFF_A);
    float* out    = (float*)d_out;

    setup_kernel<<<9801, 256, 0, stream>>>(wc1, wc2, wres, bn2_g, bn2_b, bn2_m, bn2_v,
                                           w1t, w2t, wrt, bias2f, pre, h1);
    pre_kernel<<<2048, 256, 0, stream>>>(x, bn1_g, bn1_b, bn1_m, bn1_v, pre);

    // conv1: 3x3 s2, 128->256, +BN2(bias)+ReLU, out = padded h1 (base (1,1))
    conv_8ph<128, 9, 2, true, false><<<256, 512, 0, stream>>>(
        pre, w1t, bias2f, h1, nullptr,
        129 * 128, 129 * 129 * 128,
        67 * 256, 66 * 256, 66 * 66 * 256);

    // residual: 1x1 s2, 128->256 (old small-tile kernel)
    conv_mfma<128, 1, 2, false><<<1024, 256, 0, stream>>>(
        pre, wrt, nullptr, res,
        129 * 128, 129 * 129 * 128,
        0, 64 * 256, 4096 * 256);

    // conv2: 3x3 s1, 256->256 (h2 overwrites pre region) + fused SE pooling
    conv_8ph<256, 9, 1, false, true><<<256, 512, 0, stream>>>(
        h1, w2t, nullptr, h2, part,
        66 * 256, 66 * 66 * 256,
        0, 64 * 256, 4096 * 256);

    se_kernel<<<1, 256, 0, stream>>>(part, se_w1, se_b1, se_w2, se_b2, avec);
    finalize_kernel<<<1024, 256, 0, stream>>>(h2, res, avec, out);
}

// Round 6
// 209.304 us; speedup vs baseline: 1.5559x; 1.0173x over previous
//
#include <hip/hip_runtime.h>

typedef unsigned short u16;
typedef __attribute__((ext_vector_type(8))) unsigned short u16x8;
typedef __attribute__((ext_vector_type(8))) __bf16 bf16x8;
typedef __attribute__((ext_vector_type(4))) float f32x4;

__device__ __forceinline__ float bf2f(u16 u) {
    return __uint_as_float(((unsigned)u) << 16);
}
__device__ __forceinline__ u16 f2bf(float f) {
    unsigned u = __float_as_uint(f);
    return (u16)((u + 0x7FFFu + ((u >> 16) & 1u)) >> 16);
}

// ---------------------------------------------------------------------------
// setup kernel: weight transform + pad zeroing, one launch.
// ---------------------------------------------------------------------------
__global__ void setup_kernel(const float* __restrict__ w1, const float* __restrict__ w2,
                             const float* __restrict__ wr,
                             const float* __restrict__ g2, const float* __restrict__ b2,
                             const float* __restrict__ m2, const float* __restrict__ v2,
                             u16* __restrict__ w1t, u16* __restrict__ w2t,
                             u16* __restrict__ wrt, float* __restrict__ bias2f,
                             u16* __restrict__ pre, u16* __restrict__ h1) {
    int b = blockIdx.x;
    if (b < 3585) {
        int i = b * 256 + threadIdx.x;
        if (i < 294912) {
            int ci = i & 127; int t = i >> 7; int o = t & 255; int tap = t >> 8;
            int dy = tap / 3, dx = tap - dy * 3;
            float sc = g2[o] * rsqrtf(v2[o] + 1e-5f);
            w1t[i] = f2bf(w1[((o * 128 + ci) * 3 + dy) * 3 + dx] * sc);
        } else if (i < 294912 + 589824) {
            int j = i - 294912;
            int ci = j & 255; int t = j >> 8; int o = t & 255; int tap = t >> 8;
            int dy = tap / 3, dx = tap - dy * 3;
            w2t[j] = f2bf(w2[((o * 256 + ci) * 3 + dy) * 3 + dx]);
        } else if (i < 294912 + 589824 + 32768) {
            int j = i - (294912 + 589824);
            int ci = j & 127; int o = j >> 7;
            wrt[j] = f2bf(wr[o * 128 + ci]);
        } else {
            int o = i - (294912 + 589824 + 32768);
            if (o < 256) {
                float sc = g2[o] * rsqrtf(v2[o] + 1e-5f);
                bias2f[o] = b2[o] - m2[o] * sc;
            }
        }
    } else if (b < 3585 + 2056) {
        int i = (b - 3585) * 256 + threadIdx.x;
        if (i < 16 * 129 * 128) {
            int c = i & 127; int t = i >> 7; int n = t / 129; int xx = t - n * 129;
            pre[((n * 129 + 128) * 129 + xx) * 128 + c] = 0;
        } else {
            int j = i - 16 * 129 * 128;
            int c = j & 127; int t = j >> 7; int n = t >> 7; int y = t & 127;
            pre[((n * 129 + y) * 129 + 128) * 128 + c] = 0;
        }
    } else {
        int i = (b - (3585 + 2056)) * 256 + threadIdx.x;
        int c = i & 255;
        int t = i >> 8;
        int n = t / 260;
        int cl = t - n * 260;
        int y, x;
        if (cl < 66)       { y = 0;  x = cl; }
        else if (cl < 132) { y = 65; x = cl - 66; }
        else if (cl < 196) { x = 0;  y = cl - 131; }
        else               { x = 65; y = cl - 195; }
        h1[((n * 66 + y) * 66 + x) * 256 + c] = 0;
    }
}

// ---------------------------------------------------------------------------
// K1: pre = relu(BN1(x)), NCHW f32 -> padded NHWC bf16 (interior only)
// ---------------------------------------------------------------------------
__global__ void pre_kernel(const float* __restrict__ x, const float* __restrict__ g,
                           const float* __restrict__ b, const float* __restrict__ m,
                           const float* __restrict__ v, u16* __restrict__ pre) {
    __shared__ u16 tile[128 * 136];
    int n = blockIdx.x >> 7, y = blockIdx.x & 127;
    int tid = threadIdx.x;
    int c = tid >> 1, xh = (tid & 1) << 6;
    float sc = g[c] * rsqrtf(v[c] + 1e-5f);
    float bi = b[c] - m[c] * sc;
    const float4* src = (const float4*)(x + (((n * 128 + c) * 128 + y) << 7) + xh);
#pragma unroll
    for (int j = 0; j < 16; ++j) {
        float4 val = src[j];
        int xb = xh + j * 4;
        tile[(xb + 0) * 136 + c] = f2bf(fmaxf(val.x * sc + bi, 0.f));
        tile[(xb + 1) * 136 + c] = f2bf(fmaxf(val.y * sc + bi, 0.f));
        tile[(xb + 2) * 136 + c] = f2bf(fmaxf(val.z * sc + bi, 0.f));
        tile[(xb + 3) * 136 + c] = f2bf(fmaxf(val.w * sc + bi, 0.f));
    }
    __syncthreads();
    int c0 = (tid & 15) << 3;
#pragma unroll
    for (int xi = 0; xi < 8; ++xi) {
        int xx = xi * 16 + (tid >> 4);
        u16x8 val = *(const u16x8*)&tile[xx * 136 + c0];
        *(u16x8*)(pre + ((n * 129 + y) * 129 + xx) * 128 + c0) = val;
    }
}

// ===========================================================================
// 256x256 implicit-GEMM conv.  A triple-buffered, B double-buffered.
// Deferred-quadrant software pipeline (zero extra registers):
//   tile t: (0,0) (0,1) (1,1) [vmcnt(4); barrier] LDB0(t+1)->dead b-set; (1,0)
//   -> the last quadrant's 16 reg-only MFMAs overlap the next tile's B0 reads
//   and the next tile's first MFMA waits on 12 (not 16) ds_reads.
// B register sets swap b0/b1 roles each tile (loop unrolled x2, named sets).
// T1: XCD-aware block swizzle (grid 256, 8 XCDs, 32 contiguous tiles/XCD).
// T2 swizzle via inverse-swizzled global source + swizzled ds_read.
// POOL: conv2 fuses the SE global-avg partial sums into the epilogue.
// ===========================================================================
template <int CIN, int NTAPS, int STRIDE, bool BIASRELU, bool POOL>
__global__ __launch_bounds__(512, 2)
void conv_8ph(const u16* __restrict__ in, const u16* __restrict__ wt,
              const float* __restrict__ bias, u16* __restrict__ out,
              float* __restrict__ pool_out,
              int in_row, int in_img, int out_base, int out_row, int out_img) {
    constexpr int CSTEPS = CIN / 64;
    constexpr int KT = CSTEPS * NTAPS;
    // A buffers: 0, 16384, 32768 ; B buffers: 49152, 65536   (u16 units)
    __shared__ __attribute__((aligned(16))) u16 lds[81920];

    const int tid = threadIdx.x;
    const int w = tid >> 6, l = tid & 63;
    const int wm = w >> 2, wn = w & 3;
    const int l15 = l & 15;
    // T1: XCD-aware swizzle (bijective, 256 % 8 == 0)
    const int bid = ((blockIdx.x & 7) << 5) | (blockIdx.x >> 3);
    const int Mbase = bid << 8;

    const int srow = tid >> 3;
    const int swze = (((tid & 7) ^ (srow & 7)) << 3);
    int pix0 = Mbase + srow;
    int nn0 = pix0 >> 12, p0 = (pix0 >> 6) & 63, q0 = pix0 & 63;
    const int abase0 = nn0 * in_img + (STRIDE * p0) * in_row + (STRIDE * q0) * CIN + swze;
    const int astep = STRIDE * in_row;
    const int bbase0 = srow * CIN + swze;
    const int bstep = 64 * CIN;

    int colw[2];
#pragma unroll
    for (int kk = 0; kk < 2; ++kk)
        colw[kk] = (kk * 32 + (l >> 4) * 8) ^ ((l & 7) << 3);

    f32x4 acc[8][4] = {};
    bf16x8 afr[4][2], bXf[2][2], bYf[2][2];

#define AOFF(ks) (((NTAPS == 9) ? ((((ks) / CSTEPS) / 3) * in_row + (((ks) / CSTEPS) % 3) * CIN) : 0) + ((ks) % CSTEPS) * 64)
#define BOFF(ks) (((ks) / CSTEPS) * 256 * CIN + ((ks) % CSTEPS) * 64)
#define GLDS(gsrc, ldst) __builtin_amdgcn_global_load_lds(                          \
        (__attribute__((address_space(1))) void*)(gsrc),                            \
        (__attribute__((address_space(3))) void*)(ldst), 16, 0, 0)
#define STAGE_A(base, h, ks) {                                                      \
    int _ao = AOFF(ks);                                                             \
    GLDS(in + abase0 + (2 * (h) + 0) * astep + _ao,                                 \
         &lds[(base) + (h) * 8192 + 0 * 4096 + w * 512]);                           \
    GLDS(in + abase0 + (2 * (h) + 1) * astep + _ao,                                 \
         &lds[(base) + (h) * 8192 + 1 * 4096 + w * 512]); }
#define STAGE_B(base, h, ks) {                                                      \
    int _bo = BOFF(ks);                                                             \
    GLDS(wt + bbase0 + (2 * (h) + 0) * bstep + _bo,                                 \
         &lds[(base) + (h) * 8192 + 0 * 4096 + w * 512]);                           \
    GLDS(wt + bbase0 + (2 * (h) + 1) * bstep + _bo,                                 \
         &lds[(base) + (h) * 8192 + 1 * 4096 + w * 512]); }
#define BARRIER() { __builtin_amdgcn_s_barrier(); asm volatile("" ::: "memory"); }
#define LDA(base, MH) {                                                             \
    _Pragma("unroll") for (int fm = 0; fm < 4; ++fm)                                \
    _Pragma("unroll") for (int kk = 0; kk < 2; ++kk)                                \
        afr[fm][kk] = *(const bf16x8*)&lds[(base) + ((MH) * 128 + wm * 64 + fm * 16 + l15) * 64 + colw[kk]]; }
#define LDB(base, NH, dst) {                                                        \
    _Pragma("unroll") for (int gn = 0; gn < 2; ++gn)                                \
    _Pragma("unroll") for (int kk = 0; kk < 2; ++kk)                                \
        dst[gn][kk] = *(const bf16x8*)&lds[(base) + ((NH) * 128 + gn * 64 + wn * 16 + l15) * 64 + colw[kk]]; }
#define MFMA_Q(MH, NH, bset) {                                                      \
    _Pragma("unroll") for (int fm = 0; fm < 4; ++fm)                                \
    _Pragma("unroll") for (int gn = 0; gn < 2; ++gn)                                \
    _Pragma("unroll") for (int kk = 0; kk < 2; ++kk)                                \
        acc[(MH) * 4 + fm][(NH) * 2 + gn] = __builtin_amdgcn_mfma_f32_16x16x32_bf16( \
            afr[fm][kk], bset[gn][kk], acc[(MH) * 4 + fm][(NH) * 2 + gn], 0, 0, 0); }

    // ---- prologue: A(0),B(0),A(1); drain A(0)+B(0), keep A(1) flying ----
    STAGE_A(0, 0, 0); STAGE_A(0, 1, 0);
    STAGE_B(49152, 0, 0); STAGE_B(49152, 1, 0);
    STAGE_A(16384, 0, 1); STAGE_A(16384, 1, 1);
    asm volatile("s_waitcnt vmcnt(4)" ::: "memory");
    BARRIER();

    int Ar = 0;          // A read slot (tile t)
    int As = 32768;      // A stage slot (tile t+2)
    int Brel = 0;        // B read slot rel offset; stage = ^16384

    // ---- init: load B0(0) into bX (tile 0: b0-role = bX) ----
    LDB(49152, 0, bXf);

    // BODY(t, B0, B1): quadrants (0,0)(0,1)(1,1) then deferred (1,0) after
    // the boundary barrier, overlapped with LDB0(t+1) into the B1 set.
#define CBODY(T, B0, B1, STAGEA, VM)                                                \
    {                                                                               \
        const int Br = 49152 + Brel, Bs = 49152 + (Brel ^ 16384);                   \
        LDA(Ar, 0);                                                                 \
        LDB(Br, 1, B1);                                                             \
        STAGE_B(Bs, 0, (T) + 1); STAGE_B(Bs, 1, (T) + 1);                           \
        __builtin_amdgcn_s_setprio(1);                                              \
        MFMA_Q(0, 0, B0);                                                           \
        MFMA_Q(0, 1, B1);                                                           \
        __builtin_amdgcn_s_setprio(0);                                              \
        LDA(Ar, 1);                                                                 \
        if (STAGEA) { STAGE_A(As, 0, (T) + 2); STAGE_A(As, 1, (T) + 2); }           \
        __builtin_amdgcn_s_setprio(1);                                              \
        MFMA_Q(1, 1, B1);                                                           \
        __builtin_amdgcn_s_setprio(0);                                              \
        asm volatile("s_waitcnt vmcnt(" #VM ")" ::: "memory");                      \
        BARRIER();                                                                  \
        LDB(49152 + (Brel ^ 16384), 0, B1);  /* next tile's b0 -> dead set */       \
        __builtin_amdgcn_s_setprio(1);                                              \
        MFMA_Q(1, 0, B0);                    /* deferred, reg-only */               \
        __builtin_amdgcn_s_setprio(0);                                              \
        Ar = (Ar == 32768) ? 0 : Ar + 16384;                                        \
        As = (As == 32768) ? 0 : As + 16384;                                        \
        Brel ^= 16384;                                                              \
    }

    // ---- steady loop: (KT-2) tiles, even count for all KT in {2,18,36} ----
#pragma unroll 1
    for (int t = 0; t < KT - 2; t += 2) {
        CBODY(t,     bXf, bYf, true, 4);
        CBODY(t + 1, bYf, bXf, true, 4);
    }

    // ---- tile KT-2 (b0=bX): stage only B(KT-1); drain everything ----
    CBODY(KT - 2, bXf, bYf, false, 0);

    // ---- tile KT-1 (b0=bY): fully resident; no staging, no barrier ----
    {
        const int Br = 49152 + Brel;
        LDA(Ar, 0);
        LDB(Br, 1, bXf);
        MFMA_Q(0, 0, bYf);
        MFMA_Q(0, 1, bXf);
        LDA(Ar, 1);
        MFMA_Q(1, 1, bXf);
        MFMA_Q(1, 0, bYf);
    }
#undef CBODY
#undef AOFF
#undef BOFF
#undef GLDS
#undef STAGE_A
#undef STAGE_B
#undef LDA
#undef LDB

    // ---- epilogue: C frag (col=lane&15 -> o, row=(lane>>4)*4+j -> pixel) ----
#pragma unroll
    for (int f = 0; f < 8; ++f) {
        const int prow = (f >> 2) * 128 + wm * 64 + (f & 3) * 16 + ((l >> 4) << 2);
#pragma unroll
        for (int g = 0; g < 4; ++g) {
            const int o = (g >> 1) * 128 + (g & 1) * 64 + wn * 16 + l15;
            float bb = 0.f;
            if (BIASRELU) bb = bias[o];
#pragma unroll
            for (int j = 0; j < 4; ++j) {
                int pix = Mbase + prow + j;
                int nn = pix >> 12, p = (pix >> 6) & 63, q = pix & 63;
                float val = acc[f][g][j] + bb;
                if (BIASRELU) val = fmaxf(val, 0.f);
                out[out_base + nn * out_img + p * out_row + q * 256 + o] = f2bf(val);
            }
        }
    }

    // ---- fused SE pooling: per-block column sums (deterministic) ----
    if (POOL) {
        float ps[4];
#pragma unroll
        for (int g = 0; g < 4; ++g) {
            float s = 0.f;
#pragma unroll
            for (int f = 0; f < 8; ++f)
#pragma unroll
                for (int j = 0; j < 4; ++j) s += acc[f][g][j];
            s += __shfl_xor(s, 16);
            s += __shfl_xor(s, 32);
            ps[g] = s;
        }
        // drain own LDS reads before reusing lds as float scratch
        asm volatile("s_waitcnt lgkmcnt(0)" ::: "memory");
        BARRIER();
        float* fl = (float*)lds;
        if ((l >> 4) == 0) {
#pragma unroll
            for (int g = 0; g < 4; ++g) {
                int o = (g >> 1) * 128 + (g & 1) * 64 + wn * 16 + l15;
                fl[wm * 256 + o] = ps[g];
            }
        }
        BARRIER();
        if (tid < 256)
            pool_out[bid * 256 + tid] = fl[tid] + fl[256 + tid];
    }
#undef MFMA_Q
#undef BARRIER
}

// ---------------------------------------------------------------------------
// SE MLP: a = sigmoid(relu(mean @ w1^T + b1) @ w2^T + b2)
// partial layout: [256 tiles][256 o], tile b covers image b>>4
// ---------------------------------------------------------------------------
__global__ void se_kernel(const float* __restrict__ partial,
                          const float* __restrict__ w1, const float* __restrict__ b1,
                          const float* __restrict__ w2, const float* __restrict__ b2,
                          float* __restrict__ a) {
    __shared__ float sm[16 * 256];
    __shared__ float hl[16 * 16];
    int t = threadIdx.x;
    for (int n = 0; n < 16; ++n) {
        float s = 0.f;
#pragma unroll
        for (int k = 0; k < 16; ++k) s += partial[(n * 16 + k) * 256 + t];
        sm[n * 256 + t] = s * (1.0f / 4096.0f);
    }
    __syncthreads();
    {
        int bb = t >> 4, j = t & 15;
        float d = b1[j];
        for (int c = 0; c < 256; ++c) d += sm[bb * 256 + c] * w1[j * 256 + c];
        hl[bb * 16 + j] = fmaxf(d, 0.f);
    }
    __syncthreads();
    {
        int o = t;
        for (int bb = 0; bb < 16; ++bb) {
            float z = b2[o];
            for (int j = 0; j < 16; ++j) z += hl[bb * 16 + j] * w2[o * 16 + j];
            a[bb * 256 + o] = 1.0f / (1.0f + expf(-z));
        }
    }
}

// ---------------------------------------------------------------------------
// K5: out[n][o][p][q] = h2[n][p][q][o]*a[n][o] + res[n][p][q][o]
// ---------------------------------------------------------------------------
__global__ void finalize_kernel(const u16* __restrict__ h2, const u16* __restrict__ res,
                                const float* __restrict__ a, float* __restrict__ out) {
    __shared__ u16 th[256 * 68];
    __shared__ float al[256];
    int n = blockIdx.x >> 6, p = blockIdx.x & 63;
    int t = threadIdx.x;
    al[t] = a[n * 256 + t];
    __syncthreads();
    int o8 = (t & 31) << 3, qr = t >> 5;
    int pixbase = n * 4096 + p * 64;
#pragma unroll
    for (int qi = 0; qi < 8; ++qi) {
        int q = qi * 8 + qr;
        int gi = (pixbase + q) * 256 + o8;
        u16x8 hv = *(const u16x8*)(h2 + gi);
        u16x8 rv = *(const u16x8*)(res + gi);
#pragma unroll
        for (int k = 0; k < 8; ++k) {
            float vv = bf2f(hv[k]) * al[o8 + k] + bf2f(rv[k]);
            th[(o8 + k) * 68 + q] = f2bf(vv);
        }
    }
    __syncthreads();
    int q4 = (t & 15) << 2, ob = t >> 4;
#pragma unroll
    for (int oi = 0; oi < 16; ++oi) {
        int o = oi * 16 + ob;
        float4 vv;
        vv.x = bf2f(th[o * 68 + q4 + 0]);
        vv.y = bf2f(th[o * 68 + q4 + 1]);
        vv.z = bf2f(th[o * 68 + q4 + 2]);
        vv.w = bf2f(th[o * 68 + q4 + 3]);
        *(float4*)(out + ((n * 256 + o) * 64 + p) * 64 + q4) = vv;
    }
}

// ---------------------------------------------------------------------------
// workspace layout (bytes)
// ---------------------------------------------------------------------------
static const size_t OFF_PRE  = 0;                       // 68,161,536 ; reused for h2
static const size_t OFF_H1   = 68161536;                // 35,684,352
static const size_t OFF_RES  = 103845888;               // 33,554,432
static const size_t OFF_W1T  = 137400320;               // 589,824
static const size_t OFF_W2T  = 137990144;               // 1,179,648
static const size_t OFF_WRT  = 139169792;               // 65,536
static const size_t OFF_B2F  = 139235328;               // 1,024
static const size_t OFF_PART = 139236352;               // 262,144 (256 tiles x 256 f32)
static const size_t OFF_A    = 139760640;               // 16,384

extern "C" void kernel_launch(void* const* d_in, const int* in_sizes, int n_in,
                              void* d_out, int out_size, void* d_ws, size_t ws_size,
                              hipStream_t stream) {
    (void)in_sizes; (void)n_in; (void)out_size; (void)ws_size;
    const float* x      = (const float*)d_in[0];
    const float* bn1_g  = (const float*)d_in[1];
    const float* bn1_b  = (const float*)d_in[2];
    const float* bn1_m  = (const float*)d_in[3];
    const float* bn1_v  = (const float*)d_in[4];
    const float* bn2_g  = (const float*)d_in[5];
    const float* bn2_b  = (const float*)d_in[6];
    const float* bn2_m  = (const float*)d_in[7];
    const float* bn2_v  = (const float*)d_in[8];
    const float* wc1    = (const float*)d_in[9];
    const float* wc2    = (const float*)d_in[10];
    const float* wres   = (const float*)d_in[11];
    const float* se_w1  = (const float*)d_in[12];
    const float* se_b1  = (const float*)d_in[13];
    const float* se_w2  = (const float*)d_in[14];
    const float* se_b2  = (const float*)d_in[15];

    char* ws = (char*)d_ws;
    u16*   pre    = (u16*)(ws + OFF_PRE);
    u16*   h2     = (u16*)(ws + OFF_PRE);   // aliases pre (dead by conv2)
    u16*   h1     = (u16*)(ws + OFF_H1);
    u16*   res    = (u16*)(ws + OFF_RES);
    u16*   w1t    = (u16*)(ws + OFF_W1T);
    u16*   w2t    = (u16*)(ws + OFF_W2T);
    u16*   wrt    = (u16*)(ws + OFF_WRT);
    float* bias2f = (float*)(ws + OFF_B2F);
    float* part   = (float*)(ws + OFF_PART);
    float* avec   = (float*)(ws + OFF_A);
    float* out    = (float*)d_out;

    setup_kernel<<<9801, 256, 0, stream>>>(wc1, wc2, wres, bn2_g, bn2_b, bn2_m, bn2_v,
                                           w1t, w2t, wrt, bias2f, pre, h1);
    pre_kernel<<<2048, 256, 0, stream>>>(x, bn1_g, bn1_b, bn1_m, bn1_v, pre);

    // conv1: 3x3 s2, 128->256, +BN2(bias)+ReLU, out = padded h1 (base (1,1))
    conv_8ph<128, 9, 2, true, false><<<256, 512, 0, stream>>>(
        pre, w1t, bias2f, h1, nullptr,
        129 * 128, 129 * 129 * 128,
        67 * 256, 66 * 256, 66 * 66 * 256);

    // residual: 1x1 s2, 128->256 (8ph template, KT=2)
    conv_8ph<128, 1, 2, false, false><<<256, 512, 0, stream>>>(
        pre, wrt, nullptr, res, nullptr,
        129 * 128, 129 * 129 * 128,
        0, 64 * 256, 4096 * 256);

    // conv2: 3x3 s1, 256->256 (h2 overwrites pre region) + fused SE pooling
    conv_8ph<256, 9, 1, false, true><<<256, 512, 0, stream>>>(
        h1, w2t, nullptr, h2, part,
        66 * 256, 66 * 66 * 256,
        0, 64 * 256, 4096 * 256);

    se_kernel<<<1, 256, 0, stream>>>(part, se_w1, se_b1, se_w2, se_b2, avec);
    finalize_kernel<<<1024, 256, 0, stream>>>(h2, res, avec, out);
}

// Round 7
// 201.554 us; speedup vs baseline: 1.6157x; 1.0385x over previous
//
#include <hip/hip_runtime.h>

typedef unsigned short u16;
typedef __attribute__((ext_vector_type(8))) unsigned short u16x8;
typedef __attribute__((ext_vector_type(8))) __bf16 bf16x8;
typedef __attribute__((ext_vector_type(4))) float f32x4;

__device__ __forceinline__ float bf2f(u16 u) {
    return __uint_as_float(((unsigned)u) << 16);
}
__device__ __forceinline__ u16 f2bf(float f) {
    unsigned u = __float_as_uint(f);
    return (u16)((u + 0x7FFFu + ((u >> 16) & 1u)) >> 16);
}

// ---------------------------------------------------------------------------
// setup kernel: weight transform + pad zeroing + pre=relu(BN1(x)) transpose,
// one launch, block-range dispatch.
//   [0,3585): weights; [3585,5641): pre pad; [5641,9801): h1 pad;
//   [9801,11849): pre BN+ReLU NCHW f32 -> padded NHWC bf16 (interior)
// ---------------------------------------------------------------------------
__global__ void setup_kernel(const float* __restrict__ x,
                             const float* __restrict__ g1, const float* __restrict__ b1,
                             const float* __restrict__ m1, const float* __restrict__ v1,
                             const float* __restrict__ w1, const float* __restrict__ w2,
                             const float* __restrict__ wr,
                             const float* __restrict__ g2, const float* __restrict__ b2,
                             const float* __restrict__ m2, const float* __restrict__ v2,
                             u16* __restrict__ w1t, u16* __restrict__ w2t,
                             u16* __restrict__ wrt, float* __restrict__ bias2f,
                             u16* __restrict__ pre, u16* __restrict__ h1) {
    __shared__ u16 tile[128 * 136];
    int b = blockIdx.x;
    if (b < 3585) {
        int i = b * 256 + threadIdx.x;
        if (i < 294912) {
            int ci = i & 127; int t = i >> 7; int o = t & 255; int tap = t >> 8;
            int dy = tap / 3, dx = tap - dy * 3;
            float sc = g2[o] * rsqrtf(v2[o] + 1e-5f);
            w1t[i] = f2bf(w1[((o * 128 + ci) * 3 + dy) * 3 + dx] * sc);
        } else if (i < 294912 + 589824) {
            int j = i - 294912;
            int ci = j & 255; int t = j >> 8; int o = t & 255; int tap = t >> 8;
            int dy = tap / 3, dx = tap - dy * 3;
            w2t[j] = f2bf(w2[((o * 256 + ci) * 3 + dy) * 3 + dx]);
        } else if (i < 294912 + 589824 + 32768) {
            int j = i - (294912 + 589824);
            int ci = j & 127; int o = j >> 7;
            wrt[j] = f2bf(wr[o * 128 + ci]);
        } else {
            int o = i - (294912 + 589824 + 32768);
            if (o < 256) {
                float sc = g2[o] * rsqrtf(v2[o] + 1e-5f);
                bias2f[o] = b2[o] - m2[o] * sc;
            }
        }
    } else if (b < 3585 + 2056) {
        int i = (b - 3585) * 256 + threadIdx.x;
        if (i < 16 * 129 * 128) {
            int c = i & 127; int t = i >> 7; int n = t / 129; int xx = t - n * 129;
            pre[((n * 129 + 128) * 129 + xx) * 128 + c] = 0;
        } else {
            int j = i - 16 * 129 * 128;
            int c = j & 127; int t = j >> 7; int n = t >> 7; int y = t & 127;
            pre[((n * 129 + y) * 129 + 128) * 128 + c] = 0;
        }
    } else if (b < 3585 + 2056 + 4160) {
        int i = (b - (3585 + 2056)) * 256 + threadIdx.x;
        int c = i & 255;
        int t = i >> 8;
        int n = t / 260;
        int cl = t - n * 260;
        int y, x2;
        if (cl < 66)       { y = 0;  x2 = cl; }
        else if (cl < 132) { y = 65; x2 = cl - 66; }
        else if (cl < 196) { x2 = 0; y = cl - 131; }
        else               { x2 = 65; y = cl - 195; }
        h1[((n * 66 + y) * 66 + x2) * 256 + c] = 0;
    } else {
        int pb = b - (3585 + 2056 + 4160);
        int n = pb >> 7, y = pb & 127;
        int tid = threadIdx.x;
        int c = tid >> 1, xh = (tid & 1) << 6;
        float sc = g1[c] * rsqrtf(v1[c] + 1e-5f);
        float bi = b1[c] - m1[c] * sc;
        const float4* src = (const float4*)(x + (((n * 128 + c) * 128 + y) << 7) + xh);
#pragma unroll
        for (int j = 0; j < 16; ++j) {
            float4 val = src[j];
            int xb = xh + j * 4;
            tile[(xb + 0) * 136 + c] = f2bf(fmaxf(val.x * sc + bi, 0.f));
            tile[(xb + 1) * 136 + c] = f2bf(fmaxf(val.y * sc + bi, 0.f));
            tile[(xb + 2) * 136 + c] = f2bf(fmaxf(val.z * sc + bi, 0.f));
            tile[(xb + 3) * 136 + c] = f2bf(fmaxf(val.w * sc + bi, 0.f));
        }
        __syncthreads();
        int c0 = (tid & 15) << 3;
#pragma unroll
        for (int xi = 0; xi < 8; ++xi) {
            int xx = xi * 16 + (tid >> 4);
            u16x8 val = *(const u16x8*)&tile[xx * 136 + c0];
            *(u16x8*)(pre + ((n * 129 + y) * 129 + xx) * 128 + c0) = val;
        }
    }
}

// ===========================================================================
// 256x256 implicit-GEMM conv.  A triple-buffered, B double-buffered.
// Deferred-quadrant software pipeline; one barrier + one counted vmcnt/tile.
// T1 XCD swizzle; T2 LDS swizzle via inverse-swizzled global source.
// POOL: conv2 fuses the SE global-avg partial sums into the epilogue.
// ===========================================================================
template <int CIN, int NTAPS, int STRIDE, bool BIASRELU, bool POOL>
__global__ __launch_bounds__(512, 2)
void conv_8ph(const u16* __restrict__ in, const u16* __restrict__ wt,
              const float* __restrict__ bias, u16* __restrict__ out,
              float* __restrict__ pool_out,
              int in_row, int in_img, int out_base, int out_row, int out_img) {
    constexpr int CSTEPS = CIN / 64;
    constexpr int KT = CSTEPS * NTAPS;
    // A buffers: 0, 16384, 32768 ; B buffers: 49152, 65536   (u16 units)
    __shared__ __attribute__((aligned(16))) u16 lds[81920];

    const int tid = threadIdx.x;
    const int w = tid >> 6, l = tid & 63;
    const int wm = w >> 2, wn = w & 3;
    const int l15 = l & 15;
    // T1: XCD-aware swizzle (bijective, 256 % 8 == 0)
    const int bid = ((blockIdx.x & 7) << 5) | (blockIdx.x >> 3);
    const int Mbase = bid << 8;

    const int srow = tid >> 3;
    const int swze = (((tid & 7) ^ (srow & 7)) << 3);
    int pix0 = Mbase + srow;
    int nn0 = pix0 >> 12, p0 = (pix0 >> 6) & 63, q0 = pix0 & 63;
    const int abase0 = nn0 * in_img + (STRIDE * p0) * in_row + (STRIDE * q0) * CIN + swze;
    const int astep = STRIDE * in_row;
    const int bbase0 = srow * CIN + swze;
    const int bstep = 64 * CIN;

    int colw[2];
#pragma unroll
    for (int kk = 0; kk < 2; ++kk)
        colw[kk] = (kk * 32 + (l >> 4) * 8) ^ ((l & 7) << 3);

    f32x4 acc[8][4] = {};
    bf16x8 afr[4][2], bXf[2][2], bYf[2][2];

#define AOFF(ks) (((NTAPS == 9) ? ((((ks) / CSTEPS) / 3) * in_row + (((ks) / CSTEPS) % 3) * CIN) : 0) + ((ks) % CSTEPS) * 64)
#define BOFF(ks) (((ks) / CSTEPS) * 256 * CIN + ((ks) % CSTEPS) * 64)
#define GLDS(gsrc, ldst) __builtin_amdgcn_global_load_lds(                          \
        (__attribute__((address_space(1))) void*)(gsrc),                            \
        (__attribute__((address_space(3))) void*)(ldst), 16, 0, 0)
#define STAGE_A(base, h, ks) {                                                      \
    int _ao = AOFF(ks);                                                             \
    GLDS(in + abase0 + (2 * (h) + 0) * astep + _ao,                                 \
         &lds[(base) + (h) * 8192 + 0 * 4096 + w * 512]);                           \
    GLDS(in + abase0 + (2 * (h) + 1) * astep + _ao,                                 \
         &lds[(base) + (h) * 8192 + 1 * 4096 + w * 512]); }
#define STAGE_B(base, h, ks) {                                                      \
    int _bo = BOFF(ks);                                                             \
    GLDS(wt + bbase0 + (2 * (h) + 0) * bstep + _bo,                                 \
         &lds[(base) + (h) * 8192 + 0 * 4096 + w * 512]);                           \
    GLDS(wt + bbase0 + (2 * (h) + 1) * bstep + _bo,                                 \
         &lds[(base) + (h) * 8192 + 1 * 4096 + w * 512]); }
#define BARRIER() { __builtin_amdgcn_s_barrier(); asm volatile("" ::: "memory"); }
#define LDA(base, MH) {                                                             \
    _Pragma("unroll") for (int fm = 0; fm < 4; ++fm)                                \
    _Pragma("unroll") for (int kk = 0; kk < 2; ++kk)                                \
        afr[fm][kk] = *(const bf16x8*)&lds[(base) + ((MH) * 128 + wm * 64 + fm * 16 + l15) * 64 + colw[kk]]; }
#define LDB(base, NH, dst) {                                                        \
    _Pragma("unroll") for (int gn = 0; gn < 2; ++gn)                                \
    _Pragma("unroll") for (int kk = 0; kk < 2; ++kk)                                \
        dst[gn][kk] = *(const bf16x8*)&lds[(base) + ((NH) * 128 + gn * 64 + wn * 16 + l15) * 64 + colw[kk]]; }
#define MFMA_Q(MH, NH, bset) {                                                      \
    _Pragma("unroll") for (int fm = 0; fm < 4; ++fm)                                \
    _Pragma("unroll") for (int gn = 0; gn < 2; ++gn)                                \
    _Pragma("unroll") for (int kk = 0; kk < 2; ++kk)                                \
        acc[(MH) * 4 + fm][(NH) * 2 + gn] = __builtin_amdgcn_mfma_f32_16x16x32_bf16( \
            afr[fm][kk], bset[gn][kk], acc[(MH) * 4 + fm][(NH) * 2 + gn], 0, 0, 0); }

    // ---- prologue: A(0),B(0),A(1); drain A(0)+B(0), keep A(1) flying ----
    STAGE_A(0, 0, 0); STAGE_A(0, 1, 0);
    STAGE_B(49152, 0, 0); STAGE_B(49152, 1, 0);
    STAGE_A(16384, 0, 1); STAGE_A(16384, 1, 1);
    asm volatile("s_waitcnt vmcnt(4)" ::: "memory");
    BARRIER();

    int Ar = 0;          // A read slot (tile t)
    int As = 32768;      // A stage slot (tile t+2)
    int Brel = 0;        // B read slot rel offset; stage = ^16384

    // ---- init: load B0(0) into bX (tile 0: b0-role = bX) ----
    LDB(49152, 0, bXf);

#define CBODY(T, B0, B1, STAGEA, VM)                                                \
    {                                                                               \
        const int Br = 49152 + Brel, Bs = 49152 + (Brel ^ 16384);                   \
        LDA(Ar, 0);                                                                 \
        LDB(Br, 1, B1);                                                             \
        STAGE_B(Bs, 0, (T) + 1); STAGE_B(Bs, 1, (T) + 1);                           \
        __builtin_amdgcn_s_setprio(1);                                              \
        MFMA_Q(0, 0, B0);                                                           \
        MFMA_Q(0, 1, B1);                                                           \
        __builtin_amdgcn_s_setprio(0);                                              \
        LDA(Ar, 1);                                                                 \
        if (STAGEA) { STAGE_A(As, 0, (T) + 2); STAGE_A(As, 1, (T) + 2); }           \
        __builtin_amdgcn_s_setprio(1);                                              \
        MFMA_Q(1, 1, B1);                                                           \
        __builtin_amdgcn_s_setprio(0);                                              \
        asm volatile("s_waitcnt vmcnt(" #VM ")" ::: "memory");                      \
        BARRIER();                                                                  \
        LDB(49152 + (Brel ^ 16384), 0, B1);  /* next tile's b0 -> dead set */       \
        __builtin_amdgcn_s_setprio(1);                                              \
        MFMA_Q(1, 0, B0);                    /* deferred, reg-only */               \
        __builtin_amdgcn_s_setprio(0);                                              \
        Ar = (Ar == 32768) ? 0 : Ar + 16384;                                        \
        As = (As == 32768) ? 0 : As + 16384;                                        \
        Brel ^= 16384;                                                              \
    }

    // ---- steady loop ----
#pragma unroll 1
    for (int t = 0; t < KT - 2; t += 2) {
        CBODY(t,     bXf, bYf, true, 4);
        CBODY(t + 1, bYf, bXf, true, 4);
    }

    // ---- tile KT-2 (b0=bX): stage only B(KT-1); drain everything ----
    CBODY(KT - 2, bXf, bYf, false, 0);

    // ---- tile KT-1 (b0=bY): fully resident ----
    {
        const int Br = 49152 + Brel;
        LDA(Ar, 0);
        LDB(Br, 1, bXf);
        MFMA_Q(0, 0, bYf);
        MFMA_Q(0, 1, bXf);
        LDA(Ar, 1);
        MFMA_Q(1, 1, bXf);
        MFMA_Q(1, 0, bYf);
    }
#undef CBODY
#undef AOFF
#undef BOFF
#undef GLDS
#undef STAGE_A
#undef STAGE_B
#undef LDA
#undef LDB

    // ---- epilogue: C frag (col=lane&15 -> o, row=(lane>>4)*4+j -> pixel) ----
#pragma unroll
    for (int f = 0; f < 8; ++f) {
        const int prow = (f >> 2) * 128 + wm * 64 + (f & 3) * 16 + ((l >> 4) << 2);
#pragma unroll
        for (int g = 0; g < 4; ++g) {
            const int o = (g >> 1) * 128 + (g & 1) * 64 + wn * 16 + l15;
            float bb = 0.f;
            if (BIASRELU) bb = bias[o];
#pragma unroll
            for (int j = 0; j < 4; ++j) {
                int pix = Mbase + prow + j;
                int nn = pix >> 12, p = (pix >> 6) & 63, q = pix & 63;
                float val = acc[f][g][j] + bb;
                if (BIASRELU) val = fmaxf(val, 0.f);
                out[out_base + nn * out_img + p * out_row + q * 256 + o] = f2bf(val);
            }
        }
    }

    // ---- fused SE pooling: per-block column sums (deterministic) ----
    if (POOL) {
        float ps[4];
#pragma unroll
        for (int g = 0; g < 4; ++g) {
            float s = 0.f;
#pragma unroll
            for (int f = 0; f < 8; ++f)
#pragma unroll
                for (int j = 0; j < 4; ++j) s += acc[f][g][j];
            s += __shfl_xor(s, 16);
            s += __shfl_xor(s, 32);
            ps[g] = s;
        }
        asm volatile("s_waitcnt lgkmcnt(0)" ::: "memory");
        BARRIER();
        float* fl = (float*)lds;
        if ((l >> 4) == 0) {
#pragma unroll
            for (int g = 0; g < 4; ++g) {
                int o = (g >> 1) * 128 + (g & 1) * 64 + wn * 16 + l15;
                fl[wm * 256 + o] = ps[g];
            }
        }
        BARRIER();
        if (tid < 256)
            pool_out[bid * 256 + tid] = fl[tid] + fl[256 + tid];
    }
#undef MFMA_Q
#undef BARRIER
}

// ---------------------------------------------------------------------------
// finalize: per block (n,p):
//   (1) residual 1x1 s2 conv for its 64 pixels via MFMA (A=pre, B=wrt direct
//       from global; K=128) -> resf LDS (bf16, identical path to old res buf)
//   (2) recompute SE gate a[n][:] from conv2's pooled partials (deterministic)
//   (3) out[n][o][p][q] = h2[n][p][q][o]*a[o] + resf[q][o]  (NHWC->NCHW)
// ---------------------------------------------------------------------------
__global__ __launch_bounds__(256, 2)
void finalize_kernel(const u16* __restrict__ h2, const u16* __restrict__ pre,
                     const u16* __restrict__ wrt, const float* __restrict__ part,
                     const float* __restrict__ sw1, const float* __restrict__ sb1,
                     const float* __restrict__ sw2, const float* __restrict__ sb2,
                     float* __restrict__ out) {
    __shared__ u16 th[256 * 68];
    __shared__ u16 resf[64 * 256];
    __shared__ float al[256];
    __shared__ float hl[16];
    int n = blockIdx.x >> 6, p = blockIdx.x & 63;
    int t = threadIdx.x;
    const int w = t >> 6, l = t & 63;
    const int l15 = l & 15, lk = (l >> 4) << 3;

    // ---- (1) residual MFMA: M=64 px (all), N=64 o per wave, K=128 ----
    f32x4 racc[4][4] = {};
    {
        const u16* pbase = pre + ((n * 129 + 2 * p) * 129) * 128;
#pragma unroll
        for (int ks = 0; ks < 4; ++ks) {
            bf16x8 af[4], bf[4];
#pragma unroll
            for (int fm = 0; fm < 4; ++fm) {
                int q = fm * 16 + l15;
                af[fm] = *(const bf16x8*)(pbase + (2 * q) * 128 + ks * 32 + lk);
            }
#pragma unroll
            for (int fn = 0; fn < 4; ++fn) {
                int o = w * 64 + fn * 16 + l15;
                bf[fn] = *(const bf16x8*)(wrt + o * 128 + ks * 32 + lk);
            }
#pragma unroll
            for (int fm = 0; fm < 4; ++fm)
#pragma unroll
                for (int fn = 0; fn < 4; ++fn)
                    racc[fm][fn] = __builtin_amdgcn_mfma_f32_16x16x32_bf16(
                        af[fm], bf[fn], racc[fm][fn], 0, 0, 0);
        }
#pragma unroll
        for (int fm = 0; fm < 4; ++fm)
#pragma unroll
            for (int fn = 0; fn < 4; ++fn)
#pragma unroll
                for (int j = 0; j < 4; ++j)
                    resf[(fm * 16 + ((l >> 4) << 2) + j) * 256 + w * 64 + fn * 16 + l15] =
                        f2bf(racc[fm][fn][j]);
    }

    // ---- (2) SE gate for image n ----
    {
        float s = 0.f;
#pragma unroll
        for (int k = 0; k < 16; ++k) s += part[(n * 16 + k) * 256 + t];
        al[t] = s * (1.0f / 4096.0f);          // mean
    }
    __syncthreads();                            // resf + mean ready
    if (t < 16) {
        float d = sb1[t];
        for (int c = 0; c < 256; ++c) d += al[c] * sw1[t * 256 + c];
        hl[t] = fmaxf(d, 0.f);
    }
    __syncthreads();
    {
        float z = sb2[t];
#pragma unroll
        for (int j = 0; j < 16; ++j) z += hl[j] * sw2[t * 16 + j];
        float a_t = 1.0f / (1.0f + expf(-z));
        __syncthreads();                        // all mean-reads done
        al[t] = a_t;                            // overwrite with gate
    }
    __syncthreads();

    // ---- (3) combine + NHWC->NCHW transpose ----
    int o8 = (t & 31) << 3, qr = t >> 5;
    int pixbase = n * 4096 + p * 64;
#pragma unroll
    for (int qi = 0; qi < 8; ++qi) {
        int q = qi * 8 + qr;
        u16x8 hv = *(const u16x8*)(h2 + (pixbase + q) * 256 + o8);
        u16x8 rv = *(const u16x8*)(resf + q * 256 + o8);
#pragma unroll
        for (int k = 0; k < 8; ++k) {
            float vv = bf2f(hv[k]) * al[o8 + k] + bf2f(rv[k]);
            th[(o8 + k) * 68 + q] = f2bf(vv);
        }
    }
    __syncthreads();
    int q4 = (t & 15) << 2, ob = t >> 4;
#pragma unroll
    for (int oi = 0; oi < 16; ++oi) {
        int o = oi * 16 + ob;
        float4 vv;
        vv.x = bf2f(th[o * 68 + q4 + 0]);
        vv.y = bf2f(th[o * 68 + q4 + 1]);
        vv.z = bf2f(th[o * 68 + q4 + 2]);
        vv.w = bf2f(th[o * 68 + q4 + 3]);
        *(float4*)(out + ((n * 256 + o) * 64 + p) * 64 + q4) = vv;
    }
}

// ---------------------------------------------------------------------------
// workspace layout (bytes)
// ---------------------------------------------------------------------------
static const size_t OFF_PRE  = 0;                       // 68,161,536 (alive thru finalize)
static const size_t OFF_H1   = 68161536;                // 35,684,352
static const size_t OFF_H2   = 103845888;               // 33,554,432
static const size_t OFF_W1T  = 137400320;               // 589,824
static const size_t OFF_W2T  = 137990144;               // 1,179,648
static const size_t OFF_WRT  = 139169792;               // 65,536
static const size_t OFF_B2F  = 139235328;               // 1,024
static const size_t OFF_PART = 139236352;               // 262,144 (256 tiles x 256 f32)

extern "C" void kernel_launch(void* const* d_in, const int* in_sizes, int n_in,
                              void* d_out, int out_size, void* d_ws, size_t ws_size,
                              hipStream_t stream) {
    (void)in_sizes; (void)n_in; (void)out_size; (void)ws_size;
    const float* x      = (const float*)d_in[0];
    const float* bn1_g  = (const float*)d_in[1];
    const float* bn1_b  = (const float*)d_in[2];
    const float* bn1_m  = (const float*)d_in[3];
    const float* bn1_v  = (const float*)d_in[4];
    const float* bn2_g  = (const float*)d_in[5];
    const float* bn2_b  = (const float*)d_in[6];
    const float* bn2_m  = (const float*)d_in[7];
    const float* bn2_v  = (const float*)d_in[8];
    const float* wc1    = (const float*)d_in[9];
    const float* wc2    = (const float*)d_in[10];
    const float* wres   = (const float*)d_in[11];
    const float* se_w1  = (const float*)d_in[12];
    const float* se_b1  = (const float*)d_in[13];
    const float* se_w2  = (const float*)d_in[14];
    const float* se_b2  = (const float*)d_in[15];

    char* ws = (char*)d_ws;
    u16*   pre    = (u16*)(ws + OFF_PRE);
    u16*   h1     = (u16*)(ws + OFF_H1);
    u16*   h2     = (u16*)(ws + OFF_H2);
    u16*   w1t    = (u16*)(ws + OFF_W1T);
    u16*   w2t    = (u16*)(ws + OFF_W2T);
    u16*   wrt    = (u16*)(ws + OFF_WRT);
    float* bias2f = (float*)(ws + OFF_B2F);
    float* part   = (float*)(ws + OFF_PART);
    float* out    = (float*)d_out;

    // setup: weights + pads + pre (one launch)
    setup_kernel<<<11849, 256, 0, stream>>>(x, bn1_g, bn1_b, bn1_m, bn1_v,
                                            wc1, wc2, wres, bn2_g, bn2_b, bn2_m, bn2_v,
                                            w1t, w2t, wrt, bias2f, pre, h1);

    // conv1: 3x3 s2, 128->256, +BN2(bias)+ReLU, out = padded h1 (base (1,1))
    conv_8ph<128, 9, 2, true, false><<<256, 512, 0, stream>>>(
        pre, w1t, bias2f, h1, nullptr,
        129 * 128, 129 * 129 * 128,
        67 * 256, 66 * 256, 66 * 66 * 256);

    // conv2: 3x3 s1, 256->256 + fused SE pooling (h2 in its own region now)
    conv_8ph<256, 9, 1, false, true><<<256, 512, 0, stream>>>(
        h1, w2t, nullptr, h2, part,
        66 * 256, 66 * 66 * 256,
        0, 64 * 256, 4096 * 256);

    // finalize: fused SE-MLP + residual 1x1 conv (from pre) + combine
    finalize_kernel<<<1024, 256, 0, stream>>>(h2, pre, wrt, part,
                                              se_w1, se_b1, se_w2, se_b2, out);
}

// Round 8
// 197.211 us; speedup vs baseline: 1.6513x; 1.0220x over previous
//
#include <hip/hip_runtime.h>

typedef unsigned short u16;
typedef __attribute__((ext_vector_type(8))) unsigned short u16x8;
typedef __attribute__((ext_vector_type(8))) __bf16 bf16x8;
typedef __attribute__((ext_vector_type(4))) float f32x4;

__device__ __forceinline__ float bf2f(u16 u) {
    return __uint_as_float(((unsigned)u) << 16);
}
__device__ __forceinline__ u16 f2bf(float f) {
    unsigned u = __float_as_uint(f);
    return (u16)((u + 0x7FFFu + ((u >> 16) & 1u)) >> 16);
}

// ---------------------------------------------------------------------------
// setup kernel: weight transform + pad zeroing + pre=relu(BN1(x)) transpose,
// one launch, block-range dispatch.
//   [0,3585): weights; [3585,5641): pre pad; [5641,9801): h1 pad;
//   [9801,11849): pre BN+ReLU NCHW f32 -> padded NHWC bf16 (interior)
// pre-transpose reads: 32-lane group reads one (c,y) row cooperatively
// (contiguous 512B per row) -- coalesced, vs old per-lane 64KB-strided streams.
// ---------------------------------------------------------------------------
__global__ __launch_bounds__(256)
void setup_kernel(const float* __restrict__ x,
                  const float* __restrict__ g1, const float* __restrict__ b1,
                  const float* __restrict__ m1, const float* __restrict__ v1,
                  const float* __restrict__ w1, const float* __restrict__ w2,
                  const float* __restrict__ wr,
                  const float* __restrict__ g2, const float* __restrict__ b2,
                  const float* __restrict__ m2, const float* __restrict__ v2,
                  u16* __restrict__ w1t, u16* __restrict__ w2t,
                  u16* __restrict__ wrt, float* __restrict__ bias2f,
                  u16* __restrict__ pre, u16* __restrict__ h1) {
    __shared__ u16 tile[128 * 136];
    __shared__ float scf[128], bif[128];
    int b = blockIdx.x;
    if (b < 3585) {
        int i = b * 256 + threadIdx.x;
        if (i < 294912) {
            int ci = i & 127; int t = i >> 7; int o = t & 255; int tap = t >> 8;
            int dy = tap / 3, dx = tap - dy * 3;
            float sc = g2[o] * rsqrtf(v2[o] + 1e-5f);
            w1t[i] = f2bf(w1[((o * 128 + ci) * 3 + dy) * 3 + dx] * sc);
        } else if (i < 294912 + 589824) {
            int j = i - 294912;
            int ci = j & 255; int t = j >> 8; int o = t & 255; int tap = t >> 8;
            int dy = tap / 3, dx = tap - dy * 3;
            w2t[j] = f2bf(w2[((o * 256 + ci) * 3 + dy) * 3 + dx]);
        } else if (i < 294912 + 589824 + 32768) {
            int j = i - (294912 + 589824);
            int ci = j & 127; int o = j >> 7;
            wrt[j] = f2bf(wr[o * 128 + ci]);
        } else {
            int o = i - (294912 + 589824 + 32768);
            if (o < 256) {
                float sc = g2[o] * rsqrtf(v2[o] + 1e-5f);
                bias2f[o] = b2[o] - m2[o] * sc;
            }
        }
    } else if (b < 3585 + 2056) {
        int i = (b - 3585) * 256 + threadIdx.x;
        if (i < 16 * 129 * 128) {
            int c = i & 127; int t = i >> 7; int n = t / 129; int xx = t - n * 129;
            pre[((n * 129 + 128) * 129 + xx) * 128 + c] = 0;
        } else {
            int j = i - 16 * 129 * 128;
            int c = j & 127; int t = j >> 7; int n = t >> 7; int y = t & 127;
            pre[((n * 129 + y) * 129 + 128) * 128 + c] = 0;
        }
    } else if (b < 3585 + 2056 + 4160) {
        int i = (b - (3585 + 2056)) * 256 + threadIdx.x;
        int c = i & 255;
        int t = i >> 8;
        int n = t / 260;
        int cl = t - n * 260;
        int y, x2;
        if (cl < 66)       { y = 0;  x2 = cl; }
        else if (cl < 132) { y = 65; x2 = cl - 66; }
        else if (cl < 196) { x2 = 0; y = cl - 131; }
        else               { x2 = 65; y = cl - 195; }
        h1[((n * 66 + y) * 66 + x2) * 256 + c] = 0;
    } else {
        int pb = b - (3585 + 2056 + 4160);
        int n = pb >> 7, y = pb & 127;
        int tid = threadIdx.x;
        // precompute BN scale/bias once per block
        if (tid < 128) {
            float sc = g1[tid] * rsqrtf(v1[tid] + 1e-5f);
            scf[tid] = sc;
            bif[tid] = b1[tid] - m1[tid] * sc;
        }
        __syncthreads();
        // read phase: iteration i handles channels i*8..i*8+7; 32 lanes per
        // channel-row read consecutive float4 (contiguous 512B) -- coalesced.
        const int xq = (tid & 31) << 2;       // x position (float index base)
        const int cg = tid >> 5;              // channel sub-index 0..7
        const float* xb = x + (n << 21) + (y << 7) + xq;
#pragma unroll
        for (int i = 0; i < 16; ++i) {
            int c = i * 8 + cg;
            float4 val = *(const float4*)(xb + (c << 14));
            float sc = scf[c], bi = bif[c];
            tile[(xq + 0) * 136 + c] = f2bf(fmaxf(val.x * sc + bi, 0.f));
            tile[(xq + 1) * 136 + c] = f2bf(fmaxf(val.y * sc + bi, 0.f));
            tile[(xq + 2) * 136 + c] = f2bf(fmaxf(val.z * sc + bi, 0.f));
            tile[(xq + 3) * 136 + c] = f2bf(fmaxf(val.w * sc + bi, 0.f));
        }
        __syncthreads();
        // write phase: coalesced u16x8 NHWC stores (unchanged)
        int c0 = (tid & 15) << 3;
#pragma unroll
        for (int xi = 0; xi < 8; ++xi) {
            int xx = xi * 16 + (tid >> 4);
            u16x8 val = *(const u16x8*)&tile[xx * 136 + c0];
            *(u16x8*)(pre + ((n * 129 + y) * 129 + xx) * 128 + c0) = val;
        }
    }
}

// ===========================================================================
// 256x256 implicit-GEMM conv.  A triple-buffered, B double-buffered.
// Deferred-quadrant software pipeline; one barrier + one counted vmcnt/tile.
// T1 XCD swizzle; T2 LDS swizzle via inverse-swizzled global source.
// POOL: conv2 fuses the SE global-avg partial sums into the epilogue.
// ===========================================================================
template <int CIN, int NTAPS, int STRIDE, bool BIASRELU, bool POOL>
__global__ __launch_bounds__(512, 2)
void conv_8ph(const u16* __restrict__ in, const u16* __restrict__ wt,
              const float* __restrict__ bias, u16* __restrict__ out,
              float* __restrict__ pool_out,
              int in_row, int in_img, int out_base, int out_row, int out_img) {
    constexpr int CSTEPS = CIN / 64;
    constexpr int KT = CSTEPS * NTAPS;
    // A buffers: 0, 16384, 32768 ; B buffers: 49152, 65536   (u16 units)
    __shared__ __attribute__((aligned(16))) u16 lds[81920];

    const int tid = threadIdx.x;
    const int w = tid >> 6, l = tid & 63;
    const int wm = w >> 2, wn = w & 3;
    const int l15 = l & 15;
    // T1: XCD-aware swizzle (bijective, 256 % 8 == 0)
    const int bid = ((blockIdx.x & 7) << 5) | (blockIdx.x >> 3);
    const int Mbase = bid << 8;

    const int srow = tid >> 3;
    const int swze = (((tid & 7) ^ (srow & 7)) << 3);
    int pix0 = Mbase + srow;
    int nn0 = pix0 >> 12, p0 = (pix0 >> 6) & 63, q0 = pix0 & 63;
    const int abase0 = nn0 * in_img + (STRIDE * p0) * in_row + (STRIDE * q0) * CIN + swze;
    const int astep = STRIDE * in_row;
    const int bbase0 = srow * CIN + swze;
    const int bstep = 64 * CIN;

    int colw[2];
#pragma unroll
    for (int kk = 0; kk < 2; ++kk)
        colw[kk] = (kk * 32 + (l >> 4) * 8) ^ ((l & 7) << 3);

    f32x4 acc[8][4] = {};
    bf16x8 afr[4][2], bXf[2][2], bYf[2][2];

#define AOFF(ks) (((NTAPS == 9) ? ((((ks) / CSTEPS) / 3) * in_row + (((ks) / CSTEPS) % 3) * CIN) : 0) + ((ks) % CSTEPS) * 64)
#define BOFF(ks) (((ks) / CSTEPS) * 256 * CIN + ((ks) % CSTEPS) * 64)
#define GLDS(gsrc, ldst) __builtin_amdgcn_global_load_lds(                          \
        (__attribute__((address_space(1))) void*)(gsrc),                            \
        (__attribute__((address_space(3))) void*)(ldst), 16, 0, 0)
#define STAGE_A(base, h, ks) {                                                      \
    int _ao = AOFF(ks);                                                             \
    GLDS(in + abase0 + (2 * (h) + 0) * astep + _ao,                                 \
         &lds[(base) + (h) * 8192 + 0 * 4096 + w * 512]);                           \
    GLDS(in + abase0 + (2 * (h) + 1) * astep + _ao,                                 \
         &lds[(base) + (h) * 8192 + 1 * 4096 + w * 512]); }
#define STAGE_B(base, h, ks) {                                                      \
    int _bo = BOFF(ks);                                                             \
    GLDS(wt + bbase0 + (2 * (h) + 0) * bstep + _bo,                                 \
         &lds[(base) + (h) * 8192 + 0 * 4096 + w * 512]);                           \
    GLDS(wt + bbase0 + (2 * (h) + 1) * bstep + _bo,                                 \
         &lds[(base) + (h) * 8192 + 1 * 4096 + w * 512]); }
#define BARRIER() { __builtin_amdgcn_s_barrier(); asm volatile("" ::: "memory"); }
#define LDA(base, MH) {                                                             \
    _Pragma("unroll") for (int fm = 0; fm < 4; ++fm)                                \
    _Pragma("unroll") for (int kk = 0; kk < 2; ++kk)                                \
        afr[fm][kk] = *(const bf16x8*)&lds[(base) + ((MH) * 128 + wm * 64 + fm * 16 + l15) * 64 + colw[kk]]; }
#define LDB(base, NH, dst) {                                                        \
    _Pragma("unroll") for (int gn = 0; gn < 2; ++gn)                                \
    _Pragma("unroll") for (int kk = 0; kk < 2; ++kk)                                \
        dst[gn][kk] = *(const bf16x8*)&lds[(base) + ((NH) * 128 + gn * 64 + wn * 16 + l15) * 64 + colw[kk]]; }
#define MFMA_Q(MH, NH, bset) {                                                      \
    _Pragma("unroll") for (int fm = 0; fm < 4; ++fm)                                \
    _Pragma("unroll") for (int gn = 0; gn < 2; ++gn)                                \
    _Pragma("unroll") for (int kk = 0; kk < 2; ++kk)                                \
        acc[(MH) * 4 + fm][(NH) * 2 + gn] = __builtin_amdgcn_mfma_f32_16x16x32_bf16( \
            afr[fm][kk], bset[gn][kk], acc[(MH) * 4 + fm][(NH) * 2 + gn], 0, 0, 0); }

    // ---- prologue: A(0),B(0),A(1); drain A(0)+B(0), keep A(1) flying ----
    STAGE_A(0, 0, 0); STAGE_A(0, 1, 0);
    STAGE_B(49152, 0, 0); STAGE_B(49152, 1, 0);
    STAGE_A(16384, 0, 1); STAGE_A(16384, 1, 1);
    asm volatile("s_waitcnt vmcnt(4)" ::: "memory");
    BARRIER();

    int Ar = 0;          // A read slot (tile t)
    int As = 32768;      // A stage slot (tile t+2)
    int Brel = 0;        // B read slot rel offset; stage = ^16384

    // ---- init: load B0(0) into bX (tile 0: b0-role = bX) ----
    LDB(49152, 0, bXf);

#define CBODY(T, B0, B1, STAGEA, VM)                                                \
    {                                                                               \
        const int Br = 49152 + Brel, Bs = 49152 + (Brel ^ 16384);                   \
        LDA(Ar, 0);                                                                 \
        LDB(Br, 1, B1);                                                             \
        STAGE_B(Bs, 0, (T) + 1); STAGE_B(Bs, 1, (T) + 1);                           \
        __builtin_amdgcn_s_setprio(1);                                              \
        MFMA_Q(0, 0, B0);                                                           \
        MFMA_Q(0, 1, B1);                                                           \
        __builtin_amdgcn_s_setprio(0);                                              \
        LDA(Ar, 1);                                                                 \
        if (STAGEA) { STAGE_A(As, 0, (T) + 2); STAGE_A(As, 1, (T) + 2); }           \
        __builtin_amdgcn_s_setprio(1);                                              \
        MFMA_Q(1, 1, B1);                                                           \
        __builtin_amdgcn_s_setprio(0);                                              \
        asm volatile("s_waitcnt vmcnt(" #VM ")" ::: "memory");                      \
        BARRIER();                                                                  \
        LDB(49152 + (Brel ^ 16384), 0, B1);  /* next tile's b0 -> dead set */       \
        __builtin_amdgcn_s_setprio(1);                                              \
        MFMA_Q(1, 0, B0);                    /* deferred, reg-only */               \
        __builtin_amdgcn_s_setprio(0);                                              \
        Ar = (Ar == 32768) ? 0 : Ar + 16384;                                        \
        As = (As == 32768) ? 0 : As + 16384;                                        \
        Brel ^= 16384;                                                              \
    }

    // ---- steady loop ----
#pragma unroll 1
    for (int t = 0; t < KT - 2; t += 2) {
        CBODY(t,     bXf, bYf, true, 4);
        CBODY(t + 1, bYf, bXf, true, 4);
    }

    // ---- tile KT-2 (b0=bX): stage only B(KT-1); drain everything ----
    CBODY(KT - 2, bXf, bYf, false, 0);

    // ---- tile KT-1 (b0=bY): fully resident ----
    {
        const int Br = 49152 + Brel;
        LDA(Ar, 0);
        LDB(Br, 1, bXf);
        MFMA_Q(0, 0, bYf);
        MFMA_Q(0, 1, bXf);
        LDA(Ar, 1);
        MFMA_Q(1, 1, bXf);
        MFMA_Q(1, 0, bYf);
    }
#undef CBODY
#undef AOFF
#undef BOFF
#undef GLDS
#undef STAGE_A
#undef STAGE_B
#undef LDA
#undef LDB

    // ---- epilogue: C frag (col=lane&15 -> o, row=(lane>>4)*4+j -> pixel) ----
#pragma unroll
    for (int f = 0; f < 8; ++f) {
        const int prow = (f >> 2) * 128 + wm * 64 + (f & 3) * 16 + ((l >> 4) << 2);
#pragma unroll
        for (int g = 0; g < 4; ++g) {
            const int o = (g >> 1) * 128 + (g & 1) * 64 + wn * 16 + l15;
            float bb = 0.f;
            if (BIASRELU) bb = bias[o];
#pragma unroll
            for (int j = 0; j < 4; ++j) {
                int pix = Mbase + prow + j;
                int nn = pix >> 12, p = (pix >> 6) & 63, q = pix & 63;
                float val = acc[f][g][j] + bb;
                if (BIASRELU) val = fmaxf(val, 0.f);
                out[out_base + nn * out_img + p * out_row + q * 256 + o] = f2bf(val);
            }
        }
    }

    // ---- fused SE pooling: per-block column sums (deterministic) ----
    if (POOL) {
        float ps[4];
#pragma unroll
        for (int g = 0; g < 4; ++g) {
            float s = 0.f;
#pragma unroll
            for (int f = 0; f < 8; ++f)
#pragma unroll
                for (int j = 0; j < 4; ++j) s += acc[f][g][j];
            s += __shfl_xor(s, 16);
            s += __shfl_xor(s, 32);
            ps[g] = s;
        }
        asm volatile("s_waitcnt lgkmcnt(0)" ::: "memory");
        BARRIER();
        float* fl = (float*)lds;
        if ((l >> 4) == 0) {
#pragma unroll
            for (int g = 0; g < 4; ++g) {
                int o = (g >> 1) * 128 + (g & 1) * 64 + wn * 16 + l15;
                fl[wm * 256 + o] = ps[g];
            }
        }
        BARRIER();
        if (tid < 256)
            pool_out[bid * 256 + tid] = fl[tid] + fl[256 + tid];
    }
#undef MFMA_Q
#undef BARRIER
}

// ---------------------------------------------------------------------------
// finalize: per block (n,p):
//   (1) residual 1x1 s2 conv for its 64 pixels via MFMA (A=pre, B=wrt direct
//       from global; K=128) -> resf LDS
//   (2) recompute SE gate a[n][:] from conv2's pooled partials (deterministic)
//   (3) out[n][o][p][q] = h2[n][p][q][o]*a[o] + resf[q][o]  (NHWC->NCHW)
// ---------------------------------------------------------------------------
__global__ __launch_bounds__(256, 2)
void finalize_kernel(const u16* __restrict__ h2, const u16* __restrict__ pre,
                     const u16* __restrict__ wrt, const float* __restrict__ part,
                     const float* __restrict__ sw1, const float* __restrict__ sb1,
                     const float* __restrict__ sw2, const float* __restrict__ sb2,
                     float* __restrict__ out) {
    __shared__ u16 th[256 * 68];
    __shared__ u16 resf[64 * 256];
    __shared__ float al[256];
    __shared__ float hl[16];
    int n = blockIdx.x >> 6, p = blockIdx.x & 63;
    int t = threadIdx.x;
    const int w = t >> 6, l = t & 63;
    const int l15 = l & 15, lk = (l >> 4) << 3;

    // ---- (1) residual MFMA: M=64 px (all), N=64 o per wave, K=128 ----
    f32x4 racc[4][4] = {};
    {
        const u16* pbase = pre + ((n * 129 + 2 * p) * 129) * 128;
#pragma unroll
        for (int ks = 0; ks < 4; ++ks) {
            bf16x8 af[4], bf[4];
#pragma unroll
            for (int fm = 0; fm < 4; ++fm) {
                int q = fm * 16 + l15;
                af[fm] = *(const bf16x8*)(pbase + (2 * q) * 128 + ks * 32 + lk);
            }
#pragma unroll
            for (int fn = 0; fn < 4; ++fn) {
                int o = w * 64 + fn * 16 + l15;
                bf[fn] = *(const bf16x8*)(wrt + o * 128 + ks * 32 + lk);
            }
#pragma unroll
            for (int fm = 0; fm < 4; ++fm)
#pragma unroll
                for (int fn = 0; fn < 4; ++fn)
                    racc[fm][fn] = __builtin_amdgcn_mfma_f32_16x16x32_bf16(
                        af[fm], bf[fn], racc[fm][fn], 0, 0, 0);
        }
#pragma unroll
        for (int fm = 0; fm < 4; ++fm)
#pragma unroll
            for (int fn = 0; fn < 4; ++fn)
#pragma unroll
                for (int j = 0; j < 4; ++j)
                    resf[(fm * 16 + ((l >> 4) << 2) + j) * 256 + w * 64 + fn * 16 + l15] =
                        f2bf(racc[fm][fn][j]);
    }

    // ---- (2) SE gate for image n ----
    {
        float s = 0.f;
#pragma unroll
        for (int k = 0; k < 16; ++k) s += part[(n * 16 + k) * 256 + t];
        al[t] = s * (1.0f / 4096.0f);          // mean
    }
    __syncthreads();                            // resf + mean ready
    if (t < 16) {
        float d = sb1[t];
        for (int c = 0; c < 256; ++c) d += al[c] * sw1[t * 256 + c];
        hl[t] = fmaxf(d, 0.f);
    }
    __syncthreads();
    {
        float z = sb2[t];
#pragma unroll
        for (int j = 0; j < 16; ++j) z += hl[j] * sw2[t * 16 + j];
        float a_t = 1.0f / (1.0f + expf(-z));
        __syncthreads();                        // all mean-reads done
        al[t] = a_t;                            // overwrite with gate
    }
    __syncthreads();

    // ---- (3) combine + NHWC->NCHW transpose ----
    int o8 = (t & 31) << 3, qr = t >> 5;
    int pixbase = n * 4096 + p * 64;
#pragma unroll
    for (int qi = 0; qi < 8; ++qi) {
        int q = qi * 8 + qr;
        u16x8 hv = *(const u16x8*)(h2 + (pixbase + q) * 256 + o8);
        u16x8 rv = *(const u16x8*)(resf + q * 256 + o8);
#pragma unroll
        for (int k = 0; k < 8; ++k) {
            float vv = bf2f(hv[k]) * al[o8 + k] + bf2f(rv[k]);
            th[(o8 + k) * 68 + q] = f2bf(vv);
        }
    }
    __syncthreads();
    int q4 = (t & 15) << 2, ob = t >> 4;
#pragma unroll
    for (int oi = 0; oi < 16; ++oi) {
        int o = oi * 16 + ob;
        float4 vv;
        vv.x = bf2f(th[o * 68 + q4 + 0]);
        vv.y = bf2f(th[o * 68 + q4 + 1]);
        vv.z = bf2f(th[o * 68 + q4 + 2]);
        vv.w = bf2f(th[o * 68 + q4 + 3]);
        *(float4*)(out + ((n * 256 + o) * 64 + p) * 64 + q4) = vv;
    }
}

// ---------------------------------------------------------------------------
// workspace layout (bytes)
// ---------------------------------------------------------------------------
static const size_t OFF_PRE  = 0;                       // 68,161,536 (alive thru finalize)
static const size_t OFF_H1   = 68161536;                // 35,684,352
static const size_t OFF_H2   = 103845888;               // 33,554,432
static const size_t OFF_W1T  = 137400320;               // 589,824
static const size_t OFF_W2T  = 137990144;               // 1,179,648
static const size_t OFF_WRT  = 139169792;               // 65,536
static const size_t OFF_B2F  = 139235328;               // 1,024
static const size_t OFF_PART = 139236352;               // 262,144 (256 tiles x 256 f32)

extern "C" void kernel_launch(void* const* d_in, const int* in_sizes, int n_in,
                              void* d_out, int out_size, void* d_ws, size_t ws_size,
                              hipStream_t stream) {
    (void)in_sizes; (void)n_in; (void)out_size; (void)ws_size;
    const float* x      = (const float*)d_in[0];
    const float* bn1_g  = (const float*)d_in[1];
    const float* bn1_b  = (const float*)d_in[2];
    const float* bn1_m  = (const float*)d_in[3];
    const float* bn1_v  = (const float*)d_in[4];
    const float* bn2_g  = (const float*)d_in[5];
    const float* bn2_b  = (const float*)d_in[6];
    const float* bn2_m  = (const float*)d_in[7];
    const float* bn2_v  = (const float*)d_in[8];
    const float* wc1    = (const float*)d_in[9];
    const float* wc2    = (const float*)d_in[10];
    const float* wres   = (const float*)d_in[11];
    const float* se_w1  = (const float*)d_in[12];
    const float* se_b1  = (const float*)d_in[13];
    const float* se_w2  = (const float*)d_in[14];
    const float* se_b2  = (const float*)d_in[15];

    char* ws = (char*)d_ws;
    u16*   pre    = (u16*)(ws + OFF_PRE);
    u16*   h1     = (u16*)(ws + OFF_H1);
    u16*   h2     = (u16*)(ws + OFF_H2);
    u16*   w1t    = (u16*)(ws + OFF_W1T);
    u16*   w2t    = (u16*)(ws + OFF_W2T);
    u16*   wrt    = (u16*)(ws + OFF_WRT);
    float* bias2f = (float*)(ws + OFF_B2F);
    float* part   = (float*)(ws + OFF_PART);
    float* out    = (float*)d_out;

    // setup: weights + pads + pre (one launch)
    setup_kernel<<<11849, 256, 0, stream>>>(x, bn1_g, bn1_b, bn1_m, bn1_v,
                                            wc1, wc2, wres, bn2_g, bn2_b, bn2_m, bn2_v,
                                            w1t, w2t, wrt, bias2f, pre, h1);

    // conv1: 3x3 s2, 128->256, +BN2(bias)+ReLU, out = padded h1 (base (1,1))
    conv_8ph<128, 9, 2, true, false><<<256, 512, 0, stream>>>(
        pre, w1t, bias2f, h1, nullptr,
        129 * 128, 129 * 129 * 128,
        67 * 256, 66 * 256, 66 * 66 * 256);

    // conv2: 3x3 s1, 256->256 + fused SE pooling (h2 in its own region now)
    conv_8ph<256, 9, 1, false, true><<<256, 512, 0, stream>>>(
        h1, w2t, nullptr, h2, part,
        66 * 256, 66 * 66 * 256,
        0, 64 * 256, 4096 * 256);

    // finalize: fused SE-MLP + residual 1x1 conv (from pre) + combine
    finalize_kernel<<<1024, 256, 0, stream>>>(h2, pre, wrt, part,
                                              se_w1, se_b1, se_w2, se_b2, out);
}